// Round 9
// baseline (1550.821 us; speedup 1.0000x reference)
//
#include <hip/hip_runtime.h>
#include <math.h>

#define N_ 256
#define L_ 20
#define B_ 10
#define D_ 128
#define H_ 128
#define ASP_ 4
#define KK_ 16
#define NIT_ 20000
#define H2_ 256
#define G4_ 1024
#define LBD_ 25600
#define NL_ 5120
#define NLB_ 51200

typedef __attribute__((ext_vector_type(8))) short bf16x8;
typedef __attribute__((ext_vector_type(4))) float f32x4;

__device__ __forceinline__ float sigf(float x){ return 1.0f/(1.0f+expf(-x)); }
__device__ __forceinline__ unsigned short f2b(float f){
  unsigned int u = __float_as_uint(f);
  unsigned int r = (u + 0x7FFFu + ((u>>16)&1u)) >> 16;   // RNE
  return (unsigned short)r;
}

// ---------------- gather: embs[n,l,b,:] = itemEmb[seq[n,l,b],:] (+ bf16 shadow) ----------------
__global__ void k_gather(const int* __restrict__ seq, const float* __restrict__ itemEmb,
                         float* __restrict__ embs, unsigned short* __restrict__ ebh){
  int row = blockIdx.x;          // 0..51199 = (n,l,b)
  int t = threadIdx.x;           // 0..127
  int idx = seq[row];
  float v = itemEmb[idx*D_ + t];
  embs[row*D_ + t] = v;
  ebh[row*D_ + t] = f2b(v);
}

// ---------------- fc1: u[n] = dot(embs[n,:], fc1_w) + fc1_b ----------------
__global__ void k_fc1(const float* __restrict__ embs, const float* __restrict__ w,
                      const float* __restrict__ b, float* __restrict__ u){
  int n = blockIdx.x; int t = threadIdx.x;
  float s = 0.f;
  for (int i = t; i < LBD_; i += 256) s += embs[n*LBD_+i]*w[i];
  __shared__ float red[256];
  red[t]=s; __syncthreads();
  for (int o=128;o>0;o>>=1){ if(t<o) red[t]+=red[t+o]; __syncthreads(); }
  if(t==0) u[n]=red[0]+b[0];
}

// ---------------- uA[a,n,h] = tanh(tanh(u[n]*proju[a,h])) ----------------
__global__ void k_ua(const float* __restrict__ u, const float* __restrict__ proju,
                     float* __restrict__ ua){
  int i = blockIdx.x*blockDim.x + threadIdx.x;
  if(i >= ASP_*N_*H_) return;
  int h = i % H_; int n = (i/H_) % N_; int a = i/(H_*N_);
  ua[i] = tanhf(tanhf(u[n]*proju[a*H_+h]));
}

// ---------------- sq[a,n] = sum_h uA^2 ----------------
__global__ void k_sq(const float* __restrict__ ua, float* __restrict__ sq){
  int an = blockIdx.x; int t = threadIdx.x;   // 128 threads
  float v = ua[an*H_ + t]; v *= v;
  __shared__ float red[128];
  red[t]=v; __syncthreads();
  for(int o=64;o>0;o>>=1){ if(t<o) red[t]+=red[t+o]; __syncthreads(); }
  if(t==0) sq[an]=red[0];
}

// ---------------- dist[a,n,m] ----------------
__global__ void k_dist(const float* __restrict__ ua, const float* __restrict__ sq,
                       float* __restrict__ dist){
  int n = blockIdx.x, a = blockIdx.y, m = threadIdx.x;  // 256 threads
  __shared__ float un[H_];
  if(m < H_) un[m] = ua[(a*N_+n)*H_ + m];
  __syncthreads();
  const float* um = &ua[(a*N_+m)*H_];
  float dot=0.f;
  for(int h=0;h<H_;h++) dot += un[h]*um[h];
  float dval = sq[a*N_+n] + sq[a*N_+m] - 2.f*dot;
  if(m==n) dval = -1.0f;
  dist[(a*N_+n)*N_ + m] = dval;
}

// ---------------- top-16 smallest, wave-parallel: 1 wave per (a,n) row ----------------
__global__ __launch_bounds__(256) void k_topk(const float* __restrict__ dist, int* __restrict__ nbr){
  int wid = blockIdx.x*(blockDim.x>>6) + (threadIdx.x>>6);  // row = (a*N_+n)
  if(wid >= ASP_*N_) return;
  int lane = threadIdx.x & 63;
  const float* row = &dist[(long)wid*N_];
  float v[4]; int idx[4];
  #pragma unroll
  for(int j=0;j<4;j++){ int m = lane*4 + j; v[j] = row[m]; idx[j] = m; }
  for(int k=0;k<KK_;k++){
    float bv = v[0]; int bi = idx[0];
    #pragma unroll
    for(int j=1;j<4;j++)
      if(v[j] < bv || (v[j]==bv && idx[j] < bi)){ bv=v[j]; bi=idx[j]; }
    float rv = bv; int ri = bi;
    #pragma unroll
    for(int o=32;o>0;o>>=1){
      float ov = __shfl_xor(rv, o, 64);
      int   oi = __shfl_xor(ri, o, 64);
      if(ov < rv || (ov==rv && oi < ri)){ rv=ov; ri=oi; }
    }
    if((ri>>2) == lane){ v[ri&3] = 3.4e38f; idx[ri&3] = 0x7fffffff; }
    if(k>0 && lane==0) nbr[wid*(KK_-1)+(k-1)] = ri;
  }
}

// ---------------- EB[n,l,d] = sum_b embs ----------------
__global__ void k_eb(const float* __restrict__ embs, float* __restrict__ eb){
  int nl = blockIdx.x; int d = threadIdx.x;
  float s=0.f;
  const float* p = &embs[nl*B_*D_ + d];
  for(int b=0;b<B_;b++) s += p[b*D_];
  eb[nl*D_ + d] = s;
}

// ---------------- projb[a,h,d] = bf16(aspProji[a,d,h]) ----------------
__global__ void k_projb(const float* __restrict__ proji, unsigned short* __restrict__ projb){
  int i = blockIdx.x*blockDim.x + threadIdx.x;
  if(i>=ASP_*D_*H_) return;
  int h=i%H_, d=(i/H_)%D_, a=i/(D_*H_);
  projb[(a*H_ + h)*D_ + d] = f2b(proji[i]);
}

// ---------------- fused UI stage: MFMA bf16 GEMM + tanh^2 + sum_b -> na[.., 0:128] ----------------
__global__ __launch_bounds__(256) void k_uimm(const unsigned short* __restrict__ ebh,
                                              const unsigned short* __restrict__ projb,
                                              float* __restrict__ na){
  __shared__ char smem[53248];
  unsigned short* As = (unsigned short*)smem;            // 80x128 bf16, swizzled 16B chunks
  unsigned short* Bs = (unsigned short*)(smem + 20480);  // 128x128 bf16, swizzled
  float*          Cs = (float*)smem;                     // 80x128 f32 (aliases As+Bs later)

  int mb = blockIdx.x;   // 0..639  -> nl0 = mb*8, A rows r0 = mb*80
  int a  = blockIdx.y;   // 0..3
  int tid = threadIdx.x;

  const unsigned short* asrc = ebh + (size_t)mb*10240;
  #pragma unroll
  for(int t=0;t<5;t++){
    int c = tid + t*256;
    int row = c >> 4;
    *(bf16x8*)(As + 8*(c ^ (row&7))) = *(const bf16x8*)(asrc + 8*c);
  }
  const unsigned short* bsrc = projb + a*16384;
  #pragma unroll
  for(int t=0;t<8;t++){
    int c = tid + t*256;
    int row = c >> 4;
    *(bf16x8*)(Bs + 8*(c ^ (row&7))) = *(const bf16x8*)(bsrc + 8*c);
  }
  __syncthreads();

  int lane = tid & 63, wave = tid >> 6;
  int l15 = lane & 15, l4 = lane >> 4;
  f32x4 acc[5][2] = {};
  #pragma unroll
  for(int kk=0;kk<4;kk++){
    bf16x8 bfr[2];
    #pragma unroll
    for(int tc=0;tc<2;tc++){
      int h = (wave*2+tc)*16 + l15;
      int c = h*16 + kk*4 + l4;
      bfr[tc] = *(const bf16x8*)(Bs + 8*(c ^ (h&7)));
    }
    #pragma unroll
    for(int tr=0;tr<5;tr++){
      int R = tr*16 + l15;
      int c = R*16 + kk*4 + l4;
      bf16x8 afr = *(const bf16x8*)(As + 8*(c ^ (R&7)));
      acc[tr][0] = __builtin_amdgcn_mfma_f32_16x16x32_bf16(afr, bfr[0], acc[tr][0], 0,0,0);
      acc[tr][1] = __builtin_amdgcn_mfma_f32_16x16x32_bf16(afr, bfr[1], acc[tr][1], 0,0,0);
    }
  }
  __syncthreads();

  #pragma unroll
  for(int tr=0;tr<5;tr++)
    #pragma unroll
    for(int tc=0;tc<2;tc++){
      int col = (wave*2+tc)*16 + l15;
      #pragma unroll
      for(int r=0;r<4;r++){
        int R = tr*16 + l4*4 + r;
        Cs[R*128 + col] = tanhf(tanhf(acc[tr][tc][r]));
      }
    }
  __syncthreads();

  #pragma unroll
  for(int t=0;t<4;t++){
    int oi = t*256 + tid;
    int g = oi >> 7, col = oi & 127;
    float s = 0.f;
    const float* p = Cs + g*1280 + col;
    #pragma unroll
    for(int b=0;b<10;b++) s += p[b*128];
    int nl = mb*8 + g;
    int n = nl/L_, l = nl%L_;
    na[((size_t)(n*ASP_+a)*L_ + l)*H2_ + col] = s;
  }
}

// ---------------- uHis_h: bf16 MFMA split-K (grid 4x4x25) ----------------
__global__ __launch_bounds__(256) void k_uhismm(const float* __restrict__ U,
    const float* __restrict__ W, const float* __restrict__ bias, float* __restrict__ C){
  __shared__ unsigned short As[2048];   // 64 rows x 32 k, chunk = q*64+row (8 bf16 each)
  __shared__ unsigned short Bs[2048];
  int tid = threadIdx.x;
  int m0 = blockIdx.y*64, n0 = blockIdx.x*64;
  int kb0 = blockIdx.z*800;
  int row = tid & 63, q = tid >> 6;
  int lane = tid & 63, wave = tid >> 6;
  int l15 = lane & 15, l4 = lane >> 4;
  int wr = (wave>>1)*32, wc = (wave&1)*32;
  f32x4 acc[2][2] = {};
  for(int s=0;s<25;s++){
    int k0 = kb0 + s*32 + q*8;
    {
      const float* pa = &U[(size_t)(m0+row)*NIT_ + k0];
      float4 a0 = *(const float4*)pa, a1 = *(const float4*)(pa+4);
      bf16x8 av;
      av[0]=f2b(a0.x); av[1]=f2b(a0.y); av[2]=f2b(a0.z); av[3]=f2b(a0.w);
      av[4]=f2b(a1.x); av[5]=f2b(a1.y); av[6]=f2b(a1.z); av[7]=f2b(a1.w);
      *(bf16x8*)(As + 8*tid) = av;
      const float* pb = &W[(size_t)(n0+row)*NIT_ + k0];
      float4 b0 = *(const float4*)pb, b1 = *(const float4*)(pb+4);
      bf16x8 bv;
      bv[0]=f2b(b0.x); bv[1]=f2b(b0.y); bv[2]=f2b(b0.z); bv[3]=f2b(b0.w);
      bv[4]=f2b(b1.x); bv[5]=f2b(b1.y); bv[6]=f2b(b1.z); bv[7]=f2b(b1.w);
      *(bf16x8*)(Bs + 8*tid) = bv;
    }
    __syncthreads();
    bf16x8 afr[2], bfr[2];
    #pragma unroll
    for(int mt=0;mt<2;mt++) afr[mt] = *(const bf16x8*)(As + 8*(l4*64 + wr + mt*16 + l15));
    #pragma unroll
    for(int nt=0;nt<2;nt++) bfr[nt] = *(const bf16x8*)(Bs + 8*(l4*64 + wc + nt*16 + l15));
    #pragma unroll
    for(int mt=0;mt<2;mt++)
      #pragma unroll
      for(int nt=0;nt<2;nt++)
        acc[mt][nt] = __builtin_amdgcn_mfma_f32_16x16x32_bf16(afr[mt], bfr[nt], acc[mt][nt], 0,0,0);
    __syncthreads();
  }
  #pragma unroll
  for(int mt=0;mt<2;mt++)
    #pragma unroll
    for(int nt=0;nt<2;nt++){
      int col = n0 + wc + nt*16 + l15;
      #pragma unroll
      for(int r=0;r<4;r++){
        int rw = m0 + wr + mt*16 + l4*4 + r;
        float v = acc[mt][nt][r];
        if(blockIdx.z==0) v += bias[col];
        atomicAdd(&C[rw*H2_ + col], v);
      }
    }
}

// ---------------- cast out_w -> bf16 ----------------
__global__ void k_outb(const float* __restrict__ w, unsigned short* __restrict__ wb){
  int i = blockIdx.x*blockDim.x + threadIdx.x;   // 640000 threads, 8 elems each
  const float* p = w + (size_t)i*8;
  float4 a = *(const float4*)p, b = *(const float4*)(p+4);
  bf16x8 v;
  v[0]=f2b(a.x); v[1]=f2b(a.y); v[2]=f2b(a.z); v[3]=f2b(a.w);
  v[4]=f2b(b.x); v[5]=f2b(b.y); v[6]=f2b(b.z); v[7]=f2b(b.w);
  *(bf16x8*)(wb + (size_t)i*8) = v;
}

// ---------------- logits: bf16 MFMA, tile 256x32, grid 625, frags straight from L2 ----------------
__global__ __launch_bounds__(256) void k_logitsmm(const unsigned short* __restrict__ Ab,
    const unsigned short* __restrict__ Wb, const float* __restrict__ bias,
    float* __restrict__ C){
  int n0 = blockIdx.x*32;
  int tid = threadIdx.x;
  int lane = tid & 63, wave = tid >> 6;
  int l15 = lane & 15, l4 = lane >> 4;
  f32x4 acc[4][2] = {};
  #pragma unroll
  for(int kk=0;kk<8;kk++){
    int k0 = kk*32 + l4*8;
    bf16x8 bfr[2];
    #pragma unroll
    for(int nt=0;nt<2;nt++)
      bfr[nt] = *(const bf16x8*)(Wb + (size_t)(n0 + nt*16 + l15)*H2_ + k0);
    #pragma unroll
    for(int mt=0;mt<4;mt++){
      bf16x8 afr = *(const bf16x8*)(Ab + (size_t)(wave*64 + mt*16 + l15)*H2_ + k0);
      acc[mt][0] = __builtin_amdgcn_mfma_f32_16x16x32_bf16(afr, bfr[0], acc[mt][0], 0,0,0);
      acc[mt][1] = __builtin_amdgcn_mfma_f32_16x16x32_bf16(afr, bfr[1], acc[mt][1], 0,0,0);
    }
  }
  #pragma unroll
  for(int mt=0;mt<4;mt++)
    #pragma unroll
    for(int nt=0;nt<2;nt++){
      int col = n0 + nt*16 + l15;
      float bs = bias[col];
      #pragma unroll
      for(int r=0;r<4;r++){
        int row = wave*64 + mt*16 + l4*4 + r;
        C[(size_t)row*NIT_ + col] = acc[mt][nt][r] + bs;
      }
    }
}

// ---------------- generic fp32 NT GEMM ----------------
__global__ __launch_bounds__(256) void k_gemm(const float* __restrict__ A, const float* __restrict__ W,
    float* __restrict__ C, const float* __restrict__ bias,
    int M, int Nn, int K, int kchunk, int atomic_mode){
  __shared__ float As[64][17];
  __shared__ float Ws[64][17];
  int tid = threadIdx.x;
  int tx = tid & 15, ty = tid >> 4;
  int m0 = blockIdx.y*64, n0 = blockIdx.x*64;
  int kb0 = blockIdx.z*kchunk;
  int kend = kb0 + kchunk; if(kend > K) kend = K;
  float acc[4][4] = {};
  int lrow = tid >> 2;
  int lc4 = (tid & 3) * 4;
  for(int kb = kb0; kb < kend; kb += 16){
    {
      int gr = m0 + lrow;
      float4 v = make_float4(0,0,0,0);
      if(gr < M) v = *(const float4*)&A[(long)gr*K + kb + lc4];
      As[lrow][lc4+0]=v.x; As[lrow][lc4+1]=v.y; As[lrow][lc4+2]=v.z; As[lrow][lc4+3]=v.w;
      int gw = n0 + lrow;
      float4 u = make_float4(0,0,0,0);
      if(gw < Nn) u = *(const float4*)&W[(long)gw*K + kb + lc4];
      Ws[lrow][lc4+0]=u.x; Ws[lrow][lc4+1]=u.y; Ws[lrow][lc4+2]=u.z; Ws[lrow][lc4+3]=u.w;
    }
    __syncthreads();
    for(int k=0;k<16;k++){
      float av[4], wv[4];
      #pragma unroll
      for(int r=0;r<4;r++) av[r]=As[ty*4+r][k];
      #pragma unroll
      for(int c=0;c<4;c++) wv[c]=Ws[tx*4+c][k];
      #pragma unroll
      for(int r=0;r<4;r++)
        #pragma unroll
        for(int c=0;c<4;c++) acc[r][c] += av[r]*wv[c];
    }
    __syncthreads();
  }
  for(int r=0;r<4;r++){
    int row = m0 + ty*4 + r; if(row >= M) continue;
    for(int c=0;c<4;c++){
      int col = n0 + tx*4 + c; if(col >= Nn) continue;
      float v = acc[r][c];
      if(bias && blockIdx.z==0) v += bias[col];
      if(atomic_mode) atomicAdd(&C[(long)row*Nn+col], v);
      else C[(long)row*Nn+col] = v;
    }
  }
}

// ---------------- PI: na[n,a,l,128:256] = sum_nbr E2[nbr,l,h] + B*dh_b[h] ----------------
__global__ void k_pi(const float* __restrict__ e2, const int* __restrict__ nbr,
                     const float* __restrict__ dh_b, float* __restrict__ na){
  int n = blockIdx.x, a = blockIdx.y, h = threadIdx.x; // 128
  __shared__ int nb[KK_-1];
  if(h < KK_-1) nb[h] = nbr[(a*N_+n)*(KK_-1)+h];
  __syncthreads();
  float bias = (float)B_ * dh_b[h];
  for(int l=0;l<L_;l++){
    float s = bias;
    for(int k=0;k<KK_-1;k++) s += e2[(long)(nb[k]*L_ + l)*H_ + h];
    na[((long)(n*ASP_+a)*L_ + l)*H2_ + H_ + h] = s;
  }
}

// ---------------- x: flat reinterpret max over 4 consecutive ----------------
__global__ void k_xmax(const float* __restrict__ na, float* __restrict__ x){
  int i = blockIdx.x*blockDim.x + threadIdx.x;
  if(i >= N_*L_*H2_) return;
  int n = i / (L_*H2_);
  int j = i % (L_*H2_);
  const float* p = &na[(long)n*ASP_*L_*H2_ + 4*j];
  x[i] = fmaxf(fmaxf(p[0],p[1]), fmaxf(p[2],p[3]));
}

// ---------------- LSTM weight permute (fp32, for wih used by xg GEMM) ----------------
__global__ void k_perm(const float* __restrict__ src, float* __restrict__ dst){
  int i = blockIdx.x*blockDim.x + threadIdx.x;
  if(i >= G4_*H2_) return;
  int k = i % H2_; int j = i / H2_;
  int g = j / H2_, jj = j % H2_;
  dst[(jj*4+g)*H2_ + k] = src[i];
}
// ---------------- LSTM recurrent weight permute + bf16 cast ----------------
__global__ void k_permh(const float* __restrict__ src, unsigned short* __restrict__ dst){
  int i = blockIdx.x*blockDim.x + threadIdx.x;
  if(i >= G4_*H2_) return;
  int k = i % H2_; int j = i / H2_;
  int g = j / H2_, jj = j % H2_;
  dst[(jj*4+g)*H2_ + k] = f2b(src[i]);
}
__global__ void k_permb(const float* __restrict__ bih, const float* __restrict__ bhh,
                        float* __restrict__ bp){
  int j = blockIdx.x*blockDim.x + threadIdx.x;
  if(j >= G4_) return;
  int g = j / H2_, jj = j % H2_;
  bp[jj*4+g] = bih[j] + bhh[j];
}

// ---------------- fused LSTM layer: ONE launch per layer ----------------
// 16 blocks x 1024 thr (16 waves). Block b owns samples n0=16b..16b+15 ENTIRELY
// (all 1024 gates) -> recurrence needs only own-block h => __syncthreads() only.
// h bf16 (swizzled chunks) + c fp32 in LDS; Whb streamed from L2 each step
// (same 512KB address stream every step). Epilogue = r8-verified shfl regather.
__global__ __launch_bounds__(1024) void k_lstm_layer(
    const unsigned short* __restrict__ Whb,   // [1024][256] bf16 permuted (col=jj*4+g)
    const float* __restrict__ xg,             // [256][20][1024] permuted ih products
    float* __restrict__ Y){                   // [256][20][256] fp32 h sequence
  __shared__ unsigned short hs[16*H2_];       // 8 KB, chunk ch=nl*32+k/8, swizzled ^(nl&7)
  __shared__ float cs[16*H2_];                // 16 KB
  int tid = threadIdx.x;
  int n0 = blockIdx.x * 16;
  int lane = tid & 63, wave = tid >> 6;       // wave 0..15
  int l15 = lane & 15, l4 = lane >> 4;
  int q = l15 & 3;
  for(int t=0; t<L_; t++){
    f32x4 acc[4] = {};
    if(t > 0){
      bf16x8 afr[8];
      #pragma unroll
      for(int kk=0; kk<8; kk++){
        int ch = l15*32 + kk*4 + l4;
        afr[kk] = *(const bf16x8*)(hs + 8*(ch ^ (l15&7)));
      }
      #pragma unroll
      for(int i=0;i<4;i++){
        int ct = wave*4 + i;
        const unsigned short* wrow = Whb + (size_t)(ct*16 + l15)*H2_ + l4*8;
        #pragma unroll
        for(int kk=0; kk<8; kk++){
          bf16x8 bfr = *(const bf16x8*)(wrow + kk*32);
          acc[i] = __builtin_amdgcn_mfma_f32_16x16x32_bf16(afr[kk], bfr, acc[i], 0,0,0);
        }
      }
    }
    __syncthreads();   // all A-reads of h(t-1) done before overwriting h
    #pragma unroll
    for(int i=0;i<4;i++){
      int ct = wave*4 + i;
      int col = ct*16 + l15;
      int jj = col >> 2;
      #pragma unroll
      for(int r=0;r<4;r++){
        int nl = l4*4 + r;
        int n = n0 + nl;
        float v = acc[i][r] + xg[((size_t)n*L_ + t)*G4_ + col];
        float b1 = __shfl_xor(v, 1, 64);
        float c2 = __shfl_xor(v, 2, 64);
        float d3 = __shfl_xor(b1, 2, 64);
        int m1=q^1, m2=q^2, m3=q^3;
        float gi = (q ==0)? v : (q ==1)? b1 : (q ==2)? c2 : d3;
        float gf = (m1==0)? v : (m1==1)? b1 : (m1==2)? c2 : d3;
        float gg = (m2==0)? v : (m2==1)? b1 : (m2==2)? c2 : d3;
        float go = (m3==0)? v : (m3==1)? b1 : (m3==2)? c2 : d3;
        if(q == 0){
          float cold = (t==0) ? 0.f : cs[nl*H2_ + jj];
          float cnew = sigf(gf)*cold + sigf(gi)*tanhf(gg);
          cs[nl*H2_ + jj] = cnew;
          float hnew = sigf(go)*tanhf(cnew);
          Y[((size_t)n*L_ + t)*H2_ + jj] = hnew;
          int ch = nl*32 + (jj>>3);
          *(unsigned short*)((char*)hs + 16*(ch ^ (nl&7)) + (jj&7)*2) = f2b(hnew);
        }
      }
    }
    __syncthreads();   // h(t) complete before next step's A-reads
  }
}

// ---------------- h_agg = tanh(sum_t y1) (+ bf16 shadow) ----------------
__global__ void k_hagg(const float* __restrict__ y1, float* __restrict__ hagg,
                       unsigned short* __restrict__ haggb){
  int i = blockIdx.x*blockDim.x + threadIdx.x;
  if(i>=N_*H2_) return;
  int n = i / H2_, jj = i % H2_;
  float s=0.f;
  for(int t=0;t<L_;t++) s += y1[((long)n*L_+t)*H2_ + jj];
  float v = tanhf(s);
  hagg[i] = v;
  haggb[i] = f2b(v);
}

// ---------------- gate ----------------
__global__ void k_gate(const float* __restrict__ uhish, const float* __restrict__ hagg,
                       const float* __restrict__ g1w, const float* __restrict__ g1b,
                       const float* __restrict__ g2w, const float* __restrict__ g2b,
                       float* __restrict__ gate){
  int n = blockIdx.x; int t = threadIdx.x; // 256
  float s = uhish[n*H2_+t]*g1w[t] + hagg[n*H2_+t]*g2w[t];
  __shared__ float red[256];
  red[t]=s; __syncthreads();
  for(int o=128;o>0;o>>=1){ if(t<o) red[t]+=red[t+o]; __syncthreads(); }
  if(t==0) gate[n] = 1.f/(1.f+expf(-(red[0]+g1b[0]+g2b[0])));
}

// ---------------- softmax row stats ----------------
__global__ void k_smstat(const float* __restrict__ logits, float* __restrict__ rowmax,
                         float* __restrict__ rowsum){
  int n = blockIdx.x; int t = threadIdx.x;
  const float* row = &logits[(long)n*NIT_];
  float m = -3.4e38f;
  for(int i=t;i<NIT_;i+=256) m = fmaxf(m, row[i]);
  __shared__ float red[256];
  __shared__ float mm;
  red[t]=m; __syncthreads();
  for(int o=128;o>0;o>>=1){ if(t<o) red[t]=fmaxf(red[t],red[t+o]); __syncthreads(); }
  if(t==0){ mm = red[0]; rowmax[n]=red[0]; }
  __syncthreads();
  float s=0.f;
  for(int i=t;i<NIT_;i+=256) s += expf(row[i]-mm);
  __syncthreads();
  red[t]=s; __syncthreads();
  for(int o=128;o>0;o>>=1){ if(t<o) red[t]+=red[t+o]; __syncthreads(); }
  if(t==0) rowsum[n]=red[0];
}

// ---------------- final ----------------
__global__ void k_final(const float* __restrict__ logits, const float* __restrict__ rowmax,
                        const float* __restrict__ rowsum, const float* __restrict__ gate,
                        const float* __restrict__ uHis, float* __restrict__ out){
  int i = blockIdx.x*blockDim.x + threadIdx.x;
  if(i >= N_*NIT_) return;
  int n = i / NIT_;
  float g = gate[n];
  float p = expf(logits[i]-rowmax[n]) / rowsum[n];
  out[i] = g*p + (1.f-g)*uHis[i];
}

extern "C" void kernel_launch(void* const* d_in, const int* in_sizes, int n_in,
                              void* d_out, int out_size, void* d_ws, size_t ws_size,
                              hipStream_t stream) {
  const int*   seq     = (const int*)  d_in[0];
  const float* uHis    = (const float*)d_in[1];
  const float* itemEmb = (const float*)d_in[2];
  const float* fc1_w   = (const float*)d_in[3];
  const float* fc1_b   = (const float*)d_in[4];
  const float* aspProju= (const float*)d_in[5];
  const float* aspProji= (const float*)d_in[6];
  const float* dh_w    = (const float*)d_in[7];
  const float* dh_b    = (const float*)d_in[8];
  const float* wih0    = (const float*)d_in[9];
  const float* whh0    = (const float*)d_in[10];
  const float* bih0    = (const float*)d_in[11];
  const float* bhh0    = (const float*)d_in[12];
  const float* wih1    = (const float*)d_in[13];
  const float* whh1    = (const float*)d_in[14];
  const float* bih1    = (const float*)d_in[15];
  const float* bhh1    = (const float*)d_in[16];
  const float* out_w   = (const float*)d_in[17];
  const float* out_b   = (const float*)d_in[18];
  const float* his_w   = (const float*)d_in[19];
  const float* his_b   = (const float*)d_in[20];
  const float* g1_w    = (const float*)d_in[21];
  const float* g1_b    = (const float*)d_in[22];
  const float* g2_w    = (const float*)d_in[23];
  const float* g2_b    = (const float*)d_in[24];

  float* ws = (float*)d_ws;
  float* embs = ws + 0;            // 6,553,600   (reused as logits later)
  float* cub  = ws + 6553600;      // 6,553,600   (ebh bf16 shadow; reused as xg later)
  float* na   = ws + 13107200;     // 5,242,880   (reused as outwb bf16 after xmax)
  float* x    = ws + 18350080;     // 1,310,720   (reused as haggb after xg0)
  float* y0   = ws + 19660800;     // 1,310,720
  float* y1   = ws + 20971520;     // 1,310,720
  float* eb   = ws + 22282240;     //   655,360
  float* e2   = ws + 22937600;     //   655,360
  float* dist = ws + 23592960;     //   262,144
  float* ua   = ws + 23855104;     //   131,072
  float* projT= ws + 23986176;     //    65,536  (holds projb bf16)
  float* wp0  = ws + 24051712;     //   262,144  (fp32 permuted wih0)
  float* whp0 = ws + 24313856;     //   262,144  (bf16 permuted whh0 lives here)
  float* wp1  = ws + 24576000;     //   262,144  (fp32 permuted wih1)
  float* whp1 = ws + 24838144;     //   262,144  (bf16 permuted whh1 lives here)
  float* bp0  = ws + 25100288;     //     1,024
  float* bp1  = ws + 25101312;     //     1,024
  float* uemb = ws + 25167872;     //       256
  float* sqb  = ws + 25168128;     //     1,024
  int*   nbr  = (int*)(ws + 25169152); // 15,360 ints
  float* uhish= ws + 25184512;     //    65,536
  float* hagg = ws + 25250048;     //    65,536
  float* rowmax=ws + 25315584;     //       256
  float* rowsum=ws + 25315840;     //       256
  float* gateb =ws + 25316096;     //       256
  float* logits = embs;            // reuse
  float* xg = cub;                 // reuse (ebh dead after k_uimm)
  unsigned short* ebh   = (unsigned short*)cub;   // bf16 shadow (inside cub slot)
  unsigned short* projb = (unsigned short*)projT; // bf16 (inside projT slot)
  unsigned short* outwb = (unsigned short*)na;    // bf16 out_w (na dead after xmax)
  unsigned short* haggb = (unsigned short*)x;     // bf16 hagg (x dead after xg0)
  unsigned short* whb0  = (unsigned short*)whp0;  // bf16 permuted whh0
  unsigned short* whb1  = (unsigned short*)whp1;  // bf16 permuted whh1

  // 1. embedding gather (fp32 + bf16 shadow)
  k_gather<<<NLB_, D_, 0, stream>>>(seq, itemEmb, embs, ebh);
  // 2. fc1 -> u_embs
  k_fc1<<<N_, 256, 0, stream>>>(embs, fc1_w, fc1_b, uemb);
  // 3. uA
  k_ua<<<(ASP_*N_*H_+255)/256, 256, 0, stream>>>(uemb, aspProju, ua);
  // 4. sq
  k_sq<<<ASP_*N_, 128, 0, stream>>>(ua, sqb);
  // 5. dist
  k_dist<<<dim3(N_,ASP_), 256, 0, stream>>>(ua, sqb, dist);
  // 6. top-k neighbors
  k_topk<<<ASP_*N_/4, 256, 0, stream>>>(dist, nbr);
  // 7. EB = sum_b embs
  k_eb<<<NL_, D_, 0, stream>>>(embs, eb);
  // 8. E2 = EB @ dh_w^T
  k_gemm<<<dim3(2, 80, 1), 256, 0, stream>>>(eb, dh_w, e2, nullptr, NL_, H_, D_, D_, 0);
  // 9. projb (bf16 transposed proj)
  k_projb<<<(ASP_*D_*H_+255)/256, 256, 0, stream>>>(aspProji, projb);
  // 10. fused UI stage: MFMA + tanh^2 + sum_b
  k_uimm<<<dim3(NL_/8, ASP_), 256, 0, stream>>>(ebh, projb, na);
  // 11. PI (neighbor sums)
  k_pi<<<dim3(N_,ASP_), H_, 0, stream>>>(e2, nbr, dh_b, na);
  // 12. x = flat max-4
  k_xmax<<<(N_*L_*H2_+255)/256, 256, 0, stream>>>(na, x);
  // 12b. cast out_w -> bf16 (into dead na region)
  k_outb<<<2500, 256, 0, stream>>>(out_w, outwb);
  // 13. LSTM weight permutes: wih fp32, whh bf16
  k_perm <<<(G4_*H2_+255)/256,256,0,stream>>>(wih0, wp0);
  k_permh<<<(G4_*H2_+255)/256,256,0,stream>>>(whh0, whb0);
  k_perm <<<(G4_*H2_+255)/256,256,0,stream>>>(wih1, wp1);
  k_permh<<<(G4_*H2_+255)/256,256,0,stream>>>(whh1, whb1);
  k_permb<<<4,256,0,stream>>>(bih0,bhh0,bp0);
  k_permb<<<4,256,0,stream>>>(bih1,bhh1,bp1);
  // 14. xg0 = x @ wp0^T + bp0
  k_gemm<<<dim3(16,80,1),256,0,stream>>>(x, wp0, xg, bp0, NL_, G4_, H2_, H2_, 0);
  // 15. LSTM layer 0: ONE launch, 20 steps internal
  k_lstm_layer<<<16, 1024, 0, stream>>>(whb0, xg, y0);
  // 16. xg1 = y0 @ wp1^T + bp1
  k_gemm<<<dim3(16,80,1),256,0,stream>>>(y0, wp1, xg, bp1, NL_, G4_, H2_, H2_, 0);
  // 17. LSTM layer 1: ONE launch
  k_lstm_layer<<<16, 1024, 0, stream>>>(whb1, xg, y1);
  // 18. h_agg (+ bf16 shadow into dead x region)
  k_hagg<<<(N_*H2_+255)/256,256,0,stream>>>(y1, hagg, haggb);
  // 19. logits = h_agg @ out_w^T + out_b : bf16 MFMA (grid 625, tile 256x32)
  k_logitsmm<<<625, 256, 0, stream>>>(haggb, outwb, out_b, logits);
  // 20. uHis_h = uHis @ his_w^T + his_b : bf16 MFMA split-K
  hipMemsetAsync(uhish, 0, N_*H2_*sizeof(float), stream);
  k_uhismm<<<dim3(4,4,25), 256, 0, stream>>>(uHis, his_w, his_b, uhish);
  // 21. gate
  k_gate<<<N_,256,0,stream>>>(uhish, hagg, g1_w, g1_b, g2_w, g2_b, gateb);
  // 22. softmax stats
  k_smstat<<<N_,256,0,stream>>>(logits, rowmax, rowsum);
  // 23. final scores
  k_final<<<(N_*NIT_+255)/256,256,0,stream>>>(logits, rowmax, rowsum, gateb, uHis, (float*)d_out);
}

// Round 10
// 848.223 us; speedup vs baseline: 1.8283x; 1.8283x over previous
//
#include <hip/hip_runtime.h>
#include <math.h>

#define N_ 256
#define L_ 20
#define B_ 10
#define D_ 128
#define H_ 128
#define ASP_ 4
#define KK_ 16
#define NIT_ 20000
#define H2_ 256
#define G4_ 1024
#define LBD_ 25600
#define NL_ 5120
#define NLB_ 51200

typedef __attribute__((ext_vector_type(8))) short bf16x8;
typedef __attribute__((ext_vector_type(4))) float f32x4;

__device__ __forceinline__ float sigf(float x){ return 1.0f/(1.0f+expf(-x)); }
__device__ __forceinline__ unsigned short f2b(float f){
  unsigned int u = __float_as_uint(f);
  unsigned int r = (u + 0x7FFFu + ((u>>16)&1u)) >> 16;   // RNE
  return (unsigned short)r;
}

// ---------------- gather: embs[n,l,b,:] = itemEmb[seq[n,l,b],:] (+ bf16 shadow) ----------------
__global__ void k_gather(const int* __restrict__ seq, const float* __restrict__ itemEmb,
                         float* __restrict__ embs, unsigned short* __restrict__ ebh){
  int row = blockIdx.x;          // 0..51199 = (n,l,b)
  int t = threadIdx.x;           // 0..127
  int idx = seq[row];
  float v = itemEmb[idx*D_ + t];
  embs[row*D_ + t] = v;
  ebh[row*D_ + t] = f2b(v);
}

// ---------------- fc1: u[n] = dot(embs[n,:], fc1_w) + fc1_b ----------------
__global__ void k_fc1(const float* __restrict__ embs, const float* __restrict__ w,
                      const float* __restrict__ b, float* __restrict__ u){
  int n = blockIdx.x; int t = threadIdx.x;
  float s = 0.f;
  for (int i = t; i < LBD_; i += 256) s += embs[n*LBD_+i]*w[i];
  __shared__ float red[256];
  red[t]=s; __syncthreads();
  for (int o=128;o>0;o>>=1){ if(t<o) red[t]+=red[t+o]; __syncthreads(); }
  if(t==0) u[n]=red[0]+b[0];
}

// ---------------- uA[a,n,h] = tanh(tanh(u[n]*proju[a,h])) ----------------
__global__ void k_ua(const float* __restrict__ u, const float* __restrict__ proju,
                     float* __restrict__ ua){
  int i = blockIdx.x*blockDim.x + threadIdx.x;
  if(i >= ASP_*N_*H_) return;
  int h = i % H_; int n = (i/H_) % N_; int a = i/(H_*N_);
  ua[i] = tanhf(tanhf(u[n]*proju[a*H_+h]));
}

// ---------------- sq[a,n] = sum_h uA^2 ----------------
__global__ void k_sq(const float* __restrict__ ua, float* __restrict__ sq){
  int an = blockIdx.x; int t = threadIdx.x;   // 128 threads
  float v = ua[an*H_ + t]; v *= v;
  __shared__ float red[128];
  red[t]=v; __syncthreads();
  for(int o=64;o>0;o>>=1){ if(t<o) red[t]+=red[t+o]; __syncthreads(); }
  if(t==0) sq[an]=red[0];
}

// ---------------- dist[a,n,m] ----------------
__global__ void k_dist(const float* __restrict__ ua, const float* __restrict__ sq,
                       float* __restrict__ dist){
  int n = blockIdx.x, a = blockIdx.y, m = threadIdx.x;  // 256 threads
  __shared__ float un[H_];
  if(m < H_) un[m] = ua[(a*N_+n)*H_ + m];
  __syncthreads();
  const float* um = &ua[(a*N_+m)*H_];
  float dot=0.f;
  for(int h=0;h<H_;h++) dot += un[h]*um[h];
  float dval = sq[a*N_+n] + sq[a*N_+m] - 2.f*dot;
  if(m==n) dval = -1.0f;
  dist[(a*N_+n)*N_ + m] = dval;
}

// ---------------- top-16 smallest, wave-parallel: 1 wave per (a,n) row ----------------
__global__ __launch_bounds__(256) void k_topk(const float* __restrict__ dist, int* __restrict__ nbr){
  int wid = blockIdx.x*(blockDim.x>>6) + (threadIdx.x>>6);  // row = (a*N_+n)
  if(wid >= ASP_*N_) return;
  int lane = threadIdx.x & 63;
  const float* row = &dist[(long)wid*N_];
  float v[4]; int idx[4];
  #pragma unroll
  for(int j=0;j<4;j++){ int m = lane*4 + j; v[j] = row[m]; idx[j] = m; }
  for(int k=0;k<KK_;k++){
    float bv = v[0]; int bi = idx[0];
    #pragma unroll
    for(int j=1;j<4;j++)
      if(v[j] < bv || (v[j]==bv && idx[j] < bi)){ bv=v[j]; bi=idx[j]; }
    float rv = bv; int ri = bi;
    #pragma unroll
    for(int o=32;o>0;o>>=1){
      float ov = __shfl_xor(rv, o, 64);
      int   oi = __shfl_xor(ri, o, 64);
      if(ov < rv || (ov==rv && oi < ri)){ rv=ov; ri=oi; }
    }
    if((ri>>2) == lane){ v[ri&3] = 3.4e38f; idx[ri&3] = 0x7fffffff; }
    if(k>0 && lane==0) nbr[wid*(KK_-1)+(k-1)] = ri;
  }
}

// ---------------- EB[n,l,d] = sum_b embs ----------------
__global__ void k_eb(const float* __restrict__ embs, float* __restrict__ eb){
  int nl = blockIdx.x; int d = threadIdx.x;
  float s=0.f;
  const float* p = &embs[nl*B_*D_ + d];
  for(int b=0;b<B_;b++) s += p[b*D_];
  eb[nl*D_ + d] = s;
}

// ---------------- projb[a,h,d] = bf16(aspProji[a,d,h]) ----------------
__global__ void k_projb(const float* __restrict__ proji, unsigned short* __restrict__ projb){
  int i = blockIdx.x*blockDim.x + threadIdx.x;
  if(i>=ASP_*D_*H_) return;
  int h=i%H_, d=(i/H_)%D_, a=i/(D_*H_);
  projb[(a*H_ + h)*D_ + d] = f2b(proji[i]);
}

// ---------------- fused UI stage: MFMA bf16 GEMM + tanh^2 + sum_b -> na[.., 0:128] ----------------
__global__ __launch_bounds__(256) void k_uimm(const unsigned short* __restrict__ ebh,
                                              const unsigned short* __restrict__ projb,
                                              float* __restrict__ na){
  __shared__ char smem[53248];
  unsigned short* As = (unsigned short*)smem;            // 80x128 bf16, swizzled 16B chunks
  unsigned short* Bs = (unsigned short*)(smem + 20480);  // 128x128 bf16, swizzled
  float*          Cs = (float*)smem;                     // 80x128 f32 (aliases As+Bs later)

  int mb = blockIdx.x;   // 0..639  -> nl0 = mb*8, A rows r0 = mb*80
  int a  = blockIdx.y;   // 0..3
  int tid = threadIdx.x;

  const unsigned short* asrc = ebh + (size_t)mb*10240;
  #pragma unroll
  for(int t=0;t<5;t++){
    int c = tid + t*256;
    int row = c >> 4;
    *(bf16x8*)(As + 8*(c ^ (row&7))) = *(const bf16x8*)(asrc + 8*c);
  }
  const unsigned short* bsrc = projb + a*16384;
  #pragma unroll
  for(int t=0;t<8;t++){
    int c = tid + t*256;
    int row = c >> 4;
    *(bf16x8*)(Bs + 8*(c ^ (row&7))) = *(const bf16x8*)(bsrc + 8*c);
  }
  __syncthreads();

  int lane = tid & 63, wave = tid >> 6;
  int l15 = lane & 15, l4 = lane >> 4;
  f32x4 acc[5][2] = {};
  #pragma unroll
  for(int kk=0;kk<4;kk++){
    bf16x8 bfr[2];
    #pragma unroll
    for(int tc=0;tc<2;tc++){
      int h = (wave*2+tc)*16 + l15;
      int c = h*16 + kk*4 + l4;
      bfr[tc] = *(const bf16x8*)(Bs + 8*(c ^ (h&7)));
    }
    #pragma unroll
    for(int tr=0;tr<5;tr++){
      int R = tr*16 + l15;
      int c = R*16 + kk*4 + l4;
      bf16x8 afr = *(const bf16x8*)(As + 8*(c ^ (R&7)));
      acc[tr][0] = __builtin_amdgcn_mfma_f32_16x16x32_bf16(afr, bfr[0], acc[tr][0], 0,0,0);
      acc[tr][1] = __builtin_amdgcn_mfma_f32_16x16x32_bf16(afr, bfr[1], acc[tr][1], 0,0,0);
    }
  }
  __syncthreads();

  #pragma unroll
  for(int tr=0;tr<5;tr++)
    #pragma unroll
    for(int tc=0;tc<2;tc++){
      int col = (wave*2+tc)*16 + l15;
      #pragma unroll
      for(int r=0;r<4;r++){
        int R = tr*16 + l4*4 + r;
        Cs[R*128 + col] = tanhf(tanhf(acc[tr][tc][r]));
      }
    }
  __syncthreads();

  #pragma unroll
  for(int t=0;t<4;t++){
    int oi = t*256 + tid;
    int g = oi >> 7, col = oi & 127;
    float s = 0.f;
    const float* p = Cs + g*1280 + col;
    #pragma unroll
    for(int b=0;b<10;b++) s += p[b*128];
    int nl = mb*8 + g;
    int n = nl/L_, l = nl%L_;
    na[((size_t)(n*ASP_+a)*L_ + l)*H2_ + col] = s;
  }
}

// ---------------- uHis_h: bf16 MFMA split-K (grid 4x4x25) ----------------
__global__ __launch_bounds__(256) void k_uhismm(const float* __restrict__ U,
    const float* __restrict__ W, const float* __restrict__ bias, float* __restrict__ C){
  __shared__ unsigned short As[2048];   // 64 rows x 32 k, chunk = q*64+row (8 bf16 each)
  __shared__ unsigned short Bs[2048];
  int tid = threadIdx.x;
  int m0 = blockIdx.y*64, n0 = blockIdx.x*64;
  int kb0 = blockIdx.z*800;
  int row = tid & 63, q = tid >> 6;
  int lane = tid & 63, wave = tid >> 6;
  int l15 = lane & 15, l4 = lane >> 4;
  int wr = (wave>>1)*32, wc = (wave&1)*32;
  f32x4 acc[2][2] = {};
  for(int s=0;s<25;s++){
    int k0 = kb0 + s*32 + q*8;
    {
      const float* pa = &U[(size_t)(m0+row)*NIT_ + k0];
      float4 a0 = *(const float4*)pa, a1 = *(const float4*)(pa+4);
      bf16x8 av;
      av[0]=f2b(a0.x); av[1]=f2b(a0.y); av[2]=f2b(a0.z); av[3]=f2b(a0.w);
      av[4]=f2b(a1.x); av[5]=f2b(a1.y); av[6]=f2b(a1.z); av[7]=f2b(a1.w);
      *(bf16x8*)(As + 8*tid) = av;
      const float* pb = &W[(size_t)(n0+row)*NIT_ + k0];
      float4 b0 = *(const float4*)pb, b1 = *(const float4*)(pb+4);
      bf16x8 bv;
      bv[0]=f2b(b0.x); bv[1]=f2b(b0.y); bv[2]=f2b(b0.z); bv[3]=f2b(b0.w);
      bv[4]=f2b(b1.x); bv[5]=f2b(b1.y); bv[6]=f2b(b1.z); bv[7]=f2b(b1.w);
      *(bf16x8*)(Bs + 8*tid) = bv;
    }
    __syncthreads();
    bf16x8 afr[2], bfr[2];
    #pragma unroll
    for(int mt=0;mt<2;mt++) afr[mt] = *(const bf16x8*)(As + 8*(l4*64 + wr + mt*16 + l15));
    #pragma unroll
    for(int nt=0;nt<2;nt++) bfr[nt] = *(const bf16x8*)(Bs + 8*(l4*64 + wc + nt*16 + l15));
    #pragma unroll
    for(int mt=0;mt<2;mt++)
      #pragma unroll
      for(int nt=0;nt<2;nt++)
        acc[mt][nt] = __builtin_amdgcn_mfma_f32_16x16x32_bf16(afr[mt], bfr[nt], acc[mt][nt], 0,0,0);
    __syncthreads();
  }
  #pragma unroll
  for(int mt=0;mt<2;mt++)
    #pragma unroll
    for(int nt=0;nt<2;nt++){
      int col = n0 + wc + nt*16 + l15;
      #pragma unroll
      for(int r=0;r<4;r++){
        int rw = m0 + wr + mt*16 + l4*4 + r;
        float v = acc[mt][nt][r];
        if(blockIdx.z==0) v += bias[col];
        atomicAdd(&C[rw*H2_ + col], v);
      }
    }
}

// ---------------- cast out_w -> bf16 ----------------
__global__ void k_outb(const float* __restrict__ w, unsigned short* __restrict__ wb){
  int i = blockIdx.x*blockDim.x + threadIdx.x;   // 640000 threads, 8 elems each
  const float* p = w + (size_t)i*8;
  float4 a = *(const float4*)p, b = *(const float4*)(p+4);
  bf16x8 v;
  v[0]=f2b(a.x); v[1]=f2b(a.y); v[2]=f2b(a.z); v[3]=f2b(a.w);
  v[4]=f2b(b.x); v[5]=f2b(b.y); v[6]=f2b(b.z); v[7]=f2b(b.w);
  *(bf16x8*)(wb + (size_t)i*8) = v;
}

// ---------------- logits: bf16 MFMA, tile 256x32, grid 625, frags straight from L2 ----------------
__global__ __launch_bounds__(256) void k_logitsmm(const unsigned short* __restrict__ Ab,
    const unsigned short* __restrict__ Wb, const float* __restrict__ bias,
    float* __restrict__ C){
  int n0 = blockIdx.x*32;
  int tid = threadIdx.x;
  int lane = tid & 63, wave = tid >> 6;
  int l15 = lane & 15, l4 = lane >> 4;
  f32x4 acc[4][2] = {};
  #pragma unroll
  for(int kk=0;kk<8;kk++){
    int k0 = kk*32 + l4*8;
    bf16x8 bfr[2];
    #pragma unroll
    for(int nt=0;nt<2;nt++)
      bfr[nt] = *(const bf16x8*)(Wb + (size_t)(n0 + nt*16 + l15)*H2_ + k0);
    #pragma unroll
    for(int mt=0;mt<4;mt++){
      bf16x8 afr = *(const bf16x8*)(Ab + (size_t)(wave*64 + mt*16 + l15)*H2_ + k0);
      acc[mt][0] = __builtin_amdgcn_mfma_f32_16x16x32_bf16(afr, bfr[0], acc[mt][0], 0,0,0);
      acc[mt][1] = __builtin_amdgcn_mfma_f32_16x16x32_bf16(afr, bfr[1], acc[mt][1], 0,0,0);
    }
  }
  #pragma unroll
  for(int mt=0;mt<4;mt++)
    #pragma unroll
    for(int nt=0;nt<2;nt++){
      int col = n0 + nt*16 + l15;
      float bs = bias[col];
      #pragma unroll
      for(int r=0;r<4;r++){
        int row = wave*64 + mt*16 + l4*4 + r;
        C[(size_t)row*NIT_ + col] = acc[mt][nt][r] + bs;
      }
    }
}

// ---------------- generic fp32 NT GEMM ----------------
__global__ __launch_bounds__(256) void k_gemm(const float* __restrict__ A, const float* __restrict__ W,
    float* __restrict__ C, const float* __restrict__ bias,
    int M, int Nn, int K, int kchunk, int atomic_mode){
  __shared__ float As[64][17];
  __shared__ float Ws[64][17];
  int tid = threadIdx.x;
  int tx = tid & 15, ty = tid >> 4;
  int m0 = blockIdx.y*64, n0 = blockIdx.x*64;
  int kb0 = blockIdx.z*kchunk;
  int kend = kb0 + kchunk; if(kend > K) kend = K;
  float acc[4][4] = {};
  int lrow = tid >> 2;
  int lc4 = (tid & 3) * 4;
  for(int kb = kb0; kb < kend; kb += 16){
    {
      int gr = m0 + lrow;
      float4 v = make_float4(0,0,0,0);
      if(gr < M) v = *(const float4*)&A[(long)gr*K + kb + lc4];
      As[lrow][lc4+0]=v.x; As[lrow][lc4+1]=v.y; As[lrow][lc4+2]=v.z; As[lrow][lc4+3]=v.w;
      int gw = n0 + lrow;
      float4 u = make_float4(0,0,0,0);
      if(gw < Nn) u = *(const float4*)&W[(long)gw*K + kb + lc4];
      Ws[lrow][lc4+0]=u.x; Ws[lrow][lc4+1]=u.y; Ws[lrow][lc4+2]=u.z; Ws[lrow][lc4+3]=u.w;
    }
    __syncthreads();
    for(int k=0;k<16;k++){
      float av[4], wv[4];
      #pragma unroll
      for(int r=0;r<4;r++) av[r]=As[ty*4+r][k];
      #pragma unroll
      for(int c=0;c<4;c++) wv[c]=Ws[tx*4+c][k];
      #pragma unroll
      for(int r=0;r<4;r++)
        #pragma unroll
        for(int c=0;c<4;c++) acc[r][c] += av[r]*wv[c];
    }
    __syncthreads();
  }
  for(int r=0;r<4;r++){
    int row = m0 + ty*4 + r; if(row >= M) continue;
    for(int c=0;c<4;c++){
      int col = n0 + tx*4 + c; if(col >= Nn) continue;
      float v = acc[r][c];
      if(bias && blockIdx.z==0) v += bias[col];
      if(atomic_mode) atomicAdd(&C[(long)row*Nn+col], v);
      else C[(long)row*Nn+col] = v;
    }
  }
}

// ---------------- PI: na[n,a,l,128:256] = sum_nbr E2[nbr,l,h] + B*dh_b[h] ----------------
__global__ void k_pi(const float* __restrict__ e2, const int* __restrict__ nbr,
                     const float* __restrict__ dh_b, float* __restrict__ na){
  int n = blockIdx.x, a = blockIdx.y, h = threadIdx.x; // 128
  __shared__ int nb[KK_-1];
  if(h < KK_-1) nb[h] = nbr[(a*N_+n)*(KK_-1)+h];
  __syncthreads();
  float bias = (float)B_ * dh_b[h];
  for(int l=0;l<L_;l++){
    float s = bias;
    for(int k=0;k<KK_-1;k++) s += e2[(long)(nb[k]*L_ + l)*H_ + h];
    na[((long)(n*ASP_+a)*L_ + l)*H2_ + H_ + h] = s;
  }
}

// ---------------- x: flat reinterpret max over 4 consecutive ----------------
__global__ void k_xmax(const float* __restrict__ na, float* __restrict__ x){
  int i = blockIdx.x*blockDim.x + threadIdx.x;
  if(i >= N_*L_*H2_) return;
  int n = i / (L_*H2_);
  int j = i % (L_*H2_);
  const float* p = &na[(long)n*ASP_*L_*H2_ + 4*j];
  x[i] = fmaxf(fmaxf(p[0],p[1]), fmaxf(p[2],p[3]));
}

// ---------------- LSTM weight permute (fp32, for wih used by xg GEMM) ----------------
__global__ void k_perm(const float* __restrict__ src, float* __restrict__ dst){
  int i = blockIdx.x*blockDim.x + threadIdx.x;
  if(i >= G4_*H2_) return;
  int k = i % H2_; int j = i / H2_;
  int g = j / H2_, jj = j % H2_;
  dst[(jj*4+g)*H2_ + k] = src[i];
}
// ---------------- LSTM recurrent weight permute + bf16 cast ----------------
__global__ void k_permh(const float* __restrict__ src, unsigned short* __restrict__ dst){
  int i = blockIdx.x*blockDim.x + threadIdx.x;
  if(i >= G4_*H2_) return;
  int k = i % H2_; int j = i / H2_;
  int g = j / H2_, jj = j % H2_;
  dst[(jj*4+g)*H2_ + k] = f2b(src[i]);
}
__global__ void k_permb(const float* __restrict__ bih, const float* __restrict__ bhh,
                        float* __restrict__ bp){
  int j = blockIdx.x*blockDim.x + threadIdx.x;
  if(j >= G4_) return;
  int g = j / H2_, jj = j % H2_;
  bp[jj*4+g] = bih[j] + bhh[j];
}

// ---------------- fused LSTM layer, TRANSPOSED MFMA: one launch per layer ----------------
// 16 blocks x 1024 thr (16 waves). Block b owns samples n0=16b..16b+15.
// MFMA computes Whh-tile (A, 16 gate-cols x K) x h (B, 16 samples x K):
// D[row=gate-in-tile=l4*4+r][col=sample=l15]  ->  lane (l15,l4) of tile ct holds
// acc[0..3] = gates (i,f,g,o) of jj=ct*4+l4 for sample l15. No shfl, no divergence,
// c in 4 registers/lane across all 20 steps; xg read as one float4.
__global__ __launch_bounds__(1024) void k_lstm_layer(
    const unsigned short* __restrict__ Whb,   // [1024][256] bf16 permuted (col=jj*4+g)
    const float* __restrict__ xg,             // [256][20][1024] permuted ih products
    float* __restrict__ Y){                   // [256][20][256] fp32 h sequence
  __shared__ unsigned short hs[16*H2_];       // 8 KB, chunk ch=s*32+k/8, swizzled ^(s&7)
  int tid = threadIdx.x;
  int n0 = blockIdx.x * 16;
  int lane = tid & 63, wave = tid >> 6;       // wave 0..15, owns gate tiles wave*4..wave*4+3
  int l15 = lane & 15, l4 = lane >> 4;
  int n = n0 + l15;                            // this lane's sample
  float creg[4] = {0.f,0.f,0.f,0.f};           // c for (sample=l15, jj=wave*16+i*4+l4)
  for(int t=0; t<L_; t++){
    f32x4 acc[4] = {};
    if(t > 0){
      // B-frags: h[sample=l15][k=kk*32+l4*8 ..+8]
      bf16x8 hfr[8];
      #pragma unroll
      for(int kk=0; kk<8; kk++){
        int ch = l15*32 + kk*4 + l4;
        hfr[kk] = *(const bf16x8*)(hs + 8*(ch ^ (l15&7)));
      }
      #pragma unroll
      for(int i=0;i<4;i++){
        int ct = wave*4 + i;
        const unsigned short* wrow = Whb + (size_t)(ct*16 + l15)*H2_ + l4*8;
        #pragma unroll
        for(int kk=0; kk<8; kk++){
          bf16x8 afr = *(const bf16x8*)(wrow + kk*32);
          acc[i] = __builtin_amdgcn_mfma_f32_16x16x32_bf16(afr, hfr[kk], acc[i], 0,0,0);
        }
      }
    }
    __syncthreads();   // all reads of h(t-1) done before overwriting
    #pragma unroll
    for(int i=0;i<4;i++){
      int jj = wave*16 + i*4 + l4;
      const float* xr = &xg[((size_t)n*L_ + t)*G4_ + jj*4];
      float4 x4 = *(const float4*)xr;
      float gi = acc[i][0] + x4.x;
      float gf = acc[i][1] + x4.y;
      float gg = acc[i][2] + x4.z;
      float go = acc[i][3] + x4.w;
      float cnew = sigf(gf)*creg[i] + sigf(gi)*tanhf(gg);
      creg[i] = cnew;
      float hnew = sigf(go)*tanhf(cnew);
      Y[((size_t)n*L_ + t)*H2_ + jj] = hnew;
      int ch = l15*32 + (jj>>3);
      *(unsigned short*)((char*)hs + 16*(ch ^ (l15&7)) + (jj&7)*2) = f2b(hnew);
    }
    __syncthreads();   // h(t) complete before next step's reads
  }
}

// ---------------- h_agg = tanh(sum_t y1) (+ bf16 shadow) ----------------
__global__ void k_hagg(const float* __restrict__ y1, float* __restrict__ hagg,
                       unsigned short* __restrict__ haggb){
  int i = blockIdx.x*blockDim.x + threadIdx.x;
  if(i>=N_*H2_) return;
  int n = i / H2_, jj = i % H2_;
  float s=0.f;
  for(int t=0;t<L_;t++) s += y1[((long)n*L_+t)*H2_ + jj];
  float v = tanhf(s);
  hagg[i] = v;
  haggb[i] = f2b(v);
}

// ---------------- gate ----------------
__global__ void k_gate(const float* __restrict__ uhish, const float* __restrict__ hagg,
                       const float* __restrict__ g1w, const float* __restrict__ g1b,
                       const float* __restrict__ g2w, const float* __restrict__ g2b,
                       float* __restrict__ gate){
  int n = blockIdx.x; int t = threadIdx.x; // 256
  float s = uhish[n*H2_+t]*g1w[t] + hagg[n*H2_+t]*g2w[t];
  __shared__ float red[256];
  red[t]=s; __syncthreads();
  for(int o=128;o>0;o>>=1){ if(t<o) red[t]+=red[t+o]; __syncthreads(); }
  if(t==0) gate[n] = 1.f/(1.f+expf(-(red[0]+g1b[0]+g2b[0])));
}

// ---------------- softmax row stats ----------------
__global__ void k_smstat(const float* __restrict__ logits, float* __restrict__ rowmax,
                         float* __restrict__ rowsum){
  int n = blockIdx.x; int t = threadIdx.x;
  const float* row = &logits[(long)n*NIT_];
  float m = -3.4e38f;
  for(int i=t;i<NIT_;i+=256) m = fmaxf(m, row[i]);
  __shared__ float red[256];
  __shared__ float mm;
  red[t]=m; __syncthreads();
  for(int o=128;o>0;o>>=1){ if(t<o) red[t]=fmaxf(red[t],red[t+o]); __syncthreads(); }
  if(t==0){ mm = red[0]; rowmax[n]=red[0]; }
  __syncthreads();
  float s=0.f;
  for(int i=t;i<NIT_;i+=256) s += expf(row[i]-mm);
  __syncthreads();
  red[t]=s; __syncthreads();
  for(int o=128;o>0;o>>=1){ if(t<o) red[t]+=red[t+o]; __syncthreads(); }
  if(t==0) rowsum[n]=red[0];
}

// ---------------- final ----------------
__global__ void k_final(const float* __restrict__ logits, const float* __restrict__ rowmax,
                        const float* __restrict__ rowsum, const float* __restrict__ gate,
                        const float* __restrict__ uHis, float* __restrict__ out){
  int i = blockIdx.x*blockDim.x + threadIdx.x;
  if(i >= N_*NIT_) return;
  int n = i / NIT_;
  float g = gate[n];
  float p = expf(logits[i]-rowmax[n]) / rowsum[n];
  out[i] = g*p + (1.f-g)*uHis[i];
}

extern "C" void kernel_launch(void* const* d_in, const int* in_sizes, int n_in,
                              void* d_out, int out_size, void* d_ws, size_t ws_size,
                              hipStream_t stream) {
  const int*   seq     = (const int*)  d_in[0];
  const float* uHis    = (const float*)d_in[1];
  const float* itemEmb = (const float*)d_in[2];
  const float* fc1_w   = (const float*)d_in[3];
  const float* fc1_b   = (const float*)d_in[4];
  const float* aspProju= (const float*)d_in[5];
  const float* aspProji= (const float*)d_in[6];
  const float* dh_w    = (const float*)d_in[7];
  const float* dh_b    = (const float*)d_in[8];
  const float* wih0    = (const float*)d_in[9];
  const float* whh0    = (const float*)d_in[10];
  const float* bih0    = (const float*)d_in[11];
  const float* bhh0    = (const float*)d_in[12];
  const float* wih1    = (const float*)d_in[13];
  const float* whh1    = (const float*)d_in[14];
  const float* bih1    = (const float*)d_in[15];
  const float* bhh1    = (const float*)d_in[16];
  const float* out_w   = (const float*)d_in[17];
  const float* out_b   = (const float*)d_in[18];
  const float* his_w   = (const float*)d_in[19];
  const float* his_b   = (const float*)d_in[20];
  const float* g1_w    = (const float*)d_in[21];
  const float* g1_b    = (const float*)d_in[22];
  const float* g2_w    = (const float*)d_in[23];
  const float* g2_b    = (const float*)d_in[24];

  float* ws = (float*)d_ws;
  float* embs = ws + 0;            // 6,553,600   (reused as logits later)
  float* cub  = ws + 6553600;      // 6,553,600   (ebh bf16 shadow; reused as xg later)
  float* na   = ws + 13107200;     // 5,242,880   (reused as outwb bf16 after xmax)
  float* x    = ws + 18350080;     // 1,310,720   (reused as haggb after xg0)
  float* y0   = ws + 19660800;     // 1,310,720
  float* y1   = ws + 20971520;     // 1,310,720
  float* eb   = ws + 22282240;     //   655,360
  float* e2   = ws + 22937600;     //   655,360
  float* dist = ws + 23592960;     //   262,144
  float* ua   = ws + 23855104;     //   131,072
  float* projT= ws + 23986176;     //    65,536  (holds projb bf16)
  float* wp0  = ws + 24051712;     //   262,144  (fp32 permuted wih0)
  float* whp0 = ws + 24313856;     //   262,144  (bf16 permuted whh0 lives here)
  float* wp1  = ws + 24576000;     //   262,144  (fp32 permuted wih1)
  float* whp1 = ws + 24838144;     //   262,144  (bf16 permuted whh1 lives here)
  float* bp0  = ws + 25100288;     //     1,024
  float* bp1  = ws + 25101312;     //     1,024
  float* uemb = ws + 25167872;     //       256
  float* sqb  = ws + 25168128;     //     1,024
  int*   nbr  = (int*)(ws + 25169152); // 15,360 ints
  float* uhish= ws + 25184512;     //    65,536
  float* hagg = ws + 25250048;     //    65,536
  float* rowmax=ws + 25315584;     //       256
  float* rowsum=ws + 25315840;     //       256
  float* gateb =ws + 25316096;     //       256
  float* logits = embs;            // reuse
  float* xg = cub;                 // reuse (ebh dead after k_uimm)
  unsigned short* ebh   = (unsigned short*)cub;   // bf16 shadow (inside cub slot)
  unsigned short* projb = (unsigned short*)projT; // bf16 (inside projT slot)
  unsigned short* outwb = (unsigned short*)na;    // bf16 out_w (na dead after xmax)
  unsigned short* haggb = (unsigned short*)x;     // bf16 hagg (x dead after xg0)
  unsigned short* whb0  = (unsigned short*)whp0;  // bf16 permuted whh0
  unsigned short* whb1  = (unsigned short*)whp1;  // bf16 permuted whh1

  // 1. embedding gather (fp32 + bf16 shadow)
  k_gather<<<NLB_, D_, 0, stream>>>(seq, itemEmb, embs, ebh);
  // 2. fc1 -> u_embs
  k_fc1<<<N_, 256, 0, stream>>>(embs, fc1_w, fc1_b, uemb);
  // 3. uA
  k_ua<<<(ASP_*N_*H_+255)/256, 256, 0, stream>>>(uemb, aspProju, ua);
  // 4. sq
  k_sq<<<ASP_*N_, 128, 0, stream>>>(ua, sqb);
  // 5. dist
  k_dist<<<dim3(N_,ASP_), 256, 0, stream>>>(ua, sqb, dist);
  // 6. top-k neighbors
  k_topk<<<ASP_*N_/4, 256, 0, stream>>>(dist, nbr);
  // 7. EB = sum_b embs
  k_eb<<<NL_, D_, 0, stream>>>(embs, eb);
  // 8. E2 = EB @ dh_w^T
  k_gemm<<<dim3(2, 80, 1), 256, 0, stream>>>(eb, dh_w, e2, nullptr, NL_, H_, D_, D_, 0);
  // 9. projb (bf16 transposed proj)
  k_projb<<<(ASP_*D_*H_+255)/256, 256, 0, stream>>>(aspProji, projb);
  // 10. fused UI stage: MFMA + tanh^2 + sum_b
  k_uimm<<<dim3(NL_/8, ASP_), 256, 0, stream>>>(ebh, projb, na);
  // 11. PI (neighbor sums)
  k_pi<<<dim3(N_,ASP_), H_, 0, stream>>>(e2, nbr, dh_b, na);
  // 12. x = flat max-4
  k_xmax<<<(N_*L_*H2_+255)/256, 256, 0, stream>>>(na, x);
  // 12b. cast out_w -> bf16 (into dead na region)
  k_outb<<<2500, 256, 0, stream>>>(out_w, outwb);
  // 13. LSTM weight permutes: wih fp32, whh bf16
  k_perm <<<(G4_*H2_+255)/256,256,0,stream>>>(wih0, wp0);
  k_permh<<<(G4_*H2_+255)/256,256,0,stream>>>(whh0, whb0);
  k_perm <<<(G4_*H2_+255)/256,256,0,stream>>>(wih1, wp1);
  k_permh<<<(G4_*H2_+255)/256,256,0,stream>>>(whh1, whb1);
  k_permb<<<4,256,0,stream>>>(bih0,bhh0,bp0);
  k_permb<<<4,256,0,stream>>>(bih1,bhh1,bp1);
  // 14. xg0 = x @ wp0^T + bp0
  k_gemm<<<dim3(16,80,1),256,0,stream>>>(x, wp0, xg, bp0, NL_, G4_, H2_, H2_, 0);
  // 15. LSTM layer 0: ONE launch, 20 steps, transposed MFMA epilogue
  k_lstm_layer<<<16, 1024, 0, stream>>>(whb0, xg, y0);
  // 16. xg1 = y0 @ wp1^T + bp1
  k_gemm<<<dim3(16,80,1),256,0,stream>>>(y0, wp1, xg, bp1, NL_, G4_, H2_, H2_, 0);
  // 17. LSTM layer 1
  k_lstm_layer<<<16, 1024, 0, stream>>>(whb1, xg, y1);
  // 18. h_agg (+ bf16 shadow into dead x region)
  k_hagg<<<(N_*H2_+255)/256,256,0,stream>>>(y1, hagg, haggb);
  // 19. logits = h_agg @ out_w^T + out_b : bf16 MFMA (grid 625, tile 256x32)
  k_logitsmm<<<625, 256, 0, stream>>>(haggb, outwb, out_b, logits);
  // 20. uHis_h = uHis @ his_w^T + his_b : bf16 MFMA split-K
  hipMemsetAsync(uhish, 0, N_*H2_*sizeof(float), stream);
  k_uhismm<<<dim3(4,4,25), 256, 0, stream>>>(uHis, his_w, his_b, uhish);
  // 21. gate
  k_gate<<<N_,256,0,stream>>>(uhish, hagg, g1_w, g1_b, g2_w, g2_b, gateb);
  // 22. softmax stats
  k_smstat<<<N_,256,0,stream>>>(logits, rowmax, rowsum);
  // 23. final scores
  k_final<<<(N_*NIT_+255)/256,256,0,stream>>>(logits, rowmax, rowsum, gateb, uHis, (float*)d_out);
}

// Round 11
// 744.263 us; speedup vs baseline: 2.0837x; 1.1397x over previous
//
#include <hip/hip_runtime.h>
#include <math.h>

#define N_ 256
#define L_ 20
#define B_ 10
#define D_ 128
#define H_ 128
#define ASP_ 4
#define KK_ 16
#define NIT_ 20000
#define H2_ 256
#define G4_ 1024
#define LBD_ 25600
#define NL_ 5120
#define NLB_ 51200

typedef __attribute__((ext_vector_type(8))) short bf16x8;
typedef __attribute__((ext_vector_type(4))) float f32x4;

__device__ __forceinline__ float sigf(float x){ return 1.0f/(1.0f+expf(-x)); }
// hardware-exp fast activations: v_exp_f32 + v_rcp_f32, saturate correctly at +-inf
__device__ __forceinline__ float sigf_fast(float x){
  return __builtin_amdgcn_rcpf(1.0f + __expf(-x));
}
__device__ __forceinline__ float tanh_fast(float x){
  return 1.0f - 2.0f*__builtin_amdgcn_rcpf(__expf(2.0f*x) + 1.0f);
}
__device__ __forceinline__ unsigned short f2b(float f){
  unsigned int u = __float_as_uint(f);
  unsigned int r = (u + 0x7FFFu + ((u>>16)&1u)) >> 16;   // RNE
  return (unsigned short)r;
}

// ---------------- gather: embs[n,l,b,:] = itemEmb[seq[n,l,b],:] (+ bf16 shadow) ----------------
__global__ void k_gather(const int* __restrict__ seq, const float* __restrict__ itemEmb,
                         float* __restrict__ embs, unsigned short* __restrict__ ebh){
  int row = blockIdx.x;          // 0..51199 = (n,l,b)
  int t = threadIdx.x;           // 0..127
  int idx = seq[row];
  float v = itemEmb[idx*D_ + t];
  embs[row*D_ + t] = v;
  ebh[row*D_ + t] = f2b(v);
}

// ---------------- fc1: u[n] = dot(embs[n,:], fc1_w) + fc1_b ----------------
__global__ void k_fc1(const float* __restrict__ embs, const float* __restrict__ w,
                      const float* __restrict__ b, float* __restrict__ u){
  int n = blockIdx.x; int t = threadIdx.x;
  float s = 0.f;
  for (int i = t; i < LBD_; i += 256) s += embs[n*LBD_+i]*w[i];
  __shared__ float red[256];
  red[t]=s; __syncthreads();
  for (int o=128;o>0;o>>=1){ if(t<o) red[t]+=red[t+o]; __syncthreads(); }
  if(t==0) u[n]=red[0]+b[0];
}

// ---------------- uA[a,n,h] = tanh(tanh(u[n]*proju[a,h])) ----------------
// NOTE: keep libm tanh here — feeds kNN selection (keep selection bit-stable)
__global__ void k_ua(const float* __restrict__ u, const float* __restrict__ proju,
                     float* __restrict__ ua){
  int i = blockIdx.x*blockDim.x + threadIdx.x;
  if(i >= ASP_*N_*H_) return;
  int h = i % H_; int n = (i/H_) % N_; int a = i/(H_*N_);
  ua[i] = tanhf(tanhf(u[n]*proju[a*H_+h]));
}

// ---------------- sq[a,n] = sum_h uA^2 ----------------
__global__ void k_sq(const float* __restrict__ ua, float* __restrict__ sq){
  int an = blockIdx.x; int t = threadIdx.x;   // 128 threads
  float v = ua[an*H_ + t]; v *= v;
  __shared__ float red[128];
  red[t]=v; __syncthreads();
  for(int o=64;o>0;o>>=1){ if(t<o) red[t]+=red[t+o]; __syncthreads(); }
  if(t==0) sq[an]=red[0];
}

// ---------------- dist[a,n,m] ----------------
__global__ void k_dist(const float* __restrict__ ua, const float* __restrict__ sq,
                       float* __restrict__ dist){
  int n = blockIdx.x, a = blockIdx.y, m = threadIdx.x;  // 256 threads
  __shared__ float un[H_];
  if(m < H_) un[m] = ua[(a*N_+n)*H_ + m];
  __syncthreads();
  const float* um = &ua[(a*N_+m)*H_];
  float dot=0.f;
  for(int h=0;h<H_;h++) dot += un[h]*um[h];
  float dval = sq[a*N_+n] + sq[a*N_+m] - 2.f*dot;
  if(m==n) dval = -1.0f;
  dist[(a*N_+n)*N_ + m] = dval;
}

// ---------------- top-16 smallest, wave-parallel: 1 wave per (a,n) row ----------------
__global__ __launch_bounds__(256) void k_topk(const float* __restrict__ dist, int* __restrict__ nbr){
  int wid = blockIdx.x*(blockDim.x>>6) + (threadIdx.x>>6);  // row = (a*N_+n)
  if(wid >= ASP_*N_) return;
  int lane = threadIdx.x & 63;
  const float* row = &dist[(long)wid*N_];
  float v[4]; int idx[4];
  #pragma unroll
  for(int j=0;j<4;j++){ int m = lane*4 + j; v[j] = row[m]; idx[j] = m; }
  for(int k=0;k<KK_;k++){
    float bv = v[0]; int bi = idx[0];
    #pragma unroll
    for(int j=1;j<4;j++)
      if(v[j] < bv || (v[j]==bv && idx[j] < bi)){ bv=v[j]; bi=idx[j]; }
    float rv = bv; int ri = bi;
    #pragma unroll
    for(int o=32;o>0;o>>=1){
      float ov = __shfl_xor(rv, o, 64);
      int   oi = __shfl_xor(ri, o, 64);
      if(ov < rv || (ov==rv && oi < ri)){ rv=ov; ri=oi; }
    }
    if((ri>>2) == lane){ v[ri&3] = 3.4e38f; idx[ri&3] = 0x7fffffff; }
    if(k>0 && lane==0) nbr[wid*(KK_-1)+(k-1)] = ri;
  }
}

// ---------------- EB[n,l,d] = sum_b embs ----------------
__global__ void k_eb(const float* __restrict__ embs, float* __restrict__ eb){
  int nl = blockIdx.x; int d = threadIdx.x;
  float s=0.f;
  const float* p = &embs[nl*B_*D_ + d];
  for(int b=0;b<B_;b++) s += p[b*D_];
  eb[nl*D_ + d] = s;
}

// ---------------- projb[a,h,d] = bf16(aspProji[a,d,h]) ----------------
__global__ void k_projb(const float* __restrict__ proji, unsigned short* __restrict__ projb){
  int i = blockIdx.x*blockDim.x + threadIdx.x;
  if(i>=ASP_*D_*H_) return;
  int h=i%H_, d=(i/H_)%D_, a=i/(D_*H_);
  projb[(a*H_ + h)*D_ + d] = f2b(proji[i]);
}

// ---------------- fused UI stage: MFMA bf16 GEMM + tanh^2 + sum_b -> na[.., 0:128] ----------------
__global__ __launch_bounds__(256) void k_uimm(const unsigned short* __restrict__ ebh,
                                              const unsigned short* __restrict__ projb,
                                              float* __restrict__ na){
  __shared__ char smem[53248];
  unsigned short* As = (unsigned short*)smem;            // 80x128 bf16, swizzled 16B chunks
  unsigned short* Bs = (unsigned short*)(smem + 20480);  // 128x128 bf16, swizzled
  float*          Cs = (float*)smem;                     // 80x128 f32 (aliases As+Bs later)

  int mb = blockIdx.x;   // 0..639  -> nl0 = mb*8, A rows r0 = mb*80
  int a  = blockIdx.y;   // 0..3
  int tid = threadIdx.x;

  const unsigned short* asrc = ebh + (size_t)mb*10240;
  #pragma unroll
  for(int t=0;t<5;t++){
    int c = tid + t*256;
    int row = c >> 4;
    *(bf16x8*)(As + 8*(c ^ (row&7))) = *(const bf16x8*)(asrc + 8*c);
  }
  const unsigned short* bsrc = projb + a*16384;
  #pragma unroll
  for(int t=0;t<8;t++){
    int c = tid + t*256;
    int row = c >> 4;
    *(bf16x8*)(Bs + 8*(c ^ (row&7))) = *(const bf16x8*)(bsrc + 8*c);
  }
  __syncthreads();

  int lane = tid & 63, wave = tid >> 6;
  int l15 = lane & 15, l4 = lane >> 4;
  f32x4 acc[5][2] = {};
  #pragma unroll
  for(int kk=0;kk<4;kk++){
    bf16x8 bfr[2];
    #pragma unroll
    for(int tc=0;tc<2;tc++){
      int h = (wave*2+tc)*16 + l15;
      int c = h*16 + kk*4 + l4;
      bfr[tc] = *(const bf16x8*)(Bs + 8*(c ^ (h&7)));
    }
    #pragma unroll
    for(int tr=0;tr<5;tr++){
      int R = tr*16 + l15;
      int c = R*16 + kk*4 + l4;
      bf16x8 afr = *(const bf16x8*)(As + 8*(c ^ (R&7)));
      acc[tr][0] = __builtin_amdgcn_mfma_f32_16x16x32_bf16(afr, bfr[0], acc[tr][0], 0,0,0);
      acc[tr][1] = __builtin_amdgcn_mfma_f32_16x16x32_bf16(afr, bfr[1], acc[tr][1], 0,0,0);
    }
  }
  __syncthreads();

  #pragma unroll
  for(int tr=0;tr<5;tr++)
    #pragma unroll
    for(int tc=0;tc<2;tc++){
      int col = (wave*2+tc)*16 + l15;
      #pragma unroll
      for(int r=0;r<4;r++){
        int R = tr*16 + l4*4 + r;
        Cs[R*128 + col] = tanh_fast(tanh_fast(acc[tr][tc][r]));
      }
    }
  __syncthreads();

  #pragma unroll
  for(int t=0;t<4;t++){
    int oi = t*256 + tid;
    int g = oi >> 7, col = oi & 127;
    float s = 0.f;
    const float* p = Cs + g*1280 + col;
    #pragma unroll
    for(int b=0;b<10;b++) s += p[b*128];
    int nl = mb*8 + g;
    int n = nl/L_, l = nl%L_;
    na[((size_t)(n*ASP_+a)*L_ + l)*H2_ + col] = s;
  }
}

// ---------------- uHis_h: bf16 MFMA split-K (grid 4x4x25) ----------------
__global__ __launch_bounds__(256) void k_uhismm(const float* __restrict__ U,
    const float* __restrict__ W, const float* __restrict__ bias, float* __restrict__ C){
  __shared__ unsigned short As[2048];   // 64 rows x 32 k, chunk = q*64+row (8 bf16 each)
  __shared__ unsigned short Bs[2048];
  int tid = threadIdx.x;
  int m0 = blockIdx.y*64, n0 = blockIdx.x*64;
  int kb0 = blockIdx.z*800;
  int row = tid & 63, q = tid >> 6;
  int lane = tid & 63, wave = tid >> 6;
  int l15 = lane & 15, l4 = lane >> 4;
  int wr = (wave>>1)*32, wc = (wave&1)*32;
  f32x4 acc[2][2] = {};
  for(int s=0;s<25;s++){
    int k0 = kb0 + s*32 + q*8;
    {
      const float* pa = &U[(size_t)(m0+row)*NIT_ + k0];
      float4 a0 = *(const float4*)pa, a1 = *(const float4*)(pa+4);
      bf16x8 av;
      av[0]=f2b(a0.x); av[1]=f2b(a0.y); av[2]=f2b(a0.z); av[3]=f2b(a0.w);
      av[4]=f2b(a1.x); av[5]=f2b(a1.y); av[6]=f2b(a1.z); av[7]=f2b(a1.w);
      *(bf16x8*)(As + 8*tid) = av;
      const float* pb = &W[(size_t)(n0+row)*NIT_ + k0];
      float4 b0 = *(const float4*)pb, b1 = *(const float4*)(pb+4);
      bf16x8 bv;
      bv[0]=f2b(b0.x); bv[1]=f2b(b0.y); bv[2]=f2b(b0.z); bv[3]=f2b(b0.w);
      bv[4]=f2b(b1.x); bv[5]=f2b(b1.y); bv[6]=f2b(b1.z); bv[7]=f2b(b1.w);
      *(bf16x8*)(Bs + 8*tid) = bv;
    }
    __syncthreads();
    bf16x8 afr[2], bfr[2];
    #pragma unroll
    for(int mt=0;mt<2;mt++) afr[mt] = *(const bf16x8*)(As + 8*(l4*64 + wr + mt*16 + l15));
    #pragma unroll
    for(int nt=0;nt<2;nt++) bfr[nt] = *(const bf16x8*)(Bs + 8*(l4*64 + wc + nt*16 + l15));
    #pragma unroll
    for(int mt=0;mt<2;mt++)
      #pragma unroll
      for(int nt=0;nt<2;nt++)
        acc[mt][nt] = __builtin_amdgcn_mfma_f32_16x16x32_bf16(afr[mt], bfr[nt], acc[mt][nt], 0,0,0);
    __syncthreads();
  }
  #pragma unroll
  for(int mt=0;mt<2;mt++)
    #pragma unroll
    for(int nt=0;nt<2;nt++){
      int col = n0 + wc + nt*16 + l15;
      #pragma unroll
      for(int r=0;r<4;r++){
        int rw = m0 + wr + mt*16 + l4*4 + r;
        float v = acc[mt][nt][r];
        if(blockIdx.z==0) v += bias[col];
        atomicAdd(&C[rw*H2_ + col], v);
      }
    }
}

// ---------------- xg GEMM: bf16 MFMA, in-register cast, M=5120 N=1024 K=256 ----------------
// Same verified stage/fragment layout as k_uhismm; kb0=0, 8 stages, direct store + bias.
__global__ __launch_bounds__(256) void k_xgmm(const float* __restrict__ A_,
    const float* __restrict__ W, const float* __restrict__ bias, float* __restrict__ C){
  __shared__ unsigned short As[2048];
  __shared__ unsigned short Bs[2048];
  int tid = threadIdx.x;
  int n0 = blockIdx.x*64, m0 = blockIdx.y*64;
  int row = tid & 63, q = tid >> 6;
  int lane = tid & 63, wave = tid >> 6;
  int l15 = lane & 15, l4 = lane >> 4;
  int wr = (wave>>1)*32, wc = (wave&1)*32;
  f32x4 acc[2][2] = {};
  for(int s=0;s<8;s++){
    int k0 = s*32 + q*8;
    {
      const float* pa = &A_[(size_t)(m0+row)*H2_ + k0];
      float4 a0 = *(const float4*)pa, a1 = *(const float4*)(pa+4);
      bf16x8 av;
      av[0]=f2b(a0.x); av[1]=f2b(a0.y); av[2]=f2b(a0.z); av[3]=f2b(a0.w);
      av[4]=f2b(a1.x); av[5]=f2b(a1.y); av[6]=f2b(a1.z); av[7]=f2b(a1.w);
      *(bf16x8*)(As + 8*tid) = av;
      const float* pb = &W[(size_t)(n0+row)*H2_ + k0];
      float4 b0 = *(const float4*)pb, b1 = *(const float4*)(pb+4);
      bf16x8 bv;
      bv[0]=f2b(b0.x); bv[1]=f2b(b0.y); bv[2]=f2b(b0.z); bv[3]=f2b(b0.w);
      bv[4]=f2b(b1.x); bv[5]=f2b(b1.y); bv[6]=f2b(b1.z); bv[7]=f2b(b1.w);
      *(bf16x8*)(Bs + 8*tid) = bv;
    }
    __syncthreads();
    bf16x8 afr[2], bfr[2];
    #pragma unroll
    for(int mt=0;mt<2;mt++) afr[mt] = *(const bf16x8*)(As + 8*(l4*64 + wr + mt*16 + l15));
    #pragma unroll
    for(int nt=0;nt<2;nt++) bfr[nt] = *(const bf16x8*)(Bs + 8*(l4*64 + wc + nt*16 + l15));
    #pragma unroll
    for(int mt=0;mt<2;mt++)
      #pragma unroll
      for(int nt=0;nt<2;nt++)
        acc[mt][nt] = __builtin_amdgcn_mfma_f32_16x16x32_bf16(afr[mt], bfr[nt], acc[mt][nt], 0,0,0);
    __syncthreads();
  }
  #pragma unroll
  for(int mt=0;mt<2;mt++)
    #pragma unroll
    for(int nt=0;nt<2;nt++){
      int col = n0 + wc + nt*16 + l15;
      float bs = bias[col];
      #pragma unroll
      for(int r=0;r<4;r++){
        int rw = m0 + wr + mt*16 + l4*4 + r;
        C[(size_t)rw*G4_ + col] = acc[mt][nt][r] + bs;
      }
    }
}

// ---------------- cast out_w -> bf16 ----------------
__global__ void k_outb(const float* __restrict__ w, unsigned short* __restrict__ wb){
  int i = blockIdx.x*blockDim.x + threadIdx.x;   // 640000 threads, 8 elems each
  const float* p = w + (size_t)i*8;
  float4 a = *(const float4*)p, b = *(const float4*)(p+4);
  bf16x8 v;
  v[0]=f2b(a.x); v[1]=f2b(a.y); v[2]=f2b(a.z); v[3]=f2b(a.w);
  v[4]=f2b(b.x); v[5]=f2b(b.y); v[6]=f2b(b.z); v[7]=f2b(b.w);
  *(bf16x8*)(wb + (size_t)i*8) = v;
}

// ---------------- logits: bf16 MFMA, tile 256x32, grid 625, frags straight from L2 ----------------
__global__ __launch_bounds__(256) void k_logitsmm(const unsigned short* __restrict__ Ab,
    const unsigned short* __restrict__ Wb, const float* __restrict__ bias,
    float* __restrict__ C){
  int n0 = blockIdx.x*32;
  int tid = threadIdx.x;
  int lane = tid & 63, wave = tid >> 6;
  int l15 = lane & 15, l4 = lane >> 4;
  f32x4 acc[4][2] = {};
  #pragma unroll
  for(int kk=0;kk<8;kk++){
    int k0 = kk*32 + l4*8;
    bf16x8 bfr[2];
    #pragma unroll
    for(int nt=0;nt<2;nt++)
      bfr[nt] = *(const bf16x8*)(Wb + (size_t)(n0 + nt*16 + l15)*H2_ + k0);
    #pragma unroll
    for(int mt=0;mt<4;mt++){
      bf16x8 afr = *(const bf16x8*)(Ab + (size_t)(wave*64 + mt*16 + l15)*H2_ + k0);
      acc[mt][0] = __builtin_amdgcn_mfma_f32_16x16x32_bf16(afr, bfr[0], acc[mt][0], 0,0,0);
      acc[mt][1] = __builtin_amdgcn_mfma_f32_16x16x32_bf16(afr, bfr[1], acc[mt][1], 0,0,0);
    }
  }
  #pragma unroll
  for(int mt=0;mt<4;mt++)
    #pragma unroll
    for(int nt=0;nt<2;nt++){
      int col = n0 + nt*16 + l15;
      float bs = bias[col];
      #pragma unroll
      for(int r=0;r<4;r++){
        int row = wave*64 + mt*16 + l4*4 + r;
        C[(size_t)row*NIT_ + col] = acc[mt][nt][r] + bs;
      }
    }
}

// ---------------- generic fp32 NT GEMM (E2 only now) ----------------
__global__ __launch_bounds__(256) void k_gemm(const float* __restrict__ A, const float* __restrict__ W,
    float* __restrict__ C, const float* __restrict__ bias,
    int M, int Nn, int K, int kchunk, int atomic_mode){
  __shared__ float As[64][17];
  __shared__ float Ws[64][17];
  int tid = threadIdx.x;
  int tx = tid & 15, ty = tid >> 4;
  int m0 = blockIdx.y*64, n0 = blockIdx.x*64;
  int kb0 = blockIdx.z*kchunk;
  int kend = kb0 + kchunk; if(kend > K) kend = K;
  float acc[4][4] = {};
  int lrow = tid >> 2;
  int lc4 = (tid & 3) * 4;
  for(int kb = kb0; kb < kend; kb += 16){
    {
      int gr = m0 + lrow;
      float4 v = make_float4(0,0,0,0);
      if(gr < M) v = *(const float4*)&A[(long)gr*K + kb + lc4];
      As[lrow][lc4+0]=v.x; As[lrow][lc4+1]=v.y; As[lrow][lc4+2]=v.z; As[lrow][lc4+3]=v.w;
      int gw = n0 + lrow;
      float4 u = make_float4(0,0,0,0);
      if(gw < Nn) u = *(const float4*)&W[(long)gw*K + kb + lc4];
      Ws[lrow][lc4+0]=u.x; Ws[lrow][lc4+1]=u.y; Ws[lrow][lc4+2]=u.z; Ws[lrow][lc4+3]=u.w;
    }
    __syncthreads();
    for(int k=0;k<16;k++){
      float av[4], wv[4];
      #pragma unroll
      for(int r=0;r<4;r++) av[r]=As[ty*4+r][k];
      #pragma unroll
      for(int c=0;c<4;c++) wv[c]=Ws[tx*4+c][k];
      #pragma unroll
      for(int r=0;r<4;r++)
        #pragma unroll
        for(int c=0;c<4;c++) acc[r][c] += av[r]*wv[c];
    }
    __syncthreads();
  }
  for(int r=0;r<4;r++){
    int row = m0 + ty*4 + r; if(row >= M) continue;
    for(int c=0;c<4;c++){
      int col = n0 + tx*4 + c; if(col >= Nn) continue;
      float v = acc[r][c];
      if(bias && blockIdx.z==0) v += bias[col];
      if(atomic_mode) atomicAdd(&C[(long)row*Nn+col], v);
      else C[(long)row*Nn+col] = v;
    }
  }
}

// ---------------- PI: na[n,a,l,128:256] = sum_nbr E2[nbr,l,h] + B*dh_b[h] ----------------
__global__ void k_pi(const float* __restrict__ e2, const int* __restrict__ nbr,
                     const float* __restrict__ dh_b, float* __restrict__ na){
  int n = blockIdx.x, a = blockIdx.y, h = threadIdx.x; // 128
  __shared__ int nb[KK_-1];
  if(h < KK_-1) nb[h] = nbr[(a*N_+n)*(KK_-1)+h];
  __syncthreads();
  float bias = (float)B_ * dh_b[h];
  for(int l=0;l<L_;l++){
    float s = bias;
    for(int k=0;k<KK_-1;k++) s += e2[(long)(nb[k]*L_ + l)*H_ + h];
    na[((long)(n*ASP_+a)*L_ + l)*H2_ + H_ + h] = s;
  }
}

// ---------------- x: flat reinterpret max over 4 consecutive ----------------
__global__ void k_xmax(const float* __restrict__ na, float* __restrict__ x){
  int i = blockIdx.x*blockDim.x + threadIdx.x;
  if(i >= N_*L_*H2_) return;
  int n = i / (L_*H2_);
  int j = i % (L_*H2_);
  const float* p = &na[(long)n*ASP_*L_*H2_ + 4*j];
  x[i] = fmaxf(fmaxf(p[0],p[1]), fmaxf(p[2],p[3]));
}

// ---------------- LSTM weight permute (fp32, for wih used by xg GEMM) ----------------
__global__ void k_perm(const float* __restrict__ src, float* __restrict__ dst){
  int i = blockIdx.x*blockDim.x + threadIdx.x;
  if(i >= G4_*H2_) return;
  int k = i % H2_; int j = i / H2_;
  int g = j / H2_, jj = j % H2_;
  dst[(jj*4+g)*H2_ + k] = src[i];
}
// ---------------- LSTM recurrent weight permute + bf16 cast ----------------
__global__ void k_permh(const float* __restrict__ src, unsigned short* __restrict__ dst){
  int i = blockIdx.x*blockDim.x + threadIdx.x;
  if(i >= G4_*H2_) return;
  int k = i % H2_; int j = i / H2_;
  int g = j / H2_, jj = j % H2_;
  dst[(jj*4+g)*H2_ + k] = f2b(src[i]);
}
__global__ void k_permb(const float* __restrict__ bih, const float* __restrict__ bhh,
                        float* __restrict__ bp){
  int j = blockIdx.x*blockDim.x + threadIdx.x;
  if(j >= G4_) return;
  int g = j / H2_, jj = j % H2_;
  bp[jj*4+g] = bih[j] + bhh[j];
}

// ---------------- fused LSTM layer, TRANSPOSED MFMA: one launch per layer ----------------
// 16 blocks x 1024 thr (16 waves). Block b owns samples n0=16b..16b+15.
// D[row=gate-in-tile][col=sample] -> lane holds the full (i,f,g,o) quad of one jj,
// one sample. c in registers; fast HW-exp activations in the epilogue.
__global__ __launch_bounds__(1024) void k_lstm_layer(
    const unsigned short* __restrict__ Whb,   // [1024][256] bf16 permuted (col=jj*4+g)
    const float* __restrict__ xg,             // [256][20][1024] permuted ih products
    float* __restrict__ Y){                   // [256][20][256] fp32 h sequence
  __shared__ unsigned short hs[16*H2_];       // 8 KB, chunk ch=s*32+k/8, swizzled ^(s&7)
  int tid = threadIdx.x;
  int n0 = blockIdx.x * 16;
  int lane = tid & 63, wave = tid >> 6;       // wave 0..15, owns gate tiles wave*4..wave*4+3
  int l15 = lane & 15, l4 = lane >> 4;
  int n = n0 + l15;                            // this lane's sample
  float creg[4] = {0.f,0.f,0.f,0.f};           // c for (sample=l15, jj=wave*16+i*4+l4)
  for(int t=0; t<L_; t++){
    f32x4 acc[4] = {};
    if(t > 0){
      bf16x8 hfr[8];
      #pragma unroll
      for(int kk=0; kk<8; kk++){
        int ch = l15*32 + kk*4 + l4;
        hfr[kk] = *(const bf16x8*)(hs + 8*(ch ^ (l15&7)));
      }
      #pragma unroll
      for(int i=0;i<4;i++){
        int ct = wave*4 + i;
        const unsigned short* wrow = Whb + (size_t)(ct*16 + l15)*H2_ + l4*8;
        #pragma unroll
        for(int kk=0; kk<8; kk++){
          bf16x8 afr = *(const bf16x8*)(wrow + kk*32);
          acc[i] = __builtin_amdgcn_mfma_f32_16x16x32_bf16(afr, hfr[kk], acc[i], 0,0,0);
        }
      }
    }
    __syncthreads();   // all reads of h(t-1) done before overwriting
    #pragma unroll
    for(int i=0;i<4;i++){
      int jj = wave*16 + i*4 + l4;
      const float* xr = &xg[((size_t)n*L_ + t)*G4_ + jj*4];
      float4 x4 = *(const float4*)xr;
      float gi = acc[i][0] + x4.x;
      float gf = acc[i][1] + x4.y;
      float gg = acc[i][2] + x4.z;
      float go = acc[i][3] + x4.w;
      float cnew = sigf_fast(gf)*creg[i] + sigf_fast(gi)*tanh_fast(gg);
      creg[i] = cnew;
      float hnew = sigf_fast(go)*tanh_fast(cnew);
      Y[((size_t)n*L_ + t)*H2_ + jj] = hnew;
      int ch = l15*32 + (jj>>3);
      *(unsigned short*)((char*)hs + 16*(ch ^ (l15&7)) + (jj&7)*2) = f2b(hnew);
    }
    __syncthreads();   // h(t) complete before next step's reads
  }
}

// ---------------- h_agg = tanh(sum_t y1) (+ bf16 shadow) ----------------
__global__ void k_hagg(const float* __restrict__ y1, float* __restrict__ hagg,
                       unsigned short* __restrict__ haggb){
  int i = blockIdx.x*blockDim.x + threadIdx.x;
  if(i>=N_*H2_) return;
  int n = i / H2_, jj = i % H2_;
  float s=0.f;
  for(int t=0;t<L_;t++) s += y1[((long)n*L_+t)*H2_ + jj];
  float v = tanhf(s);
  hagg[i] = v;
  haggb[i] = f2b(v);
}

// ---------------- gate ----------------
__global__ void k_gate(const float* __restrict__ uhish, const float* __restrict__ hagg,
                       const float* __restrict__ g1w, const float* __restrict__ g1b,
                       const float* __restrict__ g2w, const float* __restrict__ g2b,
                       float* __restrict__ gate){
  int n = blockIdx.x; int t = threadIdx.x; // 256
  float s = uhish[n*H2_+t]*g1w[t] + hagg[n*H2_+t]*g2w[t];
  __shared__ float red[256];
  red[t]=s; __syncthreads();
  for(int o=128;o>0;o>>=1){ if(t<o) red[t]+=red[t+o]; __syncthreads(); }
  if(t==0) gate[n] = 1.f/(1.f+expf(-(red[0]+g1b[0]+g2b[0])));
}

// ---------------- softmax row stats ----------------
__global__ void k_smstat(const float* __restrict__ logits, float* __restrict__ rowmax,
                         float* __restrict__ rowsum){
  int n = blockIdx.x; int t = threadIdx.x;
  const float* row = &logits[(long)n*NIT_];
  float m = -3.4e38f;
  for(int i=t;i<NIT_;i+=256) m = fmaxf(m, row[i]);
  __shared__ float red[256];
  __shared__ float mm;
  red[t]=m; __syncthreads();
  for(int o=128;o>0;o>>=1){ if(t<o) red[t]=fmaxf(red[t],red[t+o]); __syncthreads(); }
  if(t==0){ mm = red[0]; rowmax[n]=red[0]; }
  __syncthreads();
  float s=0.f;
  for(int i=t;i<NIT_;i+=256) s += __expf(row[i]-mm);
  __syncthreads();
  red[t]=s; __syncthreads();
  for(int o=128;o>0;o>>=1){ if(t<o) red[t]+=red[t+o]; __syncthreads(); }
  if(t==0) rowsum[n]=red[0];
}

// ---------------- final ----------------
__global__ void k_final(const float* __restrict__ logits, const float* __restrict__ rowmax,
                        const float* __restrict__ rowsum, const float* __restrict__ gate,
                        const float* __restrict__ uHis, float* __restrict__ out){
  int i = blockIdx.x*blockDim.x + threadIdx.x;
  if(i >= N_*NIT_) return;
  int n = i / NIT_;
  float g = gate[n];
  float p = __expf(logits[i]-rowmax[n]) / rowsum[n];
  out[i] = g*p + (1.f-g)*uHis[i];
}

extern "C" void kernel_launch(void* const* d_in, const int* in_sizes, int n_in,
                              void* d_out, int out_size, void* d_ws, size_t ws_size,
                              hipStream_t stream) {
  const int*   seq     = (const int*)  d_in[0];
  const float* uHis    = (const float*)d_in[1];
  const float* itemEmb = (const float*)d_in[2];
  const float* fc1_w   = (const float*)d_in[3];
  const float* fc1_b   = (const float*)d_in[4];
  const float* aspProju= (const float*)d_in[5];
  const float* aspProji= (const float*)d_in[6];
  const float* dh_w    = (const float*)d_in[7];
  const float* dh_b    = (const float*)d_in[8];
  const float* wih0    = (const float*)d_in[9];
  const float* whh0    = (const float*)d_in[10];
  const float* bih0    = (const float*)d_in[11];
  const float* bhh0    = (const float*)d_in[12];
  const float* wih1    = (const float*)d_in[13];
  const float* whh1    = (const float*)d_in[14];
  const float* bih1    = (const float*)d_in[15];
  const float* bhh1    = (const float*)d_in[16];
  const float* out_w   = (const float*)d_in[17];
  const float* out_b   = (const float*)d_in[18];
  const float* his_w   = (const float*)d_in[19];
  const float* his_b   = (const float*)d_in[20];
  const float* g1_w    = (const float*)d_in[21];
  const float* g1_b    = (const float*)d_in[22];
  const float* g2_w    = (const float*)d_in[23];
  const float* g2_b    = (const float*)d_in[24];

  float* ws = (float*)d_ws;
  float* embs = ws + 0;            // 6,553,600   (reused as logits later)
  float* cub  = ws + 6553600;      // 6,553,600   (ebh bf16 shadow; reused as xg later)
  float* na   = ws + 13107200;     // 5,242,880   (reused as outwb bf16 after xmax)
  float* x    = ws + 18350080;     // 1,310,720   (reused as haggb after xg0)
  float* y0   = ws + 19660800;     // 1,310,720
  float* y1   = ws + 20971520;     // 1,310,720
  float* eb   = ws + 22282240;     //   655,360
  float* e2   = ws + 22937600;     //   655,360
  float* dist = ws + 23592960;     //   262,144
  float* ua   = ws + 23855104;     //   131,072
  float* projT= ws + 23986176;     //    65,536  (holds projb bf16)
  float* wp0  = ws + 24051712;     //   262,144  (fp32 permuted wih0)
  float* whp0 = ws + 24313856;     //   262,144  (bf16 permuted whh0 lives here)
  float* wp1  = ws + 24576000;     //   262,144  (fp32 permuted wih1)
  float* whp1 = ws + 24838144;     //   262,144  (bf16 permuted whh1 lives here)
  float* bp0  = ws + 25100288;     //     1,024
  float* bp1  = ws + 25101312;     //     1,024
  float* uemb = ws + 25167872;     //       256
  float* sqb  = ws + 25168128;     //     1,024
  int*   nbr  = (int*)(ws + 25169152); // 15,360 ints
  float* uhish= ws + 25184512;     //    65,536
  float* hagg = ws + 25250048;     //    65,536
  float* rowmax=ws + 25315584;     //       256
  float* rowsum=ws + 25315840;     //       256
  float* gateb =ws + 25316096;     //       256
  float* logits = embs;            // reuse
  float* xg = cub;                 // reuse (ebh dead after k_uimm)
  unsigned short* ebh   = (unsigned short*)cub;   // bf16 shadow (inside cub slot)
  unsigned short* projb = (unsigned short*)projT; // bf16 (inside projT slot)
  unsigned short* outwb = (unsigned short*)na;    // bf16 out_w (na dead after xmax)
  unsigned short* haggb = (unsigned short*)x;     // bf16 hagg (x dead after xg0)
  unsigned short* whb0  = (unsigned short*)whp0;  // bf16 permuted whh0
  unsigned short* whb1  = (unsigned short*)whp1;  // bf16 permuted whh1

  // 1. embedding gather (fp32 + bf16 shadow)
  k_gather<<<NLB_, D_, 0, stream>>>(seq, itemEmb, embs, ebh);
  // 2. fc1 -> u_embs
  k_fc1<<<N_, 256, 0, stream>>>(embs, fc1_w, fc1_b, uemb);
  // 3. uA
  k_ua<<<(ASP_*N_*H_+255)/256, 256, 0, stream>>>(uemb, aspProju, ua);
  // 4. sq
  k_sq<<<ASP_*N_, 128, 0, stream>>>(ua, sqb);
  // 5. dist
  k_dist<<<dim3(N_,ASP_), 256, 0, stream>>>(ua, sqb, dist);
  // 6. top-k neighbors
  k_topk<<<ASP_*N_/4, 256, 0, stream>>>(dist, nbr);
  // 7. EB = sum_b embs
  k_eb<<<NL_, D_, 0, stream>>>(embs, eb);
  // 8. E2 = EB @ dh_w^T
  k_gemm<<<dim3(2, 80, 1), 256, 0, stream>>>(eb, dh_w, e2, nullptr, NL_, H_, D_, D_, 0);
  // 9. projb (bf16 transposed proj)
  k_projb<<<(ASP_*D_*H_+255)/256, 256, 0, stream>>>(aspProji, projb);
  // 10. fused UI stage: MFMA + tanh^2 + sum_b
  k_uimm<<<dim3(NL_/8, ASP_), 256, 0, stream>>>(ebh, projb, na);
  // 11. PI (neighbor sums)
  k_pi<<<dim3(N_,ASP_), H_, 0, stream>>>(e2, nbr, dh_b, na);
  // 12. x = flat max-4
  k_xmax<<<(N_*L_*H2_+255)/256, 256, 0, stream>>>(na, x);
  // 12b. cast out_w -> bf16 (into dead na region)
  k_outb<<<2500, 256, 0, stream>>>(out_w, outwb);
  // 13. LSTM weight permutes: wih fp32, whh bf16
  k_perm <<<(G4_*H2_+255)/256,256,0,stream>>>(wih0, wp0);
  k_permh<<<(G4_*H2_+255)/256,256,0,stream>>>(whh0, whb0);
  k_perm <<<(G4_*H2_+255)/256,256,0,stream>>>(wih1, wp1);
  k_permh<<<(G4_*H2_+255)/256,256,0,stream>>>(whh1, whb1);
  k_permb<<<4,256,0,stream>>>(bih0,bhh0,bp0);
  k_permb<<<4,256,0,stream>>>(bih1,bhh1,bp1);
  // 14. xg0 = x @ wp0^T + bp0 : bf16 MFMA (grid 16x80)
  k_xgmm<<<dim3(16,80), 256, 0, stream>>>(x, wp0, bp0, xg);
  // 15. LSTM layer 0: ONE launch, 20 steps, transposed MFMA + fast activations
  k_lstm_layer<<<16, 1024, 0, stream>>>(whb0, xg, y0);
  // 16. xg1 = y0 @ wp1^T + bp1 : bf16 MFMA
  k_xgmm<<<dim3(16,80), 256, 0, stream>>>(y0, wp1, bp1, xg);
  // 17. LSTM layer 1
  k_lstm_layer<<<16, 1024, 0, stream>>>(whb1, xg, y1);
  // 18. h_agg (+ bf16 shadow into dead x region)
  k_hagg<<<(N_*H2_+255)/256,256,0,stream>>>(y1, hagg, haggb);
  // 19. logits = h_agg @ out_w^T + out_b : bf16 MFMA (grid 625, tile 256x32)
  k_logitsmm<<<625, 256, 0, stream>>>(haggb, outwb, out_b, logits);
  // 20. uHis_h = uHis @ his_w^T + his_b : bf16 MFMA split-K
  hipMemsetAsync(uhish, 0, N_*H2_*sizeof(float), stream);
  k_uhismm<<<dim3(4,4,25), 256, 0, stream>>>(uHis, his_w, his_b, uhish);
  // 21. gate
  k_gate<<<N_,256,0,stream>>>(uhish, hagg, g1_w, g1_b, g2_w, g2_b, gateb);
  // 22. softmax stats
  k_smstat<<<N_,256,0,stream>>>(logits, rowmax, rowsum);
  // 23. final scores
  k_final<<<(N_*NIT_+255)/256,256,0,stream>>>(logits, rowmax, rowsum, gateb, uHis, (float*)d_out);
}

// Round 12
// 724.179 us; speedup vs baseline: 2.1415x; 1.0277x over previous
//
#include <hip/hip_runtime.h>
#include <math.h>

#define N_ 256
#define L_ 20
#define B_ 10
#define D_ 128
#define H_ 128
#define ASP_ 4
#define KK_ 16
#define NIT_ 20000
#define H2_ 256
#define G4_ 1024
#define LBD_ 25600
#define NL_ 5120
#define NLB_ 51200

typedef __attribute__((ext_vector_type(8))) short bf16x8;
typedef __attribute__((ext_vector_type(4))) float f32x4;

__device__ __forceinline__ float sigf(float x){ return 1.0f/(1.0f+expf(-x)); }
// hardware-exp fast activations: v_exp_f32 + v_rcp_f32, saturate correctly at +-inf
__device__ __forceinline__ float sigf_fast(float x){
  return __builtin_amdgcn_rcpf(1.0f + __expf(-x));
}
__device__ __forceinline__ float tanh_fast(float x){
  return 1.0f - 2.0f*__builtin_amdgcn_rcpf(__expf(2.0f*x) + 1.0f);
}
__device__ __forceinline__ unsigned short f2b(float f){
  unsigned int u = __float_as_uint(f);
  unsigned int r = (u + 0x7FFFu + ((u>>16)&1u)) >> 16;   // RNE
  return (unsigned short)r;
}

// ---------------- gather: embs[n,l,b,:] = itemEmb[seq[n,l,b],:] (+ bf16 shadow) ----------------
__global__ void k_gather(const int* __restrict__ seq, const float* __restrict__ itemEmb,
                         float* __restrict__ embs, unsigned short* __restrict__ ebh){
  int row = blockIdx.x;          // 0..51199 = (n,l,b)
  int t = threadIdx.x;           // 0..127
  int idx = seq[row];
  float v = itemEmb[idx*D_ + t];
  embs[row*D_ + t] = v;
  ebh[row*D_ + t] = f2b(v);
}

// ---------------- fc1: u[n] = dot(embs[n,:], fc1_w) + fc1_b ----------------
__global__ void k_fc1(const float* __restrict__ embs, const float* __restrict__ w,
                      const float* __restrict__ b, float* __restrict__ u){
  int n = blockIdx.x; int t = threadIdx.x;
  float s = 0.f;
  for (int i = t; i < LBD_; i += 256) s += embs[n*LBD_+i]*w[i];
  __shared__ float red[256];
  red[t]=s; __syncthreads();
  for (int o=128;o>0;o>>=1){ if(t<o) red[t]+=red[t+o]; __syncthreads(); }
  if(t==0) u[n]=red[0]+b[0];
}

// ---------------- uA[a,n,h] = tanh(tanh(u[n]*proju[a,h])) ----------------
// NOTE: keep libm tanh here — feeds kNN selection (keep selection bit-stable)
__global__ void k_ua(const float* __restrict__ u, const float* __restrict__ proju,
                     float* __restrict__ ua){
  int i = blockIdx.x*blockDim.x + threadIdx.x;
  if(i >= ASP_*N_*H_) return;
  int h = i % H_; int n = (i/H_) % N_; int a = i/(H_*N_);
  ua[i] = tanhf(tanhf(u[n]*proju[a*H_+h]));
}

// ---------------- sq[a,n] = sum_h uA^2 ----------------
__global__ void k_sq(const float* __restrict__ ua, float* __restrict__ sq){
  int an = blockIdx.x; int t = threadIdx.x;   // 128 threads
  float v = ua[an*H_ + t]; v *= v;
  __shared__ float red[128];
  red[t]=v; __syncthreads();
  for(int o=64;o>0;o>>=1){ if(t<o) red[t]+=red[t+o]; __syncthreads(); }
  if(t==0) sq[an]=red[0];
}

// ---------------- dist[a,n,m] ----------------
__global__ void k_dist(const float* __restrict__ ua, const float* __restrict__ sq,
                       float* __restrict__ dist){
  int n = blockIdx.x, a = blockIdx.y, m = threadIdx.x;  // 256 threads
  __shared__ float un[H_];
  if(m < H_) un[m] = ua[(a*N_+n)*H_ + m];
  __syncthreads();
  const float* um = &ua[(a*N_+m)*H_];
  float dot=0.f;
  for(int h=0;h<H_;h++) dot += un[h]*um[h];
  float dval = sq[a*N_+n] + sq[a*N_+m] - 2.f*dot;
  if(m==n) dval = -1.0f;
  dist[(a*N_+n)*N_ + m] = dval;
}

// ---------------- top-16 smallest, wave-parallel: 1 wave per (a,n) row ----------------
__global__ __launch_bounds__(256) void k_topk(const float* __restrict__ dist, int* __restrict__ nbr){
  int wid = blockIdx.x*(blockDim.x>>6) + (threadIdx.x>>6);  // row = (a*N_+n)
  if(wid >= ASP_*N_) return;
  int lane = threadIdx.x & 63;
  const float* row = &dist[(long)wid*N_];
  float v[4]; int idx[4];
  #pragma unroll
  for(int j=0;j<4;j++){ int m = lane*4 + j; v[j] = row[m]; idx[j] = m; }
  for(int k=0;k<KK_;k++){
    float bv = v[0]; int bi = idx[0];
    #pragma unroll
    for(int j=1;j<4;j++)
      if(v[j] < bv || (v[j]==bv && idx[j] < bi)){ bv=v[j]; bi=idx[j]; }
    float rv = bv; int ri = bi;
    #pragma unroll
    for(int o=32;o>0;o>>=1){
      float ov = __shfl_xor(rv, o, 64);
      int   oi = __shfl_xor(ri, o, 64);
      if(ov < rv || (ov==rv && oi < ri)){ rv=ov; ri=oi; }
    }
    if((ri>>2) == lane){ v[ri&3] = 3.4e38f; idx[ri&3] = 0x7fffffff; }
    if(k>0 && lane==0) nbr[wid*(KK_-1)+(k-1)] = ri;
  }
}

// ---------------- EB[n,l,d] = sum_b embs ----------------
__global__ void k_eb(const float* __restrict__ embs, float* __restrict__ eb){
  int nl = blockIdx.x; int d = threadIdx.x;
  float s=0.f;
  const float* p = &embs[nl*B_*D_ + d];
  for(int b=0;b<B_;b++) s += p[b*D_];
  eb[nl*D_ + d] = s;
}

// ---------------- projb[a,h,d] = bf16(aspProji[a,d,h]) ----------------
__global__ void k_projb(const float* __restrict__ proji, unsigned short* __restrict__ projb){
  int i = blockIdx.x*blockDim.x + threadIdx.x;
  if(i>=ASP_*D_*H_) return;
  int h=i%H_, d=(i/H_)%D_, a=i/(D_*H_);
  projb[(a*H_ + h)*D_ + d] = f2b(proji[i]);
}

// ---------------- fused UI stage: MFMA bf16 GEMM + tanh^2 + sum_b -> na[.., 0:128] ----------------
__global__ __launch_bounds__(256) void k_uimm(const unsigned short* __restrict__ ebh,
                                              const unsigned short* __restrict__ projb,
                                              float* __restrict__ na){
  __shared__ char smem[53248];
  unsigned short* As = (unsigned short*)smem;            // 80x128 bf16, swizzled 16B chunks
  unsigned short* Bs = (unsigned short*)(smem + 20480);  // 128x128 bf16, swizzled
  float*          Cs = (float*)smem;                     // 80x128 f32 (aliases As+Bs later)

  int mb = blockIdx.x;   // 0..639  -> nl0 = mb*8, A rows r0 = mb*80
  int a  = blockIdx.y;   // 0..3
  int tid = threadIdx.x;

  const unsigned short* asrc = ebh + (size_t)mb*10240;
  #pragma unroll
  for(int t=0;t<5;t++){
    int c = tid + t*256;
    int row = c >> 4;
    *(bf16x8*)(As + 8*(c ^ (row&7))) = *(const bf16x8*)(asrc + 8*c);
  }
  const unsigned short* bsrc = projb + a*16384;
  #pragma unroll
  for(int t=0;t<8;t++){
    int c = tid + t*256;
    int row = c >> 4;
    *(bf16x8*)(Bs + 8*(c ^ (row&7))) = *(const bf16x8*)(bsrc + 8*c);
  }
  __syncthreads();

  int lane = tid & 63, wave = tid >> 6;
  int l15 = lane & 15, l4 = lane >> 4;
  f32x4 acc[5][2] = {};
  #pragma unroll
  for(int kk=0;kk<4;kk++){
    bf16x8 bfr[2];
    #pragma unroll
    for(int tc=0;tc<2;tc++){
      int h = (wave*2+tc)*16 + l15;
      int c = h*16 + kk*4 + l4;
      bfr[tc] = *(const bf16x8*)(Bs + 8*(c ^ (h&7)));
    }
    #pragma unroll
    for(int tr=0;tr<5;tr++){
      int R = tr*16 + l15;
      int c = R*16 + kk*4 + l4;
      bf16x8 afr = *(const bf16x8*)(As + 8*(c ^ (R&7)));
      acc[tr][0] = __builtin_amdgcn_mfma_f32_16x16x32_bf16(afr, bfr[0], acc[tr][0], 0,0,0);
      acc[tr][1] = __builtin_amdgcn_mfma_f32_16x16x32_bf16(afr, bfr[1], acc[tr][1], 0,0,0);
    }
  }
  __syncthreads();

  #pragma unroll
  for(int tr=0;tr<5;tr++)
    #pragma unroll
    for(int tc=0;tc<2;tc++){
      int col = (wave*2+tc)*16 + l15;
      #pragma unroll
      for(int r=0;r<4;r++){
        int R = tr*16 + l4*4 + r;
        Cs[R*128 + col] = tanh_fast(tanh_fast(acc[tr][tc][r]));
      }
    }
  __syncthreads();

  #pragma unroll
  for(int t=0;t<4;t++){
    int oi = t*256 + tid;
    int g = oi >> 7, col = oi & 127;
    float s = 0.f;
    const float* p = Cs + g*1280 + col;
    #pragma unroll
    for(int b=0;b<10;b++) s += p[b*128];
    int nl = mb*8 + g;
    int n = nl/L_, l = nl%L_;
    na[((size_t)(n*ASP_+a)*L_ + l)*H2_ + col] = s;
  }
}

// ---------------- uHis_h: bf16 MFMA split-K (grid 4x4x25) ----------------
__global__ __launch_bounds__(256) void k_uhismm(const float* __restrict__ U,
    const float* __restrict__ W, const float* __restrict__ bias, float* __restrict__ C){
  __shared__ unsigned short As[2048];   // 64 rows x 32 k, chunk = q*64+row (8 bf16 each)
  __shared__ unsigned short Bs[2048];
  int tid = threadIdx.x;
  int m0 = blockIdx.y*64, n0 = blockIdx.x*64;
  int kb0 = blockIdx.z*800;
  int row = tid & 63, q = tid >> 6;
  int lane = tid & 63, wave = tid >> 6;
  int l15 = lane & 15, l4 = lane >> 4;
  int wr = (wave>>1)*32, wc = (wave&1)*32;
  f32x4 acc[2][2] = {};
  for(int s=0;s<25;s++){
    int k0 = kb0 + s*32 + q*8;
    {
      const float* pa = &U[(size_t)(m0+row)*NIT_ + k0];
      float4 a0 = *(const float4*)pa, a1 = *(const float4*)(pa+4);
      bf16x8 av;
      av[0]=f2b(a0.x); av[1]=f2b(a0.y); av[2]=f2b(a0.z); av[3]=f2b(a0.w);
      av[4]=f2b(a1.x); av[5]=f2b(a1.y); av[6]=f2b(a1.z); av[7]=f2b(a1.w);
      *(bf16x8*)(As + 8*tid) = av;
      const float* pb = &W[(size_t)(n0+row)*NIT_ + k0];
      float4 b0 = *(const float4*)pb, b1 = *(const float4*)(pb+4);
      bf16x8 bv;
      bv[0]=f2b(b0.x); bv[1]=f2b(b0.y); bv[2]=f2b(b0.z); bv[3]=f2b(b0.w);
      bv[4]=f2b(b1.x); bv[5]=f2b(b1.y); bv[6]=f2b(b1.z); bv[7]=f2b(b1.w);
      *(bf16x8*)(Bs + 8*tid) = bv;
    }
    __syncthreads();
    bf16x8 afr[2], bfr[2];
    #pragma unroll
    for(int mt=0;mt<2;mt++) afr[mt] = *(const bf16x8*)(As + 8*(l4*64 + wr + mt*16 + l15));
    #pragma unroll
    for(int nt=0;nt<2;nt++) bfr[nt] = *(const bf16x8*)(Bs + 8*(l4*64 + wc + nt*16 + l15));
    #pragma unroll
    for(int mt=0;mt<2;mt++)
      #pragma unroll
      for(int nt=0;nt<2;nt++)
        acc[mt][nt] = __builtin_amdgcn_mfma_f32_16x16x32_bf16(afr[mt], bfr[nt], acc[mt][nt], 0,0,0);
    __syncthreads();
  }
  #pragma unroll
  for(int mt=0;mt<2;mt++)
    #pragma unroll
    for(int nt=0;nt<2;nt++){
      int col = n0 + wc + nt*16 + l15;
      #pragma unroll
      for(int r=0;r<4;r++){
        int rw = m0 + wr + mt*16 + l4*4 + r;
        float v = acc[mt][nt][r];
        if(blockIdx.z==0) v += bias[col];
        atomicAdd(&C[rw*H2_ + col], v);
      }
    }
}

// ---------------- xg GEMM: bf16 MFMA, in-register cast, M=5120 N=1024 K=256 ----------------
__global__ __launch_bounds__(256) void k_xgmm(const float* __restrict__ A_,
    const float* __restrict__ W, const float* __restrict__ bias, float* __restrict__ C){
  __shared__ unsigned short As[2048];
  __shared__ unsigned short Bs[2048];
  int tid = threadIdx.x;
  int n0 = blockIdx.x*64, m0 = blockIdx.y*64;
  int row = tid & 63, q = tid >> 6;
  int lane = tid & 63, wave = tid >> 6;
  int l15 = lane & 15, l4 = lane >> 4;
  int wr = (wave>>1)*32, wc = (wave&1)*32;
  f32x4 acc[2][2] = {};
  for(int s=0;s<8;s++){
    int k0 = s*32 + q*8;
    {
      const float* pa = &A_[(size_t)(m0+row)*H2_ + k0];
      float4 a0 = *(const float4*)pa, a1 = *(const float4*)(pa+4);
      bf16x8 av;
      av[0]=f2b(a0.x); av[1]=f2b(a0.y); av[2]=f2b(a0.z); av[3]=f2b(a0.w);
      av[4]=f2b(a1.x); av[5]=f2b(a1.y); av[6]=f2b(a1.z); av[7]=f2b(a1.w);
      *(bf16x8*)(As + 8*tid) = av;
      const float* pb = &W[(size_t)(n0+row)*H2_ + k0];
      float4 b0 = *(const float4*)pb, b1 = *(const float4*)(pb+4);
      bf16x8 bv;
      bv[0]=f2b(b0.x); bv[1]=f2b(b0.y); bv[2]=f2b(b0.z); bv[3]=f2b(b0.w);
      bv[4]=f2b(b1.x); bv[5]=f2b(b1.y); bv[6]=f2b(b1.z); bv[7]=f2b(b1.w);
      *(bf16x8*)(Bs + 8*tid) = bv;
    }
    __syncthreads();
    bf16x8 afr[2], bfr[2];
    #pragma unroll
    for(int mt=0;mt<2;mt++) afr[mt] = *(const bf16x8*)(As + 8*(l4*64 + wr + mt*16 + l15));
    #pragma unroll
    for(int nt=0;nt<2;nt++) bfr[nt] = *(const bf16x8*)(Bs + 8*(l4*64 + wc + nt*16 + l15));
    #pragma unroll
    for(int mt=0;mt<2;mt++)
      #pragma unroll
      for(int nt=0;nt<2;nt++)
        acc[mt][nt] = __builtin_amdgcn_mfma_f32_16x16x32_bf16(afr[mt], bfr[nt], acc[mt][nt], 0,0,0);
    __syncthreads();
  }
  #pragma unroll
  for(int mt=0;mt<2;mt++)
    #pragma unroll
    for(int nt=0;nt<2;nt++){
      int col = n0 + wc + nt*16 + l15;
      float bs = bias[col];
      #pragma unroll
      for(int r=0;r<4;r++){
        int rw = m0 + wr + mt*16 + l4*4 + r;
        C[(size_t)rw*G4_ + col] = acc[mt][nt][r] + bs;
      }
    }
}

// ---------------- cast out_w -> bf16 ----------------
__global__ void k_outb(const float* __restrict__ w, unsigned short* __restrict__ wb){
  int i = blockIdx.x*blockDim.x + threadIdx.x;   // 640000 threads, 8 elems each
  const float* p = w + (size_t)i*8;
  float4 a = *(const float4*)p, b = *(const float4*)(p+4);
  bf16x8 v;
  v[0]=f2b(a.x); v[1]=f2b(a.y); v[2]=f2b(a.z); v[3]=f2b(a.w);
  v[4]=f2b(b.x); v[5]=f2b(b.y); v[6]=f2b(b.z); v[7]=f2b(b.w);
  *(bf16x8*)(wb + (size_t)i*8) = v;
}

// ---------------- logits: bf16 MFMA, tile 256x32, grid 625, frags straight from L2 ----------------
__global__ __launch_bounds__(256) void k_logitsmm(const unsigned short* __restrict__ Ab,
    const unsigned short* __restrict__ Wb, const float* __restrict__ bias,
    float* __restrict__ C){
  int n0 = blockIdx.x*32;
  int tid = threadIdx.x;
  int lane = tid & 63, wave = tid >> 6;
  int l15 = lane & 15, l4 = lane >> 4;
  f32x4 acc[4][2] = {};
  #pragma unroll
  for(int kk=0;kk<8;kk++){
    int k0 = kk*32 + l4*8;
    bf16x8 bfr[2];
    #pragma unroll
    for(int nt=0;nt<2;nt++)
      bfr[nt] = *(const bf16x8*)(Wb + (size_t)(n0 + nt*16 + l15)*H2_ + k0);
    #pragma unroll
    for(int mt=0;mt<4;mt++){
      bf16x8 afr = *(const bf16x8*)(Ab + (size_t)(wave*64 + mt*16 + l15)*H2_ + k0);
      acc[mt][0] = __builtin_amdgcn_mfma_f32_16x16x32_bf16(afr, bfr[0], acc[mt][0], 0,0,0);
      acc[mt][1] = __builtin_amdgcn_mfma_f32_16x16x32_bf16(afr, bfr[1], acc[mt][1], 0,0,0);
    }
  }
  #pragma unroll
  for(int mt=0;mt<4;mt++)
    #pragma unroll
    for(int nt=0;nt<2;nt++){
      int col = n0 + nt*16 + l15;
      float bs = bias[col];
      #pragma unroll
      for(int r=0;r<4;r++){
        int row = wave*64 + mt*16 + l4*4 + r;
        C[(size_t)row*NIT_ + col] = acc[mt][nt][r] + bs;
      }
    }
}

// ---------------- generic fp32 NT GEMM (E2 only now) ----------------
__global__ __launch_bounds__(256) void k_gemm(const float* __restrict__ A, const float* __restrict__ W,
    float* __restrict__ C, const float* __restrict__ bias,
    int M, int Nn, int K, int kchunk, int atomic_mode){
  __shared__ float As[64][17];
  __shared__ float Ws[64][17];
  int tid = threadIdx.x;
  int tx = tid & 15, ty = tid >> 4;
  int m0 = blockIdx.y*64, n0 = blockIdx.x*64;
  int kb0 = blockIdx.z*kchunk;
  int kend = kb0 + kchunk; if(kend > K) kend = K;
  float acc[4][4] = {};
  int lrow = tid >> 2;
  int lc4 = (tid & 3) * 4;
  for(int kb = kb0; kb < kend; kb += 16){
    {
      int gr = m0 + lrow;
      float4 v = make_float4(0,0,0,0);
      if(gr < M) v = *(const float4*)&A[(long)gr*K + kb + lc4];
      As[lrow][lc4+0]=v.x; As[lrow][lc4+1]=v.y; As[lrow][lc4+2]=v.z; As[lrow][lc4+3]=v.w;
      int gw = n0 + lrow;
      float4 u = make_float4(0,0,0,0);
      if(gw < Nn) u = *(const float4*)&W[(long)gw*K + kb + lc4];
      Ws[lrow][lc4+0]=u.x; Ws[lrow][lc4+1]=u.y; Ws[lrow][lc4+2]=u.z; Ws[lrow][lc4+3]=u.w;
    }
    __syncthreads();
    for(int k=0;k<16;k++){
      float av[4], wv[4];
      #pragma unroll
      for(int r=0;r<4;r++) av[r]=As[ty*4+r][k];
      #pragma unroll
      for(int c=0;c<4;c++) wv[c]=Ws[tx*4+c][k];
      #pragma unroll
      for(int r=0;r<4;r++)
        #pragma unroll
        for(int c=0;c<4;c++) acc[r][c] += av[r]*wv[c];
    }
    __syncthreads();
  }
  for(int r=0;r<4;r++){
    int row = m0 + ty*4 + r; if(row >= M) continue;
    for(int c=0;c<4;c++){
      int col = n0 + tx*4 + c; if(col >= Nn) continue;
      float v = acc[r][c];
      if(bias && blockIdx.z==0) v += bias[col];
      if(atomic_mode) atomicAdd(&C[(long)row*Nn+col], v);
      else C[(long)row*Nn+col] = v;
    }
  }
}

// ---------------- PI: na[n,a,l,128:256] = sum_nbr E2[nbr,l,h] + B*dh_b[h] ----------------
__global__ void k_pi(const float* __restrict__ e2, const int* __restrict__ nbr,
                     const float* __restrict__ dh_b, float* __restrict__ na){
  int n = blockIdx.x, a = blockIdx.y, h = threadIdx.x; // 128
  __shared__ int nb[KK_-1];
  if(h < KK_-1) nb[h] = nbr[(a*N_+n)*(KK_-1)+h];
  __syncthreads();
  float bias = (float)B_ * dh_b[h];
  for(int l=0;l<L_;l++){
    float s = bias;
    for(int k=0;k<KK_-1;k++) s += e2[(long)(nb[k]*L_ + l)*H_ + h];
    na[((long)(n*ASP_+a)*L_ + l)*H2_ + H_ + h] = s;
  }
}

// ---------------- x: flat reinterpret max over 4 consecutive ----------------
__global__ void k_xmax(const float* __restrict__ na, float* __restrict__ x){
  int i = blockIdx.x*blockDim.x + threadIdx.x;
  if(i >= N_*L_*H2_) return;
  int n = i / (L_*H2_);
  int j = i % (L_*H2_);
  const float* p = &na[(long)n*ASP_*L_*H2_ + 4*j];
  x[i] = fmaxf(fmaxf(p[0],p[1]), fmaxf(p[2],p[3]));
}

// ---------------- LSTM weight permute (fp32, for wih used by xg GEMM) ----------------
__global__ void k_perm(const float* __restrict__ src, float* __restrict__ dst){
  int i = blockIdx.x*blockDim.x + threadIdx.x;
  if(i >= G4_*H2_) return;
  int k = i % H2_; int j = i / H2_;
  int g = j / H2_, jj = j % H2_;
  dst[(jj*4+g)*H2_ + k] = src[i];
}
// ---------------- LSTM recurrent weight permute + bf16 cast ----------------
__global__ void k_permh(const float* __restrict__ src, unsigned short* __restrict__ dst){
  int i = blockIdx.x*blockDim.x + threadIdx.x;
  if(i >= G4_*H2_) return;
  int k = i % H2_; int j = i / H2_;
  int g = j / H2_, jj = j % H2_;
  dst[(jj*4+g)*H2_ + k] = f2b(src[i]);
}
__global__ void k_permb(const float* __restrict__ bih, const float* __restrict__ bhh,
                        float* __restrict__ bp){
  int j = blockIdx.x*blockDim.x + threadIdx.x;
  if(j >= G4_) return;
  int g = j / H2_, jj = j % H2_;
  bp[jj*4+g] = bih[j] + bhh[j];
}

// ---------------- fused LSTM layer, pipelined: one launch per layer ----------------
// 16 blocks x 1024 thr (16 waves). Transposed MFMA (r10-verified mapping).
// Round-12 restructure: (1) xg(t) loads issued BEFORE the MFMA phase (HBM latency
// hides under weight-stream+MFMA), (2) double-buffered h in LDS -> ONE barrier
// per step, (3) kk-major MFMA order: 4 independent chains, loads pipelined.
__global__ __launch_bounds__(1024) void k_lstm_layer(
    const unsigned short* __restrict__ Whb,   // [1024][256] bf16 permuted (col=jj*4+g)
    const float* __restrict__ xg,             // [256][20][1024] permuted ih products
    float* __restrict__ Y){                   // [256][20][256] fp32 h sequence
  __shared__ unsigned short hs[2][16*H2_];    // 2 x 8 KB, chunk ch=s*32+k/8, swz ^(s&7)
  int tid = threadIdx.x;
  int n0 = blockIdx.x * 16;
  int lane = tid & 63, wave = tid >> 6;       // wave 0..15, owns gate tiles wave*4..+3
  int l15 = lane & 15, l4 = lane >> 4;
  int n = n0 + l15;                            // this lane's sample
  float creg[4] = {0.f,0.f,0.f,0.f};
  const unsigned short* wptr[4];
  #pragma unroll
  for(int i=0;i<4;i++) wptr[i] = Whb + (size_t)((wave*4+i)*16 + l15)*H2_ + l4*8;
  for(int t=0; t<L_; t++){
    // (1) issue xg(t) loads early — complete during MFMA phase
    float4 xgv[4];
    #pragma unroll
    for(int i=0;i<4;i++){
      int jj = wave*16 + i*4 + l4;
      xgv[i] = *(const float4*)&xg[((size_t)n*L_ + t)*G4_ + jj*4];
    }
    f32x4 acc[4] = {};
    if(t > 0){
      const unsigned short* hbuf = hs[(t+1)&1];   // holds h(t-1)
      bf16x8 hfr[8];
      #pragma unroll
      for(int kk=0; kk<8; kk++){
        int ch = l15*32 + kk*4 + l4;
        hfr[kk] = *(const bf16x8*)(hbuf + 8*(ch ^ (l15&7)));
      }
      // (3) kk-major: 4 independent MFMA chains, weight loads pipeline across kk
      #pragma unroll
      for(int kk=0; kk<8; kk++){
        bf16x8 wfr[4];
        #pragma unroll
        for(int i=0;i<4;i++) wfr[i] = *(const bf16x8*)(wptr[i] + kk*32);
        #pragma unroll
        for(int i=0;i<4;i++)
          acc[i] = __builtin_amdgcn_mfma_f32_16x16x32_bf16(wfr[i], hfr[kk], acc[i], 0,0,0);
      }
    }
    // (2) epilogue writes the OTHER buffer — no mid-step barrier needed
    unsigned short* hout = hs[t&1];
    #pragma unroll
    for(int i=0;i<4;i++){
      int jj = wave*16 + i*4 + l4;
      float gi = acc[i][0] + xgv[i].x;
      float gf = acc[i][1] + xgv[i].y;
      float gg = acc[i][2] + xgv[i].z;
      float go = acc[i][3] + xgv[i].w;
      float cnew = sigf_fast(gf)*creg[i] + sigf_fast(gi)*tanh_fast(gg);
      creg[i] = cnew;
      float hnew = sigf_fast(go)*tanh_fast(cnew);
      Y[((size_t)n*L_ + t)*H2_ + jj] = hnew;
      int ch = l15*32 + (jj>>3);
      *(unsigned short*)((char*)hout + 16*(ch ^ (l15&7)) + (jj&7)*2) = f2b(hnew);
    }
    __syncthreads();   // h(t) visible before step t+1's reads
  }
}

// ---------------- h_agg = tanh(sum_t y1) (+ bf16 shadow) ----------------
__global__ void k_hagg(const float* __restrict__ y1, float* __restrict__ hagg,
                       unsigned short* __restrict__ haggb){
  int i = blockIdx.x*blockDim.x + threadIdx.x;
  if(i>=N_*H2_) return;
  int n = i / H2_, jj = i % H2_;
  float s=0.f;
  for(int t=0;t<L_;t++) s += y1[((long)n*L_+t)*H2_ + jj];
  float v = tanhf(s);
  hagg[i] = v;
  haggb[i] = f2b(v);
}

// ---------------- gate ----------------
__global__ void k_gate(const float* __restrict__ uhish, const float* __restrict__ hagg,
                       const float* __restrict__ g1w, const float* __restrict__ g1b,
                       const float* __restrict__ g2w, const float* __restrict__ g2b,
                       float* __restrict__ gate){
  int n = blockIdx.x; int t = threadIdx.x; // 256
  float s = uhish[n*H2_+t]*g1w[t] + hagg[n*H2_+t]*g2w[t];
  __shared__ float red[256];
  red[t]=s; __syncthreads();
  for(int o=128;o>0;o>>=1){ if(t<o) red[t]+=red[t+o]; __syncthreads(); }
  if(t==0) gate[n] = 1.f/(1.f+expf(-(red[0]+g1b[0]+g2b[0])));
}

// ---------------- softmax row stats ----------------
__global__ void k_smstat(const float* __restrict__ logits, float* __restrict__ rowmax,
                         float* __restrict__ rowsum){
  int n = blockIdx.x; int t = threadIdx.x;
  const float* row = &logits[(long)n*NIT_];
  float m = -3.4e38f;
  for(int i=t;i<NIT_;i+=256) m = fmaxf(m, row[i]);
  __shared__ float red[256];
  __shared__ float mm;
  red[t]=m; __syncthreads();
  for(int o=128;o>0;o>>=1){ if(t<o) red[t]=fmaxf(red[t],red[t+o]); __syncthreads(); }
  if(t==0){ mm = red[0]; rowmax[n]=red[0]; }
  __syncthreads();
  float s=0.f;
  for(int i=t;i<NIT_;i+=256) s += __expf(row[i]-mm);
  __syncthreads();
  red[t]=s; __syncthreads();
  for(int o=128;o>0;o>>=1){ if(t<o) red[t]+=red[t+o]; __syncthreads(); }
  if(t==0) rowsum[n]=red[0];
}

// ---------------- final ----------------
__global__ void k_final(const float* __restrict__ logits, const float* __restrict__ rowmax,
                        const float* __restrict__ rowsum, const float* __restrict__ gate,
                        const float* __restrict__ uHis, float* __restrict__ out){
  int i = blockIdx.x*blockDim.x + threadIdx.x;
  if(i >= N_*NIT_) return;
  int n = i / NIT_;
  float g = gate[n];
  float p = __expf(logits[i]-rowmax[n]) / rowsum[n];
  out[i] = g*p + (1.f-g)*uHis[i];
}

extern "C" void kernel_launch(void* const* d_in, const int* in_sizes, int n_in,
                              void* d_out, int out_size, void* d_ws, size_t ws_size,
                              hipStream_t stream) {
  const int*   seq     = (const int*)  d_in[0];
  const float* uHis    = (const float*)d_in[1];
  const float* itemEmb = (const float*)d_in[2];
  const float* fc1_w   = (const float*)d_in[3];
  const float* fc1_b   = (const float*)d_in[4];
  const float* aspProju= (const float*)d_in[5];
  const float* aspProji= (const float*)d_in[6];
  const float* dh_w    = (const float*)d_in[7];
  const float* dh_b    = (const float*)d_in[8];
  const float* wih0    = (const float*)d_in[9];
  const float* whh0    = (const float*)d_in[10];
  const float* bih0    = (const float*)d_in[11];
  const float* bhh0    = (const float*)d_in[12];
  const float* wih1    = (const float*)d_in[13];
  const float* whh1    = (const float*)d_in[14];
  const float* bih1    = (const float*)d_in[15];
  const float* bhh1    = (const float*)d_in[16];
  const float* out_w   = (const float*)d_in[17];
  const float* out_b   = (const float*)d_in[18];
  const float* his_w   = (const float*)d_in[19];
  const float* his_b   = (const float*)d_in[20];
  const float* g1_w    = (const float*)d_in[21];
  const float* g1_b    = (const float*)d_in[22];
  const float* g2_w    = (const float*)d_in[23];
  const float* g2_b    = (const float*)d_in[24];

  float* ws = (float*)d_ws;
  float* embs = ws + 0;            // 6,553,600   (reused as logits later)
  float* cub  = ws + 6553600;      // 6,553,600   (ebh bf16 shadow; reused as xg later)
  float* na   = ws + 13107200;     // 5,242,880   (reused as outwb bf16 after xmax)
  float* x    = ws + 18350080;     // 1,310,720   (reused as haggb after xg0)
  float* y0   = ws + 19660800;     // 1,310,720
  float* y1   = ws + 20971520;     // 1,310,720
  float* eb   = ws + 22282240;     //   655,360
  float* e2   = ws + 22937600;     //   655,360
  float* dist = ws + 23592960;     //   262,144
  float* ua   = ws + 23855104;     //   131,072
  float* projT= ws + 23986176;     //    65,536  (holds projb bf16)
  float* wp0  = ws + 24051712;     //   262,144  (fp32 permuted wih0)
  float* whp0 = ws + 24313856;     //   262,144  (bf16 permuted whh0 lives here)
  float* wp1  = ws + 24576000;     //   262,144  (fp32 permuted wih1)
  float* whp1 = ws + 24838144;     //   262,144  (bf16 permuted whh1 lives here)
  float* bp0  = ws + 25100288;     //     1,024
  float* bp1  = ws + 25101312;     //     1,024
  float* uemb = ws + 25167872;     //       256
  float* sqb  = ws + 25168128;     //     1,024
  int*   nbr  = (int*)(ws + 25169152); // 15,360 ints
  float* uhish= ws + 25184512;     //    65,536
  float* hagg = ws + 25250048;     //    65,536
  float* rowmax=ws + 25315584;     //       256
  float* rowsum=ws + 25315840;     //       256
  float* gateb =ws + 25316096;     //       256
  float* logits = embs;            // reuse
  float* xg = cub;                 // reuse (ebh dead after k_uimm)
  unsigned short* ebh   = (unsigned short*)cub;   // bf16 shadow (inside cub slot)
  unsigned short* projb = (unsigned short*)projT; // bf16 (inside projT slot)
  unsigned short* outwb = (unsigned short*)na;    // bf16 out_w (na dead after xmax)
  unsigned short* haggb = (unsigned short*)x;     // bf16 hagg (x dead after xg0)
  unsigned short* whb0  = (unsigned short*)whp0;  // bf16 permuted whh0
  unsigned short* whb1  = (unsigned short*)whp1;  // bf16 permuted whh1

  // 1. embedding gather (fp32 + bf16 shadow)
  k_gather<<<NLB_, D_, 0, stream>>>(seq, itemEmb, embs, ebh);
  // 2. fc1 -> u_embs
  k_fc1<<<N_, 256, 0, stream>>>(embs, fc1_w, fc1_b, uemb);
  // 3. uA
  k_ua<<<(ASP_*N_*H_+255)/256, 256, 0, stream>>>(uemb, aspProju, ua);
  // 4. sq
  k_sq<<<ASP_*N_, 128, 0, stream>>>(ua, sqb);
  // 5. dist
  k_dist<<<dim3(N_,ASP_), 256, 0, stream>>>(ua, sqb, dist);
  // 6. top-k neighbors
  k_topk<<<ASP_*N_/4, 256, 0, stream>>>(dist, nbr);
  // 7. EB = sum_b embs
  k_eb<<<NL_, D_, 0, stream>>>(embs, eb);
  // 8. E2 = EB @ dh_w^T
  k_gemm<<<dim3(2, 80, 1), 256, 0, stream>>>(eb, dh_w, e2, nullptr, NL_, H_, D_, D_, 0);
  // 9. projb (bf16 transposed proj)
  k_projb<<<(ASP_*D_*H_+255)/256, 256, 0, stream>>>(aspProji, projb);
  // 10. fused UI stage: MFMA + tanh^2 + sum_b
  k_uimm<<<dim3(NL_/8, ASP_), 256, 0, stream>>>(ebh, projb, na);
  // 11. PI (neighbor sums)
  k_pi<<<dim3(N_,ASP_), H_, 0, stream>>>(e2, nbr, dh_b, na);
  // 12. x = flat max-4
  k_xmax<<<(N_*L_*H2_+255)/256, 256, 0, stream>>>(na, x);
  // 12b. cast out_w -> bf16 (into dead na region)
  k_outb<<<2500, 256, 0, stream>>>(out_w, outwb);
  // 13. LSTM weight permutes: wih fp32, whh bf16
  k_perm <<<(G4_*H2_+255)/256,256,0,stream>>>(wih0, wp0);
  k_permh<<<(G4_*H2_+255)/256,256,0,stream>>>(whh0, whb0);
  k_perm <<<(G4_*H2_+255)/256,256,0,stream>>>(wih1, wp1);
  k_permh<<<(G4_*H2_+255)/256,256,0,stream>>>(whh1, whb1);
  k_permb<<<4,256,0,stream>>>(bih0,bhh0,bp0);
  k_permb<<<4,256,0,stream>>>(bih1,bhh1,bp1);
  // 14. xg0 = x @ wp0^T + bp0 : bf16 MFMA (grid 16x80)
  k_xgmm<<<dim3(16,80), 256, 0, stream>>>(x, wp0, bp0, xg);
  // 15. LSTM layer 0: ONE launch, pipelined (xg prefetch + 1 barrier/step)
  k_lstm_layer<<<16, 1024, 0, stream>>>(whb0, xg, y0);
  // 16. xg1 = y0 @ wp1^T + bp1 : bf16 MFMA
  k_xgmm<<<dim3(16,80), 256, 0, stream>>>(y0, wp1, bp1, xg);
  // 17. LSTM layer 1
  k_lstm_layer<<<16, 1024, 0, stream>>>(whb1, xg, y1);
  // 18. h_agg (+ bf16 shadow into dead x region)
  k_hagg<<<(N_*H2_+255)/256,256,0,stream>>>(y1, hagg, haggb);
  // 19. logits = h_agg @ out_w^T + out_b : bf16 MFMA (grid 625, tile 256x32)
  k_logitsmm<<<625, 256, 0, stream>>>(haggb, outwb, out_b, logits);
  // 20. uHis_h = uHis @ his_w^T + his_b : bf16 MFMA split-K
  hipMemsetAsync(uhish, 0, N_*H2_*sizeof(float), stream);
  k_uhismm<<<dim3(4,4,25), 256, 0, stream>>>(uHis, his_w, his_b, uhish);
  // 21. gate
  k_gate<<<N_,256,0,stream>>>(uhish, hagg, g1_w, g1_b, g2_w, g2_b, gateb);
  // 22. softmax stats
  k_smstat<<<N_,256,0,stream>>>(logits, rowmax, rowsum);
  // 23. final scores
  k_final<<<(N_*NIT_+255)/256,256,0,stream>>>(logits, rowmax, rowsum, gateb, uHis, (float*)d_out);
}

// Round 15
// 546.122 us; speedup vs baseline: 2.8397x; 1.3260x over previous
//
#include <hip/hip_runtime.h>
#include <math.h>

#define N_ 256
#define L_ 20
#define B_ 10
#define D_ 128
#define H_ 128
#define ASP_ 4
#define KK_ 16
#define NIT_ 20000
#define H2_ 256
#define G4_ 1024
#define LBD_ 25600
#define NL_ 5120
#define NLB_ 51200

typedef __attribute__((ext_vector_type(8))) short bf16x8;
typedef __attribute__((ext_vector_type(4))) short bf16x4;
typedef __attribute__((ext_vector_type(4))) float f32x4;

__device__ __forceinline__ float sigf(float x){ return 1.0f/(1.0f+expf(-x)); }
// hardware-exp fast activations: v_exp_f32 + v_rcp_f32, saturate correctly at +-inf
__device__ __forceinline__ float sigf_fast(float x){
  return __builtin_amdgcn_rcpf(1.0f + __expf(-x));
}
__device__ __forceinline__ float tanh_fast(float x){
  return 1.0f - 2.0f*__builtin_amdgcn_rcpf(__expf(2.0f*x) + 1.0f);
}
__device__ __forceinline__ unsigned short f2b(float f){
  unsigned int u = __float_as_uint(f);
  unsigned int r = (u + 0x7FFFu + ((u>>16)&1u)) >> 16;   // RNE
  return (unsigned short)r;
}
__device__ __forceinline__ float b2f(unsigned short b){
  return __uint_as_float(((unsigned int)b) << 16);
}

// ---------------- gather: embs[n,l,b,:] = itemEmb[seq[n,l,b],:] (+ bf16 shadow) ----------------
__global__ void k_gather(const int* __restrict__ seq, const float* __restrict__ itemEmb,
                         float* __restrict__ embs, unsigned short* __restrict__ ebh){
  int row = blockIdx.x;          // 0..51199 = (n,l,b)
  int t = threadIdx.x;           // 0..127
  int idx = seq[row];
  float v = itemEmb[idx*D_ + t];
  embs[row*D_ + t] = v;
  ebh[row*D_ + t] = f2b(v);
}

// ---------------- fc1: u[n] = dot(embs[n,:], fc1_w) + fc1_b ----------------
__global__ void k_fc1(const float* __restrict__ embs, const float* __restrict__ w,
                      const float* __restrict__ b, float* __restrict__ u){
  int n = blockIdx.x; int t = threadIdx.x;
  float s = 0.f;
  for (int i = t; i < LBD_; i += 256) s += embs[n*LBD_+i]*w[i];
  __shared__ float red[256];
  red[t]=s; __syncthreads();
  for (int o=128;o>0;o>>=1){ if(t<o) red[t]+=red[t+o]; __syncthreads(); }
  if(t==0) u[n]=red[0]+b[0];
}

// ---------------- uA[a,n,h] = tanh(tanh(u[n]*proju[a,h])) ----------------
// NOTE: keep libm tanh here — feeds kNN selection (keep selection bit-stable)
__global__ void k_ua(const float* __restrict__ u, const float* __restrict__ proju,
                     float* __restrict__ ua){
  int i = blockIdx.x*blockDim.x + threadIdx.x;
  if(i >= ASP_*N_*H_) return;
  int h = i % H_; int n = (i/H_) % N_; int a = i/(H_*N_);
  ua[i] = tanhf(tanhf(u[n]*proju[a*H_+h]));
}

// ---------------- sq[a,n] = sum_h uA^2 ----------------
__global__ void k_sq(const float* __restrict__ ua, float* __restrict__ sq){
  int an = blockIdx.x; int t = threadIdx.x;   // 128 threads
  float v = ua[an*H_ + t]; v *= v;
  __shared__ float red[128];
  red[t]=v; __syncthreads();
  for(int o=64;o>0;o>>=1){ if(t<o) red[t]+=red[t+o]; __syncthreads(); }
  if(t==0) sq[an]=red[0];
}

// ---------------- dist[a,n,m] ----------------
__global__ void k_dist(const float* __restrict__ ua, const float* __restrict__ sq,
                       float* __restrict__ dist){
  int n = blockIdx.x, a = blockIdx.y, m = threadIdx.x;  // 256 threads
  __shared__ float un[H_];
  if(m < H_) un[m] = ua[(a*N_+n)*H_ + m];
  __syncthreads();
  const float* um = &ua[(a*N_+m)*H_];
  float dot=0.f;
  for(int h=0;h<H_;h++) dot += un[h]*um[h];
  float dval = sq[a*N_+n] + sq[a*N_+m] - 2.f*dot;
  if(m==n) dval = -1.0f;
  dist[(a*N_+n)*N_ + m] = dval;
}

// ---------------- top-16 smallest, wave-parallel: 1 wave per (a,n) row ----------------
__global__ __launch_bounds__(256) void k_topk(const float* __restrict__ dist, int* __restrict__ nbr){
  int wid = blockIdx.x*(blockDim.x>>6) + (threadIdx.x>>6);  // row = (a*N_+n)
  if(wid >= ASP_*N_) return;
  int lane = threadIdx.x & 63;
  const float* row = &dist[(long)wid*N_];
  float v[4]; int idx[4];
  #pragma unroll
  for(int j=0;j<4;j++){ int m = lane*4 + j; v[j] = row[m]; idx[j] = m; }
  for(int k=0;k<KK_;k++){
    float bv = v[0]; int bi = idx[0];
    #pragma unroll
    for(int j=1;j<4;j++)
      if(v[j] < bv || (v[j]==bv && idx[j] < bi)){ bv=v[j]; bi=idx[j]; }
    float rv = bv; int ri = bi;
    #pragma unroll
    for(int o=32;o>0;o>>=1){
      float ov = __shfl_xor(rv, o, 64);
      int   oi = __shfl_xor(ri, o, 64);
      if(ov < rv || (ov==rv && oi < ri)){ rv=ov; ri=oi; }
    }
    if((ri>>2) == lane){ v[ri&3] = 3.4e38f; idx[ri&3] = 0x7fffffff; }
    if(k>0 && lane==0) nbr[wid*(KK_-1)+(k-1)] = ri;
  }
}

// ---------------- EB[n,l,d] = sum_b embs ----------------
__global__ void k_eb(const float* __restrict__ embs, float* __restrict__ eb){
  int nl = blockIdx.x; int d = threadIdx.x;
  float s=0.f;
  const float* p = &embs[nl*B_*D_ + d];
  for(int b=0;b<B_;b++) s += p[b*D_];
  eb[nl*D_ + d] = s;
}

// ---------------- projb[a,h,d] = bf16(aspProji[a,d,h]) ----------------
__global__ void k_projb(const float* __restrict__ proji, unsigned short* __restrict__ projb){
  int i = blockIdx.x*blockDim.x + threadIdx.x;
  if(i>=ASP_*D_*H_) return;
  int h=i%H_, d=(i/H_)%D_, a=i/(D_*H_);
  projb[(a*H_ + h)*D_ + d] = f2b(proji[i]);
}

// ---------------- fused UI stage: MFMA bf16 GEMM + tanh^2 + sum_b -> na[.., 0:128] ----------------
__global__ __launch_bounds__(256) void k_uimm(const unsigned short* __restrict__ ebh,
                                              const unsigned short* __restrict__ projb,
                                              float* __restrict__ na){
  __shared__ char smem[53248];
  unsigned short* As = (unsigned short*)smem;            // 80x128 bf16, swizzled 16B chunks
  unsigned short* Bs = (unsigned short*)(smem + 20480);  // 128x128 bf16, swizzled
  float*          Cs = (float*)smem;                     // 80x128 f32 (aliases As+Bs later)

  int mb = blockIdx.x;   // 0..639  -> nl0 = mb*8, A rows r0 = mb*80
  int a  = blockIdx.y;   // 0..3
  int tid = threadIdx.x;

  const unsigned short* asrc = ebh + (size_t)mb*10240;
  #pragma unroll
  for(int t=0;t<5;t++){
    int c = tid + t*256;
    int row = c >> 4;
    *(bf16x8*)(As + 8*(c ^ (row&7))) = *(const bf16x8*)(asrc + 8*c);
  }
  const unsigned short* bsrc = projb + a*16384;
  #pragma unroll
  for(int t=0;t<8;t++){
    int c = tid + t*256;
    int row = c >> 4;
    *(bf16x8*)(Bs + 8*(c ^ (row&7))) = *(const bf16x8*)(bsrc + 8*c);
  }
  __syncthreads();

  int lane = tid & 63, wave = tid >> 6;
  int l15 = lane & 15, l4 = lane >> 4;
  f32x4 acc[5][2] = {};
  #pragma unroll
  for(int kk=0;kk<4;kk++){
    bf16x8 bfr[2];
    #pragma unroll
    for(int tc=0;tc<2;tc++){
      int h = (wave*2+tc)*16 + l15;
      int c = h*16 + kk*4 + l4;
      bfr[tc] = *(const bf16x8*)(Bs + 8*(c ^ (h&7)));
    }
    #pragma unroll
    for(int tr=0;tr<5;tr++){
      int R = tr*16 + l15;
      int c = R*16 + kk*4 + l4;
      bf16x8 afr = *(const bf16x8*)(As + 8*(c ^ (R&7)));
      acc[tr][0] = __builtin_amdgcn_mfma_f32_16x16x32_bf16(afr, bfr[0], acc[tr][0], 0,0,0);
      acc[tr][1] = __builtin_amdgcn_mfma_f32_16x16x32_bf16(afr, bfr[1], acc[tr][1], 0,0,0);
    }
  }
  __syncthreads();

  #pragma unroll
  for(int tr=0;tr<5;tr++)
    #pragma unroll
    for(int tc=0;tc<2;tc++){
      int col = (wave*2+tc)*16 + l15;
      #pragma unroll
      for(int r=0;r<4;r++){
        int R = tr*16 + l4*4 + r;
        Cs[R*128 + col] = tanh_fast(tanh_fast(acc[tr][tc][r]));
      }
    }
  __syncthreads();

  #pragma unroll
  for(int t=0;t<4;t++){
    int oi = t*256 + tid;
    int g = oi >> 7, col = oi & 127;
    float s = 0.f;
    const float* p = Cs + g*1280 + col;
    #pragma unroll
    for(int b=0;b<10;b++) s += p[b*128];
    int nl = mb*8 + g;
    int n = nl/L_, l = nl%L_;
    na[((size_t)(n*ASP_+a)*L_ + l)*H2_ + col] = s;
  }
}

// ---------------- uHis_h: bf16 MFMA split-K (grid 4x4x25) ----------------
__global__ __launch_bounds__(256) void k_uhismm(const float* __restrict__ U,
    const float* __restrict__ W, const float* __restrict__ bias, float* __restrict__ C){
  __shared__ unsigned short As[2048];   // 64 rows x 32 k, chunk = q*64+row (8 bf16 each)
  __shared__ unsigned short Bs[2048];
  int tid = threadIdx.x;
  int m0 = blockIdx.y*64, n0 = blockIdx.x*64;
  int kb0 = blockIdx.z*800;
  int row = tid & 63, q = tid >> 6;
  int lane = tid & 63, wave = tid >> 6;
  int l15 = lane & 15, l4 = lane >> 4;
  int wr = (wave>>1)*32, wc = (wave&1)*32;
  f32x4 acc[2][2] = {};
  for(int s=0;s<25;s++){
    int k0 = kb0 + s*32 + q*8;
    {
      const float* pa = &U[(size_t)(m0+row)*NIT_ + k0];
      float4 a0 = *(const float4*)pa, a1 = *(const float4*)(pa+4);
      bf16x8 av;
      av[0]=f2b(a0.x); av[1]=f2b(a0.y); av[2]=f2b(a0.z); av[3]=f2b(a0.w);
      av[4]=f2b(a1.x); av[5]=f2b(a1.y); av[6]=f2b(a1.z); av[7]=f2b(a1.w);
      *(bf16x8*)(As + 8*tid) = av;
      const float* pb = &W[(size_t)(n0+row)*NIT_ + k0];
      float4 b0 = *(const float4*)pb, b1 = *(const float4*)(pb+4);
      bf16x8 bv;
      bv[0]=f2b(b0.x); bv[1]=f2b(b0.y); bv[2]=f2b(b0.z); bv[3]=f2b(b0.w);
      bv[4]=f2b(b1.x); bv[5]=f2b(b1.y); bv[6]=f2b(b1.z); bv[7]=f2b(b1.w);
      *(bf16x8*)(Bs + 8*tid) = bv;
    }
    __syncthreads();
    bf16x8 afr[2], bfr[2];
    #pragma unroll
    for(int mt=0;mt<2;mt++) afr[mt] = *(const bf16x8*)(As + 8*(l4*64 + wr + mt*16 + l15));
    #pragma unroll
    for(int nt=0;nt<2;nt++) bfr[nt] = *(const bf16x8*)(Bs + 8*(l4*64 + wc + nt*16 + l15));
    #pragma unroll
    for(int mt=0;mt<2;mt++)
      #pragma unroll
      for(int nt=0;nt<2;nt++)
        acc[mt][nt] = __builtin_amdgcn_mfma_f32_16x16x32_bf16(afr[mt], bfr[nt], acc[mt][nt], 0,0,0);
    __syncthreads();
  }
  #pragma unroll
  for(int mt=0;mt<2;mt++)
    #pragma unroll
    for(int nt=0;nt<2;nt++){
      int col = n0 + wc + nt*16 + l15;
      #pragma unroll
      for(int r=0;r<4;r++){
        int rw = m0 + wr + mt*16 + l4*4 + r;
        float v = acc[mt][nt][r];
        if(blockIdx.z==0) v += bias[col];
        atomicAdd(&C[rw*H2_ + col], v);
      }
    }
}

// ---------------- xg GEMM: bf16 MFMA, in-register cast, OUTPUT bf16 ----------------
__global__ __launch_bounds__(256) void k_xgmm(const float* __restrict__ A_,
    const float* __restrict__ W, const float* __restrict__ bias,
    unsigned short* __restrict__ Cb){
  __shared__ unsigned short As[2048];
  __shared__ unsigned short Bs[2048];
  int tid = threadIdx.x;
  int n0 = blockIdx.x*64, m0 = blockIdx.y*64;
  int row = tid & 63, q = tid >> 6;
  int lane = tid & 63, wave = tid >> 6;
  int l15 = lane & 15, l4 = lane >> 4;
  int wr = (wave>>1)*32, wc = (wave&1)*32;
  f32x4 acc[2][2] = {};
  for(int s=0;s<8;s++){
    int k0 = s*32 + q*8;
    {
      const float* pa = &A_[(size_t)(m0+row)*H2_ + k0];
      float4 a0 = *(const float4*)pa, a1 = *(const float4*)(pa+4);
      bf16x8 av;
      av[0]=f2b(a0.x); av[1]=f2b(a0.y); av[2]=f2b(a0.z); av[3]=f2b(a0.w);
      av[4]=f2b(a1.x); av[5]=f2b(a1.y); av[6]=f2b(a1.z); av[7]=f2b(a1.w);
      *(bf16x8*)(As + 8*tid) = av;
      const float* pb = &W[(size_t)(n0+row)*H2_ + k0];
      float4 b0 = *(const float4*)pb, b1 = *(const float4*)(pb+4);
      bf16x8 bv;
      bv[0]=f2b(b0.x); bv[1]=f2b(b0.y); bv[2]=f2b(b0.z); bv[3]=f2b(b0.w);
      bv[4]=f2b(b1.x); bv[5]=f2b(b1.y); bv[6]=f2b(b1.z); bv[7]=f2b(b1.w);
      *(bf16x8*)(Bs + 8*tid) = bv;
    }
    __syncthreads();
    bf16x8 afr[2], bfr[2];
    #pragma unroll
    for(int mt=0;mt<2;mt++) afr[mt] = *(const bf16x8*)(As + 8*(l4*64 + wr + mt*16 + l15));
    #pragma unroll
    for(int nt=0;nt<2;nt++) bfr[nt] = *(const bf16x8*)(Bs + 8*(l4*64 + wc + nt*16 + l15));
    #pragma unroll
    for(int mt=0;mt<2;mt++)
      #pragma unroll
      for(int nt=0;nt<2;nt++)
        acc[mt][nt] = __builtin_amdgcn_mfma_f32_16x16x32_bf16(afr[mt], bfr[nt], acc[mt][nt], 0,0,0);
    __syncthreads();
  }
  #pragma unroll
  for(int mt=0;mt<2;mt++)
    #pragma unroll
    for(int nt=0;nt<2;nt++){
      int col = n0 + wc + nt*16 + l15;
      float bs = bias[col];
      #pragma unroll
      for(int r=0;r<4;r++){
        int rw = m0 + wr + mt*16 + l4*4 + r;
        Cb[(size_t)rw*G4_ + col] = f2b(acc[mt][nt][r] + bs);
      }
    }
}

// ---------------- cast out_w -> bf16 ----------------
__global__ void k_outb(const float* __restrict__ w, unsigned short* __restrict__ wb){
  int i = blockIdx.x*blockDim.x + threadIdx.x;   // 640000 threads, 8 elems each
  const float* p = w + (size_t)i*8;
  float4 a = *(const float4*)p, b = *(const float4*)(p+4);
  bf16x8 v;
  v[0]=f2b(a.x); v[1]=f2b(a.y); v[2]=f2b(a.z); v[3]=f2b(a.w);
  v[4]=f2b(b.x); v[5]=f2b(b.y); v[6]=f2b(b.z); v[7]=f2b(b.w);
  *(bf16x8*)(wb + (size_t)i*8) = v;
}

// ---------------- logits: bf16 MFMA, tile 256x32, grid 625, frags straight from L2 ----------------
__global__ __launch_bounds__(256) void k_logitsmm(const unsigned short* __restrict__ Ab,
    const unsigned short* __restrict__ Wb, const float* __restrict__ bias,
    float* __restrict__ C){
  int n0 = blockIdx.x*32;
  int tid = threadIdx.x;
  int lane = tid & 63, wave = tid >> 6;
  int l15 = lane & 15, l4 = lane >> 4;
  f32x4 acc[4][2] = {};
  #pragma unroll
  for(int kk=0;kk<8;kk++){
    int k0 = kk*32 + l4*8;
    bf16x8 bfr[2];
    #pragma unroll
    for(int nt=0;nt<2;nt++)
      bfr[nt] = *(const bf16x8*)(Wb + (size_t)(n0 + nt*16 + l15)*H2_ + k0);
    #pragma unroll
    for(int mt=0;mt<4;mt++){
      bf16x8 afr = *(const bf16x8*)(Ab + (size_t)(wave*64 + mt*16 + l15)*H2_ + k0);
      acc[mt][0] = __builtin_amdgcn_mfma_f32_16x16x32_bf16(afr, bfr[0], acc[mt][0], 0,0,0);
      acc[mt][1] = __builtin_amdgcn_mfma_f32_16x16x32_bf16(afr, bfr[1], acc[mt][1], 0,0,0);
    }
  }
  #pragma unroll
  for(int mt=0;mt<4;mt++)
    #pragma unroll
    for(int nt=0;nt<2;nt++){
      int col = n0 + nt*16 + l15;
      float bs = bias[col];
      #pragma unroll
      for(int r=0;r<4;r++){
        int row = wave*64 + mt*16 + l4*4 + r;
        C[(size_t)row*NIT_ + col] = acc[mt][nt][r] + bs;
      }
    }
}

// ---------------- generic fp32 NT GEMM (E2 only now) ----------------
__global__ __launch_bounds__(256) void k_gemm(const float* __restrict__ A, const float* __restrict__ W,
    float* __restrict__ C, const float* __restrict__ bias,
    int M, int Nn, int K, int kchunk, int atomic_mode){
  __shared__ float As[64][17];
  __shared__ float Ws[64][17];
  int tid = threadIdx.x;
  int tx = tid & 15, ty = tid >> 4;
  int m0 = blockIdx.y*64, n0 = blockIdx.x*64;
  int kb0 = blockIdx.z*kchunk;
  int kend = kb0 + kchunk; if(kend > K) kend = K;
  float acc[4][4] = {};
  int lrow = tid >> 2;
  int lc4 = (tid & 3) * 4;
  for(int kb = kb0; kb < kend; kb += 16){
    {
      int gr = m0 + lrow;
      float4 v = make_float4(0,0,0,0);
      if(gr < M) v = *(const float4*)&A[(long)gr*K + kb + lc4];
      As[lrow][lc4+0]=v.x; As[lrow][lc4+1]=v.y; As[lrow][lc4+2]=v.z; As[lrow][lc4+3]=v.w;
      int gw = n0 + lrow;
      float4 u = make_float4(0,0,0,0);
      if(gw < Nn) u = *(const float4*)&W[(long)gw*K + kb + lc4];
      Ws[lrow][lc4+0]=u.x; Ws[lrow][lc4+1]=u.y; Ws[lrow][lc4+2]=u.z; Ws[lrow][lc4+3]=u.w;
    }
    __syncthreads();
    for(int k=0;k<16;k++){
      float av[4], wv[4];
      #pragma unroll
      for(int r=0;r<4;r++) av[r]=As[ty*4+r][k];
      #pragma unroll
      for(int c=0;c<4;c++) wv[c]=Ws[tx*4+c][k];
      #pragma unroll
      for(int r=0;r<4;r++)
        #pragma unroll
        for(int c=0;c<4;c++) acc[r][c] += av[r]*wv[c];
    }
    __syncthreads();
  }
  for(int r=0;r<4;r++){
    int row = m0 + ty*4 + r; if(row >= M) continue;
    for(int c=0;c<4;c++){
      int col = n0 + tx*4 + c; if(col >= Nn) continue;
      float v = acc[r][c];
      if(bias && blockIdx.z==0) v += bias[col];
      if(atomic_mode) atomicAdd(&C[(long)row*Nn+col], v);
      else C[(long)row*Nn+col] = v;
    }
  }
}

// ---------------- PI: na[n,a,l,128:256] = sum_nbr E2[nbr,l,h] + B*dh_b[h] ----------------
__global__ void k_pi(const float* __restrict__ e2, const int* __restrict__ nbr,
                     const float* __restrict__ dh_b, float* __restrict__ na){
  int n = blockIdx.x, a = blockIdx.y, h = threadIdx.x; // 128
  __shared__ int nb[KK_-1];
  if(h < KK_-1) nb[h] = nbr[(a*N_+n)*(KK_-1)+h];
  __syncthreads();
  float bias = (float)B_ * dh_b[h];
  for(int l=0;l<L_;l++){
    float s = bias;
    for(int k=0;k<KK_-1;k++) s += e2[(long)(nb[k]*L_ + l)*H_ + h];
    na[((long)(n*ASP_+a)*L_ + l)*H2_ + H_ + h] = s;
  }
}

// ---------------- x: flat reinterpret max over 4 consecutive ----------------
__global__ void k_xmax(const float* __restrict__ na, float* __restrict__ x){
  int i = blockIdx.x*blockDim.x + threadIdx.x;
  if(i >= N_*L_*H2_) return;
  int n = i / (L_*H2_);
  int j = i % (L_*H2_);
  const float* p = &na[(long)n*ASP_*L_*H2_ + 4*j];
  x[i] = fmaxf(fmaxf(p[0],p[1]), fmaxf(p[2],p[3]));
}

// ---------------- LSTM weight permute (fp32, for wih used by xg GEMM) ----------------
__global__ void k_perm(const float* __restrict__ src, float* __restrict__ dst){
  int i = blockIdx.x*blockDim.x + threadIdx.x;
  if(i >= G4_*H2_) return;
  int k = i % H2_; int j = i / H2_;
  int g = j / H2_, jj = j % H2_;
  dst[(jj*4+g)*H2_ + k] = src[i];
}
// ---------------- LSTM recurrent weight permute + bf16 cast ----------------
__global__ void k_permh(const float* __restrict__ src, unsigned short* __restrict__ dst){
  int i = blockIdx.x*blockDim.x + threadIdx.x;
  if(i >= G4_*H2_) return;
  int k = i % H2_; int j = i / H2_;
  int g = j / H2_, jj = j % H2_;
  dst[(jj*4+g)*H2_ + k] = f2b(src[i]);
}
__global__ void k_permb(const float* __restrict__ bih, const float* __restrict__ bhh,
                        float* __restrict__ bp){
  int j = blockIdx.x*blockDim.x + threadIdx.x;
  if(j >= G4_) return;
  int g = j / H2_, jj = j % H2_;
  bp[jj*4+g] = bih[j] + bhh[j];
}

// ---------------- fused LSTM layer: per-CU load-byte bound -> cut bytes ----------------
// 16 blocks x 1024 thr (16 waves). Transposed MFMA (r10-verified mapping).
// r13: (1) each wave's gate-tile 0 cached in LDS once (128KB) -> streamed weights
// 512->384KB/step; (2) xg is bf16 (32KB/step). h dbuf 16KB; total LDS 144KB.
__global__ __launch_bounds__(1024) void k_lstm_layer(
    const unsigned short* __restrict__ Whb,   // [1024][256] bf16 permuted (col=jj*4+g)
    const unsigned short* __restrict__ xgb,   // [256][20][1024] bf16 ih products
    float* __restrict__ Y){                   // [256][20][256] fp32 h sequence
  __shared__ unsigned short wc[65536];        // 128 KB: 16 waves x 8KB (gate-tile 0 each)
  __shared__ unsigned short hs[2][16*H2_];    // 2 x 8 KB, chunk ch=s*32+k/8, swz ^(s&7)
  int tid = threadIdx.x;
  int n0 = blockIdx.x * 16;
  int lane = tid & 63, wave = tid >> 6;       // wave 0..15, owns gate tiles wave*4..+3
  int l15 = lane & 15, l4 = lane >> 4;
  int n = n0 + l15;                            // this lane's sample
  float creg[4] = {0.f,0.f,0.f,0.f};
  // preload wave's gate-tile 0 into LDS (once for all 20 steps)
  {
    int ct0 = wave*4;
    #pragma unroll
    for(int it=0; it<8; it++){
      int c = it*64 + lane;                   // 0..511 chunks of 8 bf16
      int row = c >> 5;
      bf16x8 w8 = *(const bf16x8*)(Whb + (size_t)(ct0*16+row)*H2_ + (c&31)*8);
      *(bf16x8*)(wc + 8*((wave<<9) + (c ^ (row&7)))) = w8;
    }
  }
  const unsigned short* wptr[3];
  #pragma unroll
  for(int i=0;i<3;i++) wptr[i] = Whb + (size_t)((wave*4+1+i)*16 + l15)*H2_ + l4*8;
  const unsigned short* wc0 = wc + (wave<<12);   // wave's 8KB slice (4096 ushorts)
  __syncthreads();
  for(int t=0; t<L_; t++){
    // xg(t) loads issued early (bf16x4 per gate quad)
    bf16x4 xgv[4];
    #pragma unroll
    for(int i=0;i<4;i++){
      int jj = wave*16 + i*4 + l4;
      xgv[i] = *(const bf16x4*)(xgb + ((size_t)n*L_ + t)*G4_ + jj*4);
    }
    f32x4 acc[4] = {};
    if(t > 0){
      const unsigned short* hbuf = hs[(t+1)&1];   // holds h(t-1)
      bf16x8 hfr[8];
      #pragma unroll
      for(int kk=0; kk<8; kk++){
        int ch = l15*32 + kk*4 + l4;
        hfr[kk] = *(const bf16x8*)(hbuf + 8*(ch ^ (l15&7)));
      }
      #pragma unroll
      for(int kk=0; kk<8; kk++){
        bf16x8 wfr[4];
        // tile 0 from LDS cache, tiles 1..3 streamed from L2
        wfr[0] = *(const bf16x8*)(wc0 + 8*((l15*32 + kk*4 + l4) ^ (l15&7)));
        #pragma unroll
        for(int i=0;i<3;i++) wfr[1+i] = *(const bf16x8*)(wptr[i] + kk*32);
        #pragma unroll
        for(int i=0;i<4;i++)
          acc[i] = __builtin_amdgcn_mfma_f32_16x16x32_bf16(wfr[i], hfr[kk], acc[i], 0,0,0);
      }
    }
    // epilogue writes the OTHER h buffer — no mid-step barrier
    unsigned short* hout = hs[t&1];
    #pragma unroll
    for(int i=0;i<4;i++){
      int jj = wave*16 + i*4 + l4;
      float gi = acc[i][0] + b2f((unsigned short)xgv[i][0]);
      float gf = acc[i][1] + b2f((unsigned short)xgv[i][1]);
      float gg = acc[i][2] + b2f((unsigned short)xgv[i][2]);
      float go = acc[i][3] + b2f((unsigned short)xgv[i][3]);
      float cnew = sigf_fast(gf)*creg[i] + sigf_fast(gi)*tanh_fast(gg);
      creg[i] = cnew;
      float hnew = sigf_fast(go)*tanh_fast(cnew);
      Y[((size_t)n*L_ + t)*H2_ + jj] = hnew;
      int ch = l15*32 + (jj>>3);
      *(unsigned short*)((char*)hout + 16*(ch ^ (l15&7)) + (jj&7)*2) = f2b(hnew);
    }
    __syncthreads();   // h(t) visible before step t+1's reads
  }
}

// ---------------- h_agg = tanh(sum_t y1) (+ bf16 shadow) ----------------
__global__ void k_hagg(const float* __restrict__ y1, float* __restrict__ hagg,
                       unsigned short* __restrict__ haggb){
  int i = blockIdx.x*blockDim.x + threadIdx.x;
  if(i>=N_*H2_) return;
  int n = i / H2_, jj = i % H2_;
  float s=0.f;
  for(int t=0;t<L_;t++) s += y1[((long)n*L_+t)*H2_ + jj];
  float v = tanhf(s);
  hagg[i] = v;
  haggb[i] = f2b(v);
}

// ---------------- gate ----------------
__global__ void k_gate(const float* __restrict__ uhish, const float* __restrict__ hagg,
                       const float* __restrict__ g1w, const float* __restrict__ g1b,
                       const float* __restrict__ g2w, const float* __restrict__ g2b,
                       float* __restrict__ gate){
  int n = blockIdx.x; int t = threadIdx.x; // 256
  float s = uhish[n*H2_+t]*g1w[t] + hagg[n*H2_+t]*g2w[t];
  __shared__ float red[256];
  red[t]=s; __syncthreads();
  for(int o=128;o>0;o>>=1){ if(t<o) red[t]+=red[t+o]; __syncthreads(); }
  if(t==0) gate[n] = 1.f/(1.f+expf(-(red[0]+g1b[0]+g2b[0])));
}

// ---------------- softmax row stats ----------------
__global__ void k_smstat(const float* __restrict__ logits, float* __restrict__ rowmax,
                         float* __restrict__ rowsum){
  int n = blockIdx.x; int t = threadIdx.x;
  const float* row = &logits[(long)n*NIT_];
  float m = -3.4e38f;
  for(int i=t;i<NIT_;i+=256) m = fmaxf(m, row[i]);
  __shared__ float red[256];
  __shared__ float mm;
  red[t]=m; __syncthreads();
  for(int o=128;o>0;o>>=1){ if(t<o) red[t]=fmaxf(red[t],red[t+o]); __syncthreads(); }
  if(t==0){ mm = red[0]; rowmax[n]=red[0]; }
  __syncthreads();
  float s=0.f;
  for(int i=t;i<NIT_;i+=256) s += __expf(row[i]-mm);
  __syncthreads();
  red[t]=s; __syncthreads();
  for(int o=128;o>0;o>>=1){ if(t<o) red[t]+=red[t+o]; __syncthreads(); }
  if(t==0) rowsum[n]=red[0];
}

// ---------------- final ----------------
__global__ void k_final(const float* __restrict__ logits, const float* __restrict__ rowmax,
                        const float* __restrict__ rowsum, const float* __restrict__ gate,
                        const float* __restrict__ uHis, float* __restrict__ out){
  int i = blockIdx.x*blockDim.x + threadIdx.x;
  if(i >= N_*NIT_) return;
  int n = i / NIT_;
  float g = gate[n];
  float p = __expf(logits[i]-rowmax[n]) / rowsum[n];
  out[i] = g*p + (1.f-g)*uHis[i];
}

extern "C" void kernel_launch(void* const* d_in, const int* in_sizes, int n_in,
                              void* d_out, int out_size, void* d_ws, size_t ws_size,
                              hipStream_t stream) {
  const int*   seq     = (const int*)  d_in[0];
  const float* uHis    = (const float*)d_in[1];
  const float* itemEmb = (const float*)d_in[2];
  const float* fc1_w   = (const float*)d_in[3];
  const float* fc1_b   = (const float*)d_in[4];
  const float* aspProju= (const float*)d_in[5];
  const float* aspProji= (const float*)d_in[6];
  const float* dh_w    = (const float*)d_in[7];
  const float* dh_b    = (const float*)d_in[8];
  const float* wih0    = (const float*)d_in[9];
  const float* whh0    = (const float*)d_in[10];
  const float* bih0    = (const float*)d_in[11];
  const float* bhh0    = (const float*)d_in[12];
  const float* wih1    = (const float*)d_in[13];
  const float* whh1    = (const float*)d_in[14];
  const float* bih1    = (const float*)d_in[15];
  const float* bhh1    = (const float*)d_in[16];
  const float* out_w   = (const float*)d_in[17];
  const float* out_b   = (const float*)d_in[18];
  const float* his_w   = (const float*)d_in[19];
  const float* his_b   = (const float*)d_in[20];
  const float* g1_w    = (const float*)d_in[21];
  const float* g1_b    = (const float*)d_in[22];
  const float* g2_w    = (const float*)d_in[23];
  const float* g2_b    = (const float*)d_in[24];

  float* ws = (float*)d_ws;
  float* embs = ws + 0;            // 6,553,600   (reused as logits later)
  float* cub  = ws + 6553600;      // 6,553,600   (ebh bf16 shadow; reused as xgb bf16 later)
  float* na   = ws + 13107200;     // 5,242,880   (reused as outwb bf16 after xmax)
  float* x    = ws + 18350080;     // 1,310,720   (reused as haggb after xg0)
  float* y0   = ws + 19660800;     // 1,310,720
  float* y1   = ws + 20971520;     // 1,310,720
  float* eb   = ws + 22282240;     //   655,360
  float* e2   = ws + 22937600;     //   655,360
  float* dist = ws + 23592960;     //   262,144
  float* ua   = ws + 23855104;     //   131,072
  float* projT= ws + 23986176;     //    65,536  (holds projb bf16)
  float* wp0  = ws + 24051712;     //   262,144  (fp32 permuted wih0)
  float* whp0 = ws + 24313856;     //   262,144  (bf16 permuted whh0 lives here)
  float* wp1  = ws + 24576000;     //   262,144  (fp32 permuted wih1)
  float* whp1 = ws + 24838144;     //   262,144  (bf16 permuted whh1 lives here)
  float* bp0  = ws + 25100288;     //     1,024
  float* bp1  = ws + 25101312;     //     1,024
  float* uemb = ws + 25167872;     //       256
  float* sqb  = ws + 25168128;     //     1,024
  int*   nbr  = (int*)(ws + 25169152); // 15,360 ints
  float* uhish= ws + 25184512;     //    65,536
  float* hagg = ws + 25250048;     //    65,536
  float* rowmax=ws + 25315584;     //       256
  float* rowsum=ws + 25315840;     //       256
  float* gateb =ws + 25316096;     //       256
  float* logits = embs;            // reuse
  unsigned short* ebh   = (unsigned short*)cub;   // bf16 shadow (inside cub slot)
  unsigned short* xgb   = (unsigned short*)cub;   // bf16 xg (ebh dead after k_uimm)
  unsigned short* projb = (unsigned short*)projT; // bf16 (inside projT slot)
  unsigned short* outwb = (unsigned short*)na;    // bf16 out_w (na dead after xmax)
  unsigned short* haggb = (unsigned short*)x;     // bf16 hagg (x dead after xg0)
  unsigned short* whb0  = (unsigned short*)whp0;  // bf16 permuted whh0
  unsigned short* whb1  = (unsigned short*)whp1;  // bf16 permuted whh1

  // 1. embedding gather (fp32 + bf16 shadow)
  k_gather<<<NLB_, D_, 0, stream>>>(seq, itemEmb, embs, ebh);
  // 2. fc1 -> u_embs
  k_fc1<<<N_, 256, 0, stream>>>(embs, fc1_w, fc1_b, uemb);
  // 3. uA
  k_ua<<<(ASP_*N_*H_+255)/256, 256, 0, stream>>>(uemb, aspProju, ua);
  // 4. sq
  k_sq<<<ASP_*N_, 128, 0, stream>>>(ua, sqb);
  // 5. dist
  k_dist<<<dim3(N_,ASP_), 256, 0, stream>>>(ua, sqb, dist);
  // 6. top-k neighbors
  k_topk<<<ASP_*N_/4, 256, 0, stream>>>(dist, nbr);
  // 7. EB = sum_b embs
  k_eb<<<NL_, D_, 0, stream>>>(embs, eb);
  // 8. E2 = EB @ dh_w^T
  k_gemm<<<dim3(2, 80, 1), 256, 0, stream>>>(eb, dh_w, e2, nullptr, NL_, H_, D_, D_, 0);
  // 9. projb (bf16 transposed proj)
  k_projb<<<(ASP_*D_*H_+255)/256, 256, 0, stream>>>(aspProji, projb);
  // 10. fused UI stage: MFMA + tanh^2 + sum_b
  k_uimm<<<dim3(NL_/8, ASP_), 256, 0, stream>>>(ebh, projb, na);
  // 11. PI (neighbor sums)
  k_pi<<<dim3(N_,ASP_), H_, 0, stream>>>(e2, nbr, dh_b, na);
  // 12. x = flat max-4
  k_xmax<<<(N_*L_*H2_+255)/256, 256, 0, stream>>>(na, x);
  // 12b. cast out_w -> bf16 (into dead na region)
  k_outb<<<2500, 256, 0, stream>>>(out_w, outwb);
  // 13. LSTM weight permutes: wih fp32, whh bf16
  k_perm <<<(G4_*H2_+255)/256,256,0,stream>>>(wih0, wp0);
  k_permh<<<(G4_*H2_+255)/256,256,0,stream>>>(whh0, whb0);
  k_perm <<<(G4_*H2_+255)/256,256,0,stream>>>(wih1, wp1);
  k_permh<<<(G4_*H2_+255)/256,256,0,stream>>>(whh1, whb1);
  k_permb<<<4,256,0,stream>>>(bih0,bhh0,bp0);
  k_permb<<<4,256,0,stream>>>(bih1,bhh1,bp1);
  // 14. xg0 = x @ wp0^T + bp0 : bf16 MFMA, bf16 output
  k_xgmm<<<dim3(16,80), 256, 0, stream>>>(x, wp0, bp0, xgb);
  // 15. LSTM layer 0: ONE launch (weight LDS-cache + bf16 xg)
  k_lstm_layer<<<16, 1024, 0, stream>>>(whb0, xgb, y0);
  // 16. xg1 = y0 @ wp1^T + bp1 : bf16 MFMA, bf16 output
  k_xgmm<<<dim3(16,80), 256, 0, stream>>>(y0, wp1, bp1, xgb);
  // 17. LSTM layer 1
  k_lstm_layer<<<16, 1024, 0, stream>>>(whb1, xgb, y1);
  // 18. h_agg (+ bf16 shadow into dead x region)
  k_hagg<<<(N_*H2_+255)/256,256,0,stream>>>(y1, hagg, haggb);
  // 19. logits = h_agg @ out_w^T + out_b : bf16 MFMA (grid 625, tile 256x32)
  k_logitsmm<<<625, 256, 0, stream>>>(haggb, outwb, out_b, logits);
  // 20. uHis_h = uHis @ his_w^T + his_b : bf16 MFMA split-K
  hipMemsetAsync(uhish, 0, N_*H2_*sizeof(float), stream);
  k_uhismm<<<dim3(4,4,25), 256, 0, stream>>>(uHis, his_w, his_b, uhish);
  // 21. gate
  k_gate<<<N_,256,0,stream>>>(uhish, hagg, g1_w, g1_b, g2_w, g2_b, gateb);
  // 22. softmax stats
  k_smstat<<<N_,256,0,stream>>>(logits, rowmax, rowsum);
  // 23. final scores
  k_final<<<(N_*NIT_+255)/256,256,0,stream>>>(logits, rowmax, rowsum, gateb, uHis, (float*)d_out);
}

// Round 16
// 516.290 us; speedup vs baseline: 3.0038x; 1.0578x over previous
//
#include <hip/hip_runtime.h>
#include <math.h>

#define N_ 256
#define L_ 20
#define B_ 10
#define D_ 128
#define H_ 128
#define ASP_ 4
#define KK_ 16
#define NIT_ 20000
#define H2_ 256
#define G4_ 1024
#define LBD_ 25600
#define NL_ 5120
#define NLB_ 51200

typedef __attribute__((ext_vector_type(8))) short bf16x8;
typedef __attribute__((ext_vector_type(4))) short bf16x4;
typedef __attribute__((ext_vector_type(4))) float f32x4;

__device__ __forceinline__ float sigf(float x){ return 1.0f/(1.0f+expf(-x)); }
__device__ __forceinline__ float sigf_fast(float x){
  return __builtin_amdgcn_rcpf(1.0f + __expf(-x));
}
__device__ __forceinline__ float tanh_fast(float x){
  return 1.0f - 2.0f*__builtin_amdgcn_rcpf(__expf(2.0f*x) + 1.0f);
}
__device__ __forceinline__ unsigned short f2b(float f){
  unsigned int u = __float_as_uint(f);
  unsigned int r = (u + 0x7FFFu + ((u>>16)&1u)) >> 16;   // RNE
  return (unsigned short)r;
}
__device__ __forceinline__ float b2f(unsigned short b){
  return __uint_as_float(((unsigned int)b) << 16);
}

// ---------------- gather: embs[n,l,b,:] = itemEmb[seq[n,l,b],:] (+ bf16 shadow) ----------------
__global__ void k_gather(const int* __restrict__ seq, const float* __restrict__ itemEmb,
                         float* __restrict__ embs, unsigned short* __restrict__ ebh){
  int row = blockIdx.x;          // 0..51199 = (n,l,b)
  int t = threadIdx.x;           // 0..127
  int idx = seq[row];
  float v = itemEmb[idx*D_ + t];
  embs[row*D_ + t] = v;
  ebh[row*D_ + t] = f2b(v);
}

// ---------------- fc1: u[n] = dot(embs[n,:], fc1_w) + fc1_b ----------------
__global__ void k_fc1(const float* __restrict__ embs, const float* __restrict__ w,
                      const float* __restrict__ b, float* __restrict__ u){
  int n = blockIdx.x; int t = threadIdx.x;
  float s = 0.f;
  for (int i = t; i < LBD_; i += 256) s += embs[n*LBD_+i]*w[i];
  __shared__ float red[256];
  red[t]=s; __syncthreads();
  for (int o=128;o>0;o>>=1){ if(t<o) red[t]+=red[t+o]; __syncthreads(); }
  if(t==0) u[n]=red[0]+b[0];
}

// ---------------- uA[a,n,h] = tanh(tanh(u[n]*proju[a,h])) (libm: feeds kNN selection) ----------------
__global__ void k_ua(const float* __restrict__ u, const float* __restrict__ proju,
                     float* __restrict__ ua){
  int i = blockIdx.x*blockDim.x + threadIdx.x;
  if(i >= ASP_*N_*H_) return;
  int h = i % H_; int n = (i/H_) % N_; int a = i/(H_*N_);
  ua[i] = tanhf(tanhf(u[n]*proju[a*H_+h]));
}

// ---------------- sq[a,n] = sum_h uA^2 ----------------
__global__ void k_sq(const float* __restrict__ ua, float* __restrict__ sq){
  int an = blockIdx.x; int t = threadIdx.x;   // 128 threads
  float v = ua[an*H_ + t]; v *= v;
  __shared__ float red[128];
  red[t]=v; __syncthreads();
  for(int o=64;o>0;o>>=1){ if(t<o) red[t]+=red[t+o]; __syncthreads(); }
  if(t==0) sq[an]=red[0];
}

// ---------------- dist[a,n,m] ----------------
__global__ void k_dist(const float* __restrict__ ua, const float* __restrict__ sq,
                       float* __restrict__ dist){
  int n = blockIdx.x, a = blockIdx.y, m = threadIdx.x;  // 256 threads
  __shared__ float un[H_];
  if(m < H_) un[m] = ua[(a*N_+n)*H_ + m];
  __syncthreads();
  const float* um = &ua[(a*N_+m)*H_];
  float dot=0.f;
  for(int h=0;h<H_;h++) dot += un[h]*um[h];
  float dval = sq[a*N_+n] + sq[a*N_+m] - 2.f*dot;
  if(m==n) dval = -1.0f;
  dist[(a*N_+n)*N_ + m] = dval;
}

// ---------------- top-16 smallest, wave-parallel: 1 wave per (a,n) row ----------------
__global__ __launch_bounds__(256) void k_topk(const float* __restrict__ dist, int* __restrict__ nbr){
  int wid = blockIdx.x*(blockDim.x>>6) + (threadIdx.x>>6);  // row = (a*N_+n)
  if(wid >= ASP_*N_) return;
  int lane = threadIdx.x & 63;
  const float* row = &dist[(long)wid*N_];
  float v[4]; int idx[4];
  #pragma unroll
  for(int j=0;j<4;j++){ int m = lane*4 + j; v[j] = row[m]; idx[j] = m; }
  for(int k=0;k<KK_;k++){
    float bv = v[0]; int bi = idx[0];
    #pragma unroll
    for(int j=1;j<4;j++)
      if(v[j] < bv || (v[j]==bv && idx[j] < bi)){ bv=v[j]; bi=idx[j]; }
    float rv = bv; int ri = bi;
    #pragma unroll
    for(int o=32;o>0;o>>=1){
      float ov = __shfl_xor(rv, o, 64);
      int   oi = __shfl_xor(ri, o, 64);
      if(ov < rv || (ov==rv && oi < ri)){ rv=ov; ri=oi; }
    }
    if((ri>>2) == lane){ v[ri&3] = 3.4e38f; idx[ri&3] = 0x7fffffff; }
    if(k>0 && lane==0) nbr[wid*(KK_-1)+(k-1)] = ri;
  }
}

// ---------------- EB[n,l,d] = sum_b embs ----------------
__global__ void k_eb(const float* __restrict__ embs, float* __restrict__ eb){
  int nl = blockIdx.x; int d = threadIdx.x;
  float s=0.f;
  const float* p = &embs[nl*B_*D_ + d];
  for(int b=0;b<B_;b++) s += p[b*D_];
  eb[nl*D_ + d] = s;
}

// ---------------- projb[a,h,d] = bf16(aspProji[a,d,h]) ----------------
__global__ void k_projb(const float* __restrict__ proji, unsigned short* __restrict__ projb){
  int i = blockIdx.x*blockDim.x + threadIdx.x;
  if(i>=ASP_*D_*H_) return;
  int h=i%H_, d=(i/H_)%D_, a=i/(D_*H_);
  projb[(a*H_ + h)*D_ + d] = f2b(proji[i]);
}

// ---------------- fused UI stage: MFMA bf16 GEMM + tanh^2 + sum_b -> na[.., 0:128] ----------------
__global__ __launch_bounds__(256) void k_uimm(const unsigned short* __restrict__ ebh,
                                              const unsigned short* __restrict__ projb,
                                              float* __restrict__ na){
  __shared__ char smem[53248];
  unsigned short* As = (unsigned short*)smem;            // 80x128 bf16, swizzled 16B chunks
  unsigned short* Bs = (unsigned short*)(smem + 20480);  // 128x128 bf16, swizzled
  float*          Cs = (float*)smem;                     // 80x128 f32 (aliases As+Bs later)

  int mb = blockIdx.x;   // 0..639  -> nl0 = mb*8, A rows r0 = mb*80
  int a  = blockIdx.y;   // 0..3
  int tid = threadIdx.x;

  const unsigned short* asrc = ebh + (size_t)mb*10240;
  #pragma unroll
  for(int t=0;t<5;t++){
    int c = tid + t*256;
    int row = c >> 4;
    *(bf16x8*)(As + 8*(c ^ (row&7))) = *(const bf16x8*)(asrc + 8*c);
  }
  const unsigned short* bsrc = projb + a*16384;
  #pragma unroll
  for(int t=0;t<8;t++){
    int c = tid + t*256;
    int row = c >> 4;
    *(bf16x8*)(Bs + 8*(c ^ (row&7))) = *(const bf16x8*)(bsrc + 8*c);
  }
  __syncthreads();

  int lane = tid & 63, wave = tid >> 6;
  int l15 = lane & 15, l4 = lane >> 4;
  f32x4 acc[5][2] = {};
  #pragma unroll
  for(int kk=0;kk<4;kk++){
    bf16x8 bfr[2];
    #pragma unroll
    for(int tc=0;tc<2;tc++){
      int h = (wave*2+tc)*16 + l15;
      int c = h*16 + kk*4 + l4;
      bfr[tc] = *(const bf16x8*)(Bs + 8*(c ^ (h&7)));
    }
    #pragma unroll
    for(int tr=0;tr<5;tr++){
      int R = tr*16 + l15;
      int c = R*16 + kk*4 + l4;
      bf16x8 afr = *(const bf16x8*)(As + 8*(c ^ (R&7)));
      acc[tr][0] = __builtin_amdgcn_mfma_f32_16x16x32_bf16(afr, bfr[0], acc[tr][0], 0,0,0);
      acc[tr][1] = __builtin_amdgcn_mfma_f32_16x16x32_bf16(afr, bfr[1], acc[tr][1], 0,0,0);
    }
  }
  __syncthreads();

  #pragma unroll
  for(int tr=0;tr<5;tr++)
    #pragma unroll
    for(int tc=0;tc<2;tc++){
      int col = (wave*2+tc)*16 + l15;
      #pragma unroll
      for(int r=0;r<4;r++){
        int R = tr*16 + l4*4 + r;
        Cs[R*128 + col] = tanh_fast(tanh_fast(acc[tr][tc][r]));
      }
    }
  __syncthreads();

  #pragma unroll
  for(int t=0;t<4;t++){
    int oi = t*256 + tid;
    int g = oi >> 7, col = oi & 127;
    float s = 0.f;
    const float* p = Cs + g*1280 + col;
    #pragma unroll
    for(int b=0;b<10;b++) s += p[b*128];
    int nl = mb*8 + g;
    int n = nl/L_, l = nl%L_;
    na[((size_t)(n*ASP_+a)*L_ + l)*H2_ + col] = s;
  }
}

// ---------------- uHis_h: bf16 MFMA split-K (grid 4x4x25) ----------------
__global__ __launch_bounds__(256) void k_uhismm(const float* __restrict__ U,
    const float* __restrict__ W, const float* __restrict__ bias, float* __restrict__ C){
  __shared__ unsigned short As[2048];   // 64 rows x 32 k, chunk = q*64+row (8 bf16 each)
  __shared__ unsigned short Bs[2048];
  int tid = threadIdx.x;
  int m0 = blockIdx.y*64, n0 = blockIdx.x*64;
  int kb0 = blockIdx.z*800;
  int row = tid & 63, q = tid >> 6;
  int lane = tid & 63, wave = tid >> 6;
  int l15 = lane & 15, l4 = lane >> 4;
  int wr = (wave>>1)*32, wc = (wave&1)*32;
  f32x4 acc[2][2] = {};
  for(int s=0;s<25;s++){
    int k0 = kb0 + s*32 + q*8;
    {
      const float* pa = &U[(size_t)(m0+row)*NIT_ + k0];
      float4 a0 = *(const float4*)pa, a1 = *(const float4*)(pa+4);
      bf16x8 av;
      av[0]=f2b(a0.x); av[1]=f2b(a0.y); av[2]=f2b(a0.z); av[3]=f2b(a0.w);
      av[4]=f2b(a1.x); av[5]=f2b(a1.y); av[6]=f2b(a1.z); av[7]=f2b(a1.w);
      *(bf16x8*)(As + 8*tid) = av;
      const float* pb = &W[(size_t)(n0+row)*NIT_ + k0];
      float4 b0 = *(const float4*)pb, b1 = *(const float4*)(pb+4);
      bf16x8 bv;
      bv[0]=f2b(b0.x); bv[1]=f2b(b0.y); bv[2]=f2b(b0.z); bv[3]=f2b(b0.w);
      bv[4]=f2b(b1.x); bv[5]=f2b(b1.y); bv[6]=f2b(b1.z); bv[7]=f2b(b1.w);
      *(bf16x8*)(Bs + 8*tid) = bv;
    }
    __syncthreads();
    bf16x8 afr[2], bfr[2];
    #pragma unroll
    for(int mt=0;mt<2;mt++) afr[mt] = *(const bf16x8*)(As + 8*(l4*64 + wr + mt*16 + l15));
    #pragma unroll
    for(int nt=0;nt<2;nt++) bfr[nt] = *(const bf16x8*)(Bs + 8*(l4*64 + wc + nt*16 + l15));
    #pragma unroll
    for(int mt=0;mt<2;mt++)
      #pragma unroll
      for(int nt=0;nt<2;nt++)
        acc[mt][nt] = __builtin_amdgcn_mfma_f32_16x16x32_bf16(afr[mt], bfr[nt], acc[mt][nt], 0,0,0);
    __syncthreads();
  }
  #pragma unroll
  for(int mt=0;mt<2;mt++)
    #pragma unroll
    for(int nt=0;nt<2;nt++){
      int col = n0 + wc + nt*16 + l15;
      #pragma unroll
      for(int r=0;r<4;r++){
        int rw = m0 + wr + mt*16 + l4*4 + r;
        float v = acc[mt][nt][r];
        if(blockIdx.z==0) v += bias[col];
        atomicAdd(&C[rw*H2_ + col], v);
      }
    }
}

// ---------------- xg GEMM: bf16 MFMA, in-register cast, OUTPUT bf16 ----------------
__global__ __launch_bounds__(256) void k_xgmm(const float* __restrict__ A_,
    const float* __restrict__ W, const float* __restrict__ bias,
    unsigned short* __restrict__ Cb){
  __shared__ unsigned short As[2048];
  __shared__ unsigned short Bs[2048];
  int tid = threadIdx.x;
  int n0 = blockIdx.x*64, m0 = blockIdx.y*64;
  int row = tid & 63, q = tid >> 6;
  int lane = tid & 63, wave = tid >> 6;
  int l15 = lane & 15, l4 = lane >> 4;
  int wr = (wave>>1)*32, wc = (wave&1)*32;
  f32x4 acc[2][2] = {};
  for(int s=0;s<8;s++){
    int k0 = s*32 + q*8;
    {
      const float* pa = &A_[(size_t)(m0+row)*H2_ + k0];
      float4 a0 = *(const float4*)pa, a1 = *(const float4*)(pa+4);
      bf16x8 av;
      av[0]=f2b(a0.x); av[1]=f2b(a0.y); av[2]=f2b(a0.z); av[3]=f2b(a0.w);
      av[4]=f2b(a1.x); av[5]=f2b(a1.y); av[6]=f2b(a1.z); av[7]=f2b(a1.w);
      *(bf16x8*)(As + 8*tid) = av;
      const float* pb = &W[(size_t)(n0+row)*H2_ + k0];
      float4 b0 = *(const float4*)pb, b1 = *(const float4*)(pb+4);
      bf16x8 bv;
      bv[0]=f2b(b0.x); bv[1]=f2b(b0.y); bv[2]=f2b(b0.z); bv[3]=f2b(b0.w);
      bv[4]=f2b(b1.x); bv[5]=f2b(b1.y); bv[6]=f2b(b1.z); bv[7]=f2b(b1.w);
      *(bf16x8*)(Bs + 8*tid) = bv;
    }
    __syncthreads();
    bf16x8 afr[2], bfr[2];
    #pragma unroll
    for(int mt=0;mt<2;mt++) afr[mt] = *(const bf16x8*)(As + 8*(l4*64 + wr + mt*16 + l15));
    #pragma unroll
    for(int nt=0;nt<2;nt++) bfr[nt] = *(const bf16x8*)(Bs + 8*(l4*64 + wc + nt*16 + l15));
    #pragma unroll
    for(int mt=0;mt<2;mt++)
      #pragma unroll
      for(int nt=0;nt<2;nt++)
        acc[mt][nt] = __builtin_amdgcn_mfma_f32_16x16x32_bf16(afr[mt], bfr[nt], acc[mt][nt], 0,0,0);
    __syncthreads();
  }
  #pragma unroll
  for(int mt=0;mt<2;mt++)
    #pragma unroll
    for(int nt=0;nt<2;nt++){
      int col = n0 + wc + nt*16 + l15;
      float bs = bias[col];
      #pragma unroll
      for(int r=0;r<4;r++){
        int rw = m0 + wr + mt*16 + l4*4 + r;
        Cb[(size_t)rw*G4_ + col] = f2b(acc[mt][nt][r] + bs);
      }
    }
}

// ---------------- cast out_w -> bf16 ----------------
__global__ void k_outb(const float* __restrict__ w, unsigned short* __restrict__ wb){
  int i = blockIdx.x*blockDim.x + threadIdx.x;   // 640000 threads, 8 elems each
  const float* p = w + (size_t)i*8;
  float4 a = *(const float4*)p, b = *(const float4*)(p+4);
  bf16x8 v;
  v[0]=f2b(a.x); v[1]=f2b(a.y); v[2]=f2b(a.z); v[3]=f2b(a.w);
  v[4]=f2b(b.x); v[5]=f2b(b.y); v[6]=f2b(b.z); v[7]=f2b(b.w);
  *(bf16x8*)(wb + (size_t)i*8) = v;
}

// ---------------- logits: bf16 MFMA, tile 256x32, grid 625 ----------------
__global__ __launch_bounds__(256) void k_logitsmm(const unsigned short* __restrict__ Ab,
    const unsigned short* __restrict__ Wb, const float* __restrict__ bias,
    float* __restrict__ C){
  int n0 = blockIdx.x*32;
  int tid = threadIdx.x;
  int lane = tid & 63, wave = tid >> 6;
  int l15 = lane & 15, l4 = lane >> 4;
  f32x4 acc[4][2] = {};
  #pragma unroll
  for(int kk=0;kk<8;kk++){
    int k0 = kk*32 + l4*8;
    bf16x8 bfr[2];
    #pragma unroll
    for(int nt=0;nt<2;nt++)
      bfr[nt] = *(const bf16x8*)(Wb + (size_t)(n0 + nt*16 + l15)*H2_ + k0);
    #pragma unroll
    for(int mt=0;mt<4;mt++){
      bf16x8 afr = *(const bf16x8*)(Ab + (size_t)(wave*64 + mt*16 + l15)*H2_ + k0);
      acc[mt][0] = __builtin_amdgcn_mfma_f32_16x16x32_bf16(afr, bfr[0], acc[mt][0], 0,0,0);
      acc[mt][1] = __builtin_amdgcn_mfma_f32_16x16x32_bf16(afr, bfr[1], acc[mt][1], 0,0,0);
    }
  }
  #pragma unroll
  for(int mt=0;mt<4;mt++)
    #pragma unroll
    for(int nt=0;nt<2;nt++){
      int col = n0 + nt*16 + l15;
      float bs = bias[col];
      #pragma unroll
      for(int r=0;r<4;r++){
        int row = wave*64 + mt*16 + l4*4 + r;
        C[(size_t)row*NIT_ + col] = acc[mt][nt][r] + bs;
      }
    }
}

// ---------------- generic fp32 NT GEMM (E2 only now) ----------------
__global__ __launch_bounds__(256) void k_gemm(const float* __restrict__ A, const float* __restrict__ W,
    float* __restrict__ C, const float* __restrict__ bias,
    int M, int Nn, int K, int kchunk, int atomic_mode){
  __shared__ float As[64][17];
  __shared__ float Ws[64][17];
  int tid = threadIdx.x;
  int tx = tid & 15, ty = tid >> 4;
  int m0 = blockIdx.y*64, n0 = blockIdx.x*64;
  int kb0 = blockIdx.z*kchunk;
  int kend = kb0 + kchunk; if(kend > K) kend = K;
  float acc[4][4] = {};
  int lrow = tid >> 2;
  int lc4 = (tid & 3) * 4;
  for(int kb = kb0; kb < kend; kb += 16){
    {
      int gr = m0 + lrow;
      float4 v = make_float4(0,0,0,0);
      if(gr < M) v = *(const float4*)&A[(long)gr*K + kb + lc4];
      As[lrow][lc4+0]=v.x; As[lrow][lc4+1]=v.y; As[lrow][lc4+2]=v.z; As[lrow][lc4+3]=v.w;
      int gw = n0 + lrow;
      float4 u = make_float4(0,0,0,0);
      if(gw < Nn) u = *(const float4*)&W[(long)gw*K + kb + lc4];
      Ws[lrow][lc4+0]=u.x; Ws[lrow][lc4+1]=u.y; Ws[lrow][lc4+2]=u.z; Ws[lrow][lc4+3]=u.w;
    }
    __syncthreads();
    for(int k=0;k<16;k++){
      float av[4], wv[4];
      #pragma unroll
      for(int r=0;r<4;r++) av[r]=As[ty*4+r][k];
      #pragma unroll
      for(int c=0;c<4;c++) wv[c]=Ws[tx*4+c][k];
      #pragma unroll
      for(int r=0;r<4;r++)
        #pragma unroll
        for(int c=0;c<4;c++) acc[r][c] += av[r]*wv[c];
    }
    __syncthreads();
  }
  for(int r=0;r<4;r++){
    int row = m0 + ty*4 + r; if(row >= M) continue;
    for(int c=0;c<4;c++){
      int col = n0 + tx*4 + c; if(col >= Nn) continue;
      float v = acc[r][c];
      if(bias && blockIdx.z==0) v += bias[col];
      if(atomic_mode) atomicAdd(&C[(long)row*Nn+col], v);
      else C[(long)row*Nn+col] = v;
    }
  }
}

// ---------------- PI: na[n,a,l,128:256] = sum_nbr E2[nbr,l,h] + B*dh_b[h] ----------------
__global__ void k_pi(const float* __restrict__ e2, const int* __restrict__ nbr,
                     const float* __restrict__ dh_b, float* __restrict__ na){
  int n = blockIdx.x, a = blockIdx.y, h = threadIdx.x; // 128
  __shared__ int nb[KK_-1];
  if(h < KK_-1) nb[h] = nbr[(a*N_+n)*(KK_-1)+h];
  __syncthreads();
  float bias = (float)B_ * dh_b[h];
  for(int l=0;l<L_;l++){
    float s = bias;
    for(int k=0;k<KK_-1;k++) s += e2[(long)(nb[k]*L_ + l)*H_ + h];
    na[((long)(n*ASP_+a)*L_ + l)*H2_ + H_ + h] = s;
  }
}

// ---------------- x: flat reinterpret max over 4 consecutive ----------------
__global__ void k_xmax(const float* __restrict__ na, float* __restrict__ x){
  int i = blockIdx.x*blockDim.x + threadIdx.x;
  if(i >= N_*L_*H2_) return;
  int n = i / (L_*H2_);
  int j = i % (L_*H2_);
  const float* p = &na[(long)n*ASP_*L_*H2_ + 4*j];
  x[i] = fmaxf(fmaxf(p[0],p[1]), fmaxf(p[2],p[3]));
}

// ---------------- LSTM weight permute (fp32, for wih used by xg GEMM) ----------------
__global__ void k_perm(const float* __restrict__ src, float* __restrict__ dst){
  int i = blockIdx.x*blockDim.x + threadIdx.x;
  if(i >= G4_*H2_) return;
  int k = i % H2_; int j = i / H2_;
  int g = j / H2_, jj = j % H2_;
  dst[(jj*4+g)*H2_ + k] = src[i];
}
// ---------------- LSTM recurrent weight permute + bf16 cast ----------------
__global__ void k_permh(const float* __restrict__ src, unsigned short* __restrict__ dst){
  int i = blockIdx.x*blockDim.x + threadIdx.x;
  if(i >= G4_*H2_) return;
  int k = i % H2_; int j = i / H2_;
  int g = j / H2_, jj = j % H2_;
  dst[(jj*4+g)*H2_ + k] = f2b(src[i]);
}
__global__ void k_permb(const float* __restrict__ bih, const float* __restrict__ bhh,
                        float* __restrict__ bp){
  int j = blockIdx.x*blockDim.x + threadIdx.x;
  if(j >= G4_) return;
  int g = j / H2_, jj = j % H2_;
  bp[jj*4+g] = bih[j] + bhh[j];
}

// ---------------- fused LSTM layer, gate-split: 64 blocks, ALL weights LDS-resident ----------------
// Block b = (sg = b>>2, q = b&3): gates [q*256, q*256+256) for samples [sg*16, sg*16+16).
// Weight quarter (128 KB) preloaded to LDS once; per-step cross-block h exchange via
// device-scope atomics (G16/m20): pack pairs, relaxed-agent stores -> barrier (vmcnt drained,
// m97) -> release flag -> acquire spin on 3 siblings -> relaxed-agent loads -> LDS assemble.
// hexch double-buffered by t&1 (flag>=t+1 implies sibling consumed t-1). Publish-before-wait:
// no deadlock; 64 blocks co-resident (1/CU at 144KB LDS, 256 CUs). Math bit-identical to r15.
__global__ __launch_bounds__(256) void k_lstm_layer(
    const unsigned short* __restrict__ Whb,   // [1024][256] bf16 permuted (col=jj*4+g)
    const unsigned short* __restrict__ xgb,   // [256][20][1024] bf16 ih products
    float* __restrict__ Y,                    // [256][20][256] fp32 h sequence
    unsigned int* __restrict__ hexch,         // [2][64][512] packed bf16 pairs
    int* __restrict__ flags){                 // [16][4] step counters (zeroed per launch)
  __shared__ unsigned short wc[65536];        // 128 KB: 16 local tiles x 8KB
  __shared__ unsigned short hs[2][16*H2_];    // 2 x 8 KB full h, chunk ch=s*32+k/8, swz ^(s&7)
  int tid = threadIdx.x;
  int b = blockIdx.x, sg = b>>2, q = b&3;
  int n0 = sg*16;
  int lane = tid & 63, wave = tid >> 6;       // wave 0..3, owns local tiles wave*4..+3
  int l15 = lane & 15, l4 = lane >> 4;
  int n = n0 + l15;
  float creg[4] = {0.f,0.f,0.f,0.f};
  // preload this block's 16 gate tiles (global tiles q*16 .. q*16+15)
  #pragma unroll
  for(int it=0; it<32; it++){
    int cidx = it*256 + tid;                 // 0..8191 chunks of 8 bf16
    int tl = cidx >> 9;                      // local tile 0..15
    int c  = cidx & 511;
    int row = c >> 5;
    bf16x8 w8 = *(const bf16x8*)(Whb + (size_t)((q*16+tl)*16 + row)*H2_ + (c&31)*8);
    *(bf16x8*)(wc + 8*((tl<<9) + (c ^ (row&7)))) = w8;
  }
  __syncthreads();
  for(int t=0; t<L_; t++){
    bf16x4 xgv[4];
    #pragma unroll
    for(int i=0;i<4;i++){
      int jj = q*64 + wave*16 + i*4 + l4;
      xgv[i] = *(const bf16x4*)(xgb + ((size_t)n*L_ + t)*G4_ + jj*4);
    }
    f32x4 acc[4] = {};
    if(t > 0){
      const unsigned short* hbuf = hs[(t+1)&1];   // holds h(t-1)
      bf16x8 hfr[8];
      #pragma unroll
      for(int kk=0; kk<8; kk++){
        int ch = l15*32 + kk*4 + l4;
        hfr[kk] = *(const bf16x8*)(hbuf + 8*(ch ^ (l15&7)));
      }
      #pragma unroll
      for(int kk=0; kk<8; kk++){
        bf16x8 wfr[4];
        #pragma unroll
        for(int i=0;i<4;i++){
          int tl = wave*4 + i;
          wfr[i] = *(const bf16x8*)(wc + 8*((tl<<9) + ((l15*32 + kk*4 + l4) ^ (l15&7))));
        }
        #pragma unroll
        for(int i=0;i<4;i++)
          acc[i] = __builtin_amdgcn_mfma_f32_16x16x32_bf16(wfr[i], hfr[kk], acc[i], 0,0,0);
      }
    }
    unsigned short* hout = hs[t&1];
    unsigned int hbits[4];
    #pragma unroll
    for(int i=0;i<4;i++){
      int jj = q*64 + wave*16 + i*4 + l4;
      float gi = acc[i][0] + b2f((unsigned short)xgv[i][0]);
      float gf = acc[i][1] + b2f((unsigned short)xgv[i][1]);
      float gg = acc[i][2] + b2f((unsigned short)xgv[i][2]);
      float go = acc[i][3] + b2f((unsigned short)xgv[i][3]);
      float cnew = sigf_fast(gf)*creg[i] + sigf_fast(gi)*tanh_fast(gg);
      creg[i] = cnew;
      float hnew = sigf_fast(go)*tanh_fast(cnew);
      Y[((size_t)n*L_ + t)*H2_ + jj] = hnew;
      unsigned short us = f2b(hnew);
      hbits[i] = us;
      int ch = l15*32 + (jj>>3);
      *(unsigned short*)((char*)hout + 16*(ch ^ (l15&7)) + (jj&7)*2) = us;
    }
    if(t < L_-1){
      // publish own quarter (pack (jj,jj+1) pairs on even-l4 lanes)
      unsigned int* hx = hexch + ((size_t)(t&1)*64 + b)*512;
      #pragma unroll
      for(int i=0;i<4;i++){
        unsigned int part = (unsigned int)__shfl_xor((int)hbits[i], 16, 64);
        if((l4 & 1) == 0){
          int jjl = wave*16 + i*4 + l4;      // even local jj
          unsigned int packed = (hbits[i] & 0xFFFFu) | (part << 16);
          __hip_atomic_store(&hx[l15*32 + (jjl>>1)], packed,
                             __ATOMIC_RELAXED, __HIP_MEMORY_SCOPE_AGENT);
        }
      }
      __syncthreads();   // barrier drains vmcnt: all lanes' stores performed
      if(tid == 0)
        __hip_atomic_store(&flags[sg*4+q], t+1, __ATOMIC_RELEASE, __HIP_MEMORY_SCOPE_AGENT);
      if(tid < 3){
        int qq = tid + (tid >= q ? 1 : 0);
        while(__hip_atomic_load(&flags[sg*4+qq], __ATOMIC_ACQUIRE,
                                __HIP_MEMORY_SCOPE_AGENT) < t+1){}
      }
      __syncthreads();
      // gather 3 sibling quarters into hout
      #pragma unroll
      for(int it2=0; it2<6; it2++){
        int idx = it2*256 + tid;            // 0..1535
        int qr = idx >> 9;                  // 0..2
        int qq = qr + (qr >= q ? 1 : 0);
        int u  = idx & 511;
        unsigned int pk = __hip_atomic_load(
            &hexch[((size_t)(t&1)*64 + sg*4 + qq)*512 + u],
            __ATOMIC_RELAXED, __HIP_MEMORY_SCOPE_AGENT);
        int smp = u >> 5;
        int jj  = qq*64 + (u & 31)*2;
        int ch  = smp*32 + (jj>>3);
        *(unsigned int*)((char*)hout + 16*(ch ^ (smp&7)) + (jj&7)*2) = pk;
      }
    }
    __syncthreads();   // h(t) fully assembled before step t+1 reads
  }
}

// ---------------- h_agg = tanh(sum_t y1) (+ bf16 shadow) ----------------
__global__ void k_hagg(const float* __restrict__ y1, float* __restrict__ hagg,
                       unsigned short* __restrict__ haggb){
  int i = blockIdx.x*blockDim.x + threadIdx.x;
  if(i>=N_*H2_) return;
  int n = i / H2_, jj = i % H2_;
  float s=0.f;
  for(int t=0;t<L_;t++) s += y1[((long)n*L_+t)*H2_ + jj];
  float v = tanhf(s);
  hagg[i] = v;
  haggb[i] = f2b(v);
}

// ---------------- gate ----------------
__global__ void k_gate(const float* __restrict__ uhish, const float* __restrict__ hagg,
                       const float* __restrict__ g1w, const float* __restrict__ g1b,
                       const float* __restrict__ g2w, const float* __restrict__ g2b,
                       float* __restrict__ gate){
  int n = blockIdx.x; int t = threadIdx.x; // 256
  float s = uhish[n*H2_+t]*g1w[t] + hagg[n*H2_+t]*g2w[t];
  __shared__ float red[256];
  red[t]=s; __syncthreads();
  for(int o=128;o>0;o>>=1){ if(t<o) red[t]+=red[t+o]; __syncthreads(); }
  if(t==0) gate[n] = 1.f/(1.f+expf(-(red[0]+g1b[0]+g2b[0])));
}

// ---------------- softmax row stats ----------------
__global__ void k_smstat(const float* __restrict__ logits, float* __restrict__ rowmax,
                         float* __restrict__ rowsum){
  int n = blockIdx.x; int t = threadIdx.x;
  const float* row = &logits[(long)n*NIT_];
  float m = -3.4e38f;
  for(int i=t;i<NIT_;i+=256) m = fmaxf(m, row[i]);
  __shared__ float red[256];
  __shared__ float mm;
  red[t]=m; __syncthreads();
  for(int o=128;o>0;o>>=1){ if(t<o) red[t]=fmaxf(red[t],red[t+o]); __syncthreads(); }
  if(t==0){ mm = red[0]; rowmax[n]=red[0]; }
  __syncthreads();
  float s=0.f;
  for(int i=t;i<NIT_;i+=256) s += __expf(row[i]-mm);
  __syncthreads();
  red[t]=s; __syncthreads();
  for(int o=128;o>0;o>>=1){ if(t<o) red[t]+=red[t+o]; __syncthreads(); }
  if(t==0) rowsum[n]=red[0];
}

// ---------------- final ----------------
__global__ void k_final(const float* __restrict__ logits, const float* __restrict__ rowmax,
                        const float* __restrict__ rowsum, const float* __restrict__ gate,
                        const float* __restrict__ uHis, float* __restrict__ out){
  int i = blockIdx.x*blockDim.x + threadIdx.x;
  if(i >= N_*NIT_) return;
  int n = i / NIT_;
  float g = gate[n];
  float p = __expf(logits[i]-rowmax[n]) / rowsum[n];
  out[i] = g*p + (1.f-g)*uHis[i];
}

extern "C" void kernel_launch(void* const* d_in, const int* in_sizes, int n_in,
                              void* d_out, int out_size, void* d_ws, size_t ws_size,
                              hipStream_t stream) {
  const int*   seq     = (const int*)  d_in[0];
  const float* uHis    = (const float*)d_in[1];
  const float* itemEmb = (const float*)d_in[2];
  const float* fc1_w   = (const float*)d_in[3];
  const float* fc1_b   = (const float*)d_in[4];
  const float* aspProju= (const float*)d_in[5];
  const float* aspProji= (const float*)d_in[6];
  const float* dh_w    = (const float*)d_in[7];
  const float* dh_b    = (const float*)d_in[8];
  const float* wih0    = (const float*)d_in[9];
  const float* whh0    = (const float*)d_in[10];
  const float* bih0    = (const float*)d_in[11];
  const float* bhh0    = (const float*)d_in[12];
  const float* wih1    = (const float*)d_in[13];
  const float* whh1    = (const float*)d_in[14];
  const float* bih1    = (const float*)d_in[15];
  const float* bhh1    = (const float*)d_in[16];
  const float* out_w   = (const float*)d_in[17];
  const float* out_b   = (const float*)d_in[18];
  const float* his_w   = (const float*)d_in[19];
  const float* his_b   = (const float*)d_in[20];
  const float* g1_w    = (const float*)d_in[21];
  const float* g1_b    = (const float*)d_in[22];
  const float* g2_w    = (const float*)d_in[23];
  const float* g2_b    = (const float*)d_in[24];

  float* ws = (float*)d_ws;
  float* embs = ws + 0;            // 6,553,600   (reused as logits later)
  float* cub  = ws + 6553600;      // 6,553,600   (ebh bf16 shadow; reused as xgb bf16 later)
  float* na   = ws + 13107200;     // 5,242,880   (reused as outwb bf16 after xmax)
  float* x    = ws + 18350080;     // 1,310,720   (reused as haggb after xg0)
  float* y0   = ws + 19660800;     // 1,310,720
  float* y1   = ws + 20971520;     // 1,310,720
  float* eb   = ws + 22282240;     //   655,360
  float* e2   = ws + 22937600;     //   655,360
  float* dist = ws + 23592960;     //   262,144  (dead after topk: hexch+flags live here)
  float* ua   = ws + 23855104;     //   131,072
  float* projT= ws + 23986176;     //    65,536  (holds projb bf16)
  float* wp0  = ws + 24051712;     //   262,144  (fp32 permuted wih0)
  float* whp0 = ws + 24313856;     //   262,144  (bf16 permuted whh0 lives here)
  float* wp1  = ws + 24576000;     //   262,144  (fp32 permuted wih1)
  float* whp1 = ws + 24838144;     //   262,144  (bf16 permuted whh1 lives here)
  float* bp0  = ws + 25100288;     //     1,024
  float* bp1  = ws + 25101312;     //     1,024
  float* uemb = ws + 25167872;     //       256
  float* sqb  = ws + 25168128;     //     1,024
  int*   nbr  = (int*)(ws + 25169152); // 15,360 ints
  float* uhish= ws + 25184512;     //    65,536
  float* hagg = ws + 25250048;     //    65,536
  float* rowmax=ws + 25315584;     //       256
  float* rowsum=ws + 25315840;     //       256
  float* gateb =ws + 25316096;     //       256
  float* logits = embs;            // reuse
  unsigned short* ebh   = (unsigned short*)cub;   // bf16 shadow (inside cub slot)
  unsigned short* xgb   = (unsigned short*)cub;   // bf16 xg (ebh dead after k_uimm)
  unsigned short* projb = (unsigned short*)projT; // bf16 (inside projT slot)
  unsigned short* outwb = (unsigned short*)na;    // bf16 out_w (na dead after xmax)
  unsigned short* haggb = (unsigned short*)x;     // bf16 hagg (x dead after xg0)
  unsigned short* whb0  = (unsigned short*)whp0;  // bf16 permuted whh0
  unsigned short* whb1  = (unsigned short*)whp1;  // bf16 permuted whh1
  unsigned int*   hexch = (unsigned int*)dist;    // 65,536 uints = 256KB (dist dead after topk)
  int*            lflags= (int*)(dist + 65536);   // 128 ints: [0..63] layer0, [64..127] layer1

  // 1. embedding gather (fp32 + bf16 shadow)
  k_gather<<<NLB_, D_, 0, stream>>>(seq, itemEmb, embs, ebh);
  // 2. fc1 -> u_embs
  k_fc1<<<N_, 256, 0, stream>>>(embs, fc1_w, fc1_b, uemb);
  // 3. uA
  k_ua<<<(ASP_*N_*H_+255)/256, 256, 0, stream>>>(uemb, aspProju, ua);
  // 4. sq
  k_sq<<<ASP_*N_, 128, 0, stream>>>(ua, sqb);
  // 5. dist
  k_dist<<<dim3(N_,ASP_), 256, 0, stream>>>(ua, sqb, dist);
  // 6. top-k neighbors
  k_topk<<<ASP_*N_/4, 256, 0, stream>>>(dist, nbr);
  // 7. EB = sum_b embs
  k_eb<<<NL_, D_, 0, stream>>>(embs, eb);
  // 8. E2 = EB @ dh_w^T
  k_gemm<<<dim3(2, 80, 1), 256, 0, stream>>>(eb, dh_w, e2, nullptr, NL_, H_, D_, D_, 0);
  // 9. projb (bf16 transposed proj)
  k_projb<<<(ASP_*D_*H_+255)/256, 256, 0, stream>>>(aspProji, projb);
  // 10. fused UI stage: MFMA + tanh^2 + sum_b
  k_uimm<<<dim3(NL_/8, ASP_), 256, 0, stream>>>(ebh, projb, na);
  // 11. PI (neighbor sums)
  k_pi<<<dim3(N_,ASP_), H_, 0, stream>>>(e2, nbr, dh_b, na);
  // 12. x = flat max-4
  k_xmax<<<(N_*L_*H2_+255)/256, 256, 0, stream>>>(na, x);
  // 12b. cast out_w -> bf16 (into dead na region)
  k_outb<<<2500, 256, 0, stream>>>(out_w, outwb);
  // 13. LSTM weight permutes: wih fp32, whh bf16; zero sync flags (dist region dead now)
  k_perm <<<(G4_*H2_+255)/256,256,0,stream>>>(wih0, wp0);
  k_permh<<<(G4_*H2_+255)/256,256,0,stream>>>(whh0, whb0);
  k_perm <<<(G4_*H2_+255)/256,256,0,stream>>>(wih1, wp1);
  k_permh<<<(G4_*H2_+255)/256,256,0,stream>>>(whh1, whb1);
  k_permb<<<4,256,0,stream>>>(bih0,bhh0,bp0);
  k_permb<<<4,256,0,stream>>>(bih1,bhh1,bp1);
  hipMemsetAsync(lflags, 0, 128*sizeof(int), stream);
  // 14. xg0 = x @ wp0^T + bp0 : bf16 MFMA, bf16 output
  k_xgmm<<<dim3(16,80), 256, 0, stream>>>(x, wp0, bp0, xgb);
  // 15. LSTM layer 0: 64 gate-split blocks, weights LDS-resident, atomic h-exchange
  k_lstm_layer<<<64, 256, 0, stream>>>(whb0, xgb, y0, hexch, lflags);
  // 16. xg1 = y0 @ wp1^T + bp1 : bf16 MFMA, bf16 output
  k_xgmm<<<dim3(16,80), 256, 0, stream>>>(y0, wp1, bp1, xgb);
  // 17. LSTM layer 1 (separate flag region)
  k_lstm_layer<<<64, 256, 0, stream>>>(whb1, xgb, y1, hexch, lflags + 64);
  // 18. h_agg (+ bf16 shadow into dead x region)
  k_hagg<<<(N_*H2_+255)/256,256,0,stream>>>(y1, hagg, haggb);
  // 19. logits = h_agg @ out_w^T + out_b : bf16 MFMA (grid 625, tile 256x32)
  k_logitsmm<<<625, 256, 0, stream>>>(haggb, outwb, out_b, logits);
  // 20. uHis_h = uHis @ his_w^T + his_b : bf16 MFMA split-K
  hipMemsetAsync(uhish, 0, N_*H2_*sizeof(float), stream);
  k_uhismm<<<dim3(4,4,25), 256, 0, stream>>>(uHis, his_w, his_b, uhish);
  // 21. gate
  k_gate<<<N_,256,0,stream>>>(uhish, hagg, g1_w, g1_b, g2_w, g2_b, gateb);
  // 22. softmax stats
  k_smstat<<<N_,256,0,stream>>>(logits, rowmax, rowsum);
  // 23. final scores
  k_final<<<(N_*NIT_+255)/256,256,0,stream>>>(logits, rowmax, rowsum, gateb, uHis, (float*)d_out);
}